// Round 2
// baseline (2821.791 us; speedup 1.0000x reference)
//
#include <hip/hip_runtime.h>
#include <math.h>

#define NB 8
#define NC 192
#define NHEADS 8
#define NCF 24
#define NHW 16384
#define NWIDTH 128
#define NO_QKV 576
#define NHID 510
#define NO_PIN 1020

typedef unsigned short bfu;

__device__ __forceinline__ float b2f(unsigned short u) { return __uint_as_float(((unsigned)u) << 16); }
__device__ __forceinline__ unsigned short f2b(float f) {
    unsigned u = __float_as_uint(f);
    u += 0x7FFFu + ((u >> 16) & 1u);
    return (unsigned short)(u >> 16);
}
__device__ __forceinline__ float geluf(float v) {
    return 0.5f * v * (1.0f + erff(v * 0.70710678118654752440f));
}

struct F8 { float v[8]; };
__device__ __forceinline__ F8 load8(const bfu* p) {
    uint4 r = *(const uint4*)p;
    F8 o;
    o.v[0] = b2f((unsigned short)(r.x & 0xffff)); o.v[1] = b2f((unsigned short)(r.x >> 16));
    o.v[2] = b2f((unsigned short)(r.y & 0xffff)); o.v[3] = b2f((unsigned short)(r.y >> 16));
    o.v[4] = b2f((unsigned short)(r.z & 0xffff)); o.v[5] = b2f((unsigned short)(r.z >> 16));
    o.v[6] = b2f((unsigned short)(r.w & 0xffff)); o.v[7] = b2f((unsigned short)(r.w >> 16));
    return o;
}
__device__ __forceinline__ void store8(bfu* p, const float* a) {
    uint4 r;
    r.x = (unsigned)f2b(a[0]) | ((unsigned)f2b(a[1]) << 16);
    r.y = (unsigned)f2b(a[2]) | ((unsigned)f2b(a[3]) << 16);
    r.z = (unsigned)f2b(a[4]) | ((unsigned)f2b(a[5]) << 16);
    r.w = (unsigned)f2b(a[6]) | ((unsigned)f2b(a[7]) << 16);
    *(uint4*)p = r;
}

__global__ __launch_bounds__(256) void zfill(float* __restrict__ p, int n) {
    int i = blockIdx.x * 256 + threadIdx.x;
    if (i < n) p[i] = 0.f;
}

// ---------------------------------------------------------------------------
// prep: m = k_v @ kern^T ; s[c]=ln_w[c]*m[c]; t[c]=ln_b[c]*m[c]+m[192+c];
// uvec[o]=sum_c W[o,c]*s[c]; v0vec[o]=sum_c W[o,c]*t[c].  grid (ceil(O/256), NB)
// ---------------------------------------------------------------------------
__global__ __launch_bounds__(256) void prep_film(
    const float* __restrict__ kv, const float* __restrict__ kern,
    const float* __restrict__ lnw, const float* __restrict__ lnb,
    const float* __restrict__ W, int O,
    float* __restrict__ sArr, float* __restrict__ tArr,
    float* __restrict__ uvec, float* __restrict__ v0vec)
{
    const int oc = blockIdx.x, b = blockIdx.y, t = threadIdx.x;
    __shared__ float m[2 * NC];
    __shared__ float sl[NC], tl[NC];
    const float* kvb = kv + b * 256;
    for (int r = t; r < 2 * NC; r += 256) {
        const float* kr = kern + (size_t)r * 256;
        float acc = 0.f;
        for (int i = 0; i < 256; ++i) acc = fmaf(kvb[i], kr[i], acc);
        m[r] = acc;
    }
    __syncthreads();
    if (t < NC) {
        float ma = m[t], mb2 = m[NC + t];
        float sv = lnw[t] * ma;
        float tv = lnb[t] * ma + mb2;
        sl[t] = sv; tl[t] = tv;
        if (oc == 0) { sArr[b * NC + t] = sv; tArr[b * NC + t] = tv; }
    }
    __syncthreads();
    int o = oc * 256 + t;
    if (o < O) {
        const float* wr = W + (size_t)o * NC;
        float au = 0.f, av = 0.f;
        for (int c = 0; c < NC; ++c) { float w = wr[c]; au = fmaf(w, sl[c], au); av = fmaf(w, tl[c], av); }
        uvec[(size_t)b * O + o] = au;
        v0vec[(size_t)b * O + o] = av;
    }
}

// ---------------------------------------------------------------------------
// per-pixel LN stats over 192 channels, chunk of CB batches (local b).
// ---------------------------------------------------------------------------
__global__ __launch_bounds__(256) void ln_stats(
    const float* __restrict__ x, float* __restrict__ mu, float* __restrict__ rstd, int cb)
{
    int idx = blockIdx.x * 256 + threadIdx.x;
    if (idx >= cb * NHW) return;
    int b = idx >> 14, n = idx & (NHW - 1);
    const float* p = x + (size_t)b * NC * NHW + n;
    float s = 0.f, ss = 0.f;
    for (int c = 0; c < NC; ++c) { float v = p[(size_t)c * NHW]; s += v; ss = fmaf(v, v, ss); }
    float m = s * (1.f / 192.f);
    float var = ss * (1.f / 192.f) - m * m;
    mu[idx] = m;
    rstd[idx] = rsqrtf(var + 1e-5f);
}

// ---------------------------------------------------------------------------
// channel-contraction GEMM: Y[b,o,n] = epilogue( sum_c A[o,c] * X[b,off+c,n] )
// MODE 0: X fp32, A=W[o,c]*s[b,c], epi = rstd*(acc-mu*uvec[o])+v0vec[o], Y bf16
// MODE 1: X bf16, A=Wm[b][o][c],  epi = acc + res, Y fp32
// MODE 2: X bf16, A=Wm[o][c],     epi = acc + res, Y fp32
// tiles 64x64x64, 256 threads, 4x4 microtile. blockIdx.z = local batch.
// ---------------------------------------------------------------------------
template<int MODE>
__global__ __launch_bounds__(256) void gemm_cc(
    const float* __restrict__ Wm, int O, int K,
    const void* __restrict__ Xv, int xStride, int xOff,
    void* __restrict__ Yv,
    const float* __restrict__ sArr,
    const float* __restrict__ mu, const float* __restrict__ rstd,
    const float* __restrict__ uvec, const float* __restrict__ v0vec,
    const float* __restrict__ res)
{
    __shared__ __align__(16) float As[64][65];
    __shared__ __align__(16) float Bs[64][64];
    const int b  = blockIdx.z;
    const int om = blockIdx.y * 64;
    const int n0 = blockIdx.x * 64;
    const int tid = threadIdx.x;
    const int tx = tid & 15, ty = tid >> 4;

    float acc[4][4] = {};
    const float* Wb = (MODE == 1) ? Wm + (size_t)b * O * K : Wm;
    const float* sb = (MODE == 0) ? sArr + (size_t)b * NC : nullptr;
    const int nk = (K + 63) >> 6;

    for (int kk = 0; kk < nk; ++kk) {
        const int ck = kk << 6;
        #pragma unroll
        for (int i = 0; i < 16; ++i) {
            int e = i * 256 + tid;
            int cc = e & 63, oo = e >> 6;
            int gc = ck + cc, go = om + oo;
            float a = 0.f;
            if (go < O && gc < K) {
                a = Wb[(size_t)go * K + gc];
                if (MODE == 0) a *= sb[gc];
            }
            As[cc][oo] = a;
        }
        if (MODE == 0) {
            const float* X = (const float*)Xv;
            #pragma unroll
            for (int i = 0; i < 4; ++i) {
                int e = i * 256 + tid;
                int k = e >> 4, nq = e & 15;
                int gc = ck + k;
                float4 v = make_float4(0.f, 0.f, 0.f, 0.f);
                if (gc < K)
                    v = *(const float4*)(X + ((size_t)b * xStride + xOff + gc) * NHW + n0 + (nq << 2));
                *(float4*)&Bs[k][nq << 2] = v;
            }
        } else {
            const bfu* X = (const bfu*)Xv;
            #pragma unroll
            for (int i = 0; i < 2; ++i) {
                int e = i * 256 + tid;
                int k = e >> 3, nq = (e & 7) << 3;
                int gc = ck + k;
                if (gc < K) {
                    F8 f = load8(X + ((size_t)b * xStride + xOff + gc) * NHW + n0 + nq);
                    #pragma unroll
                    for (int j = 0; j < 8; ++j) Bs[k][nq + j] = f.v[j];
                } else {
                    #pragma unroll
                    for (int j = 0; j < 8; ++j) Bs[k][nq + j] = 0.f;
                }
            }
        }
        __syncthreads();
        #pragma unroll 8
        for (int k = 0; k < 64; ++k) {
            float a0 = As[k][(ty << 2) + 0], a1 = As[k][(ty << 2) + 1];
            float a2 = As[k][(ty << 2) + 2], a3 = As[k][(ty << 2) + 3];
            float b0 = Bs[k][(tx << 2) + 0], b1 = Bs[k][(tx << 2) + 1];
            float b2 = Bs[k][(tx << 2) + 2], b3 = Bs[k][(tx << 2) + 3];
            acc[0][0] = fmaf(a0, b0, acc[0][0]); acc[0][1] = fmaf(a0, b1, acc[0][1]);
            acc[0][2] = fmaf(a0, b2, acc[0][2]); acc[0][3] = fmaf(a0, b3, acc[0][3]);
            acc[1][0] = fmaf(a1, b0, acc[1][0]); acc[1][1] = fmaf(a1, b1, acc[1][1]);
            acc[1][2] = fmaf(a1, b2, acc[1][2]); acc[1][3] = fmaf(a1, b3, acc[1][3]);
            acc[2][0] = fmaf(a2, b0, acc[2][0]); acc[2][1] = fmaf(a2, b1, acc[2][1]);
            acc[2][2] = fmaf(a2, b2, acc[2][2]); acc[2][3] = fmaf(a2, b3, acc[2][3]);
            acc[3][0] = fmaf(a3, b0, acc[3][0]); acc[3][1] = fmaf(a3, b1, acc[3][1]);
            acc[3][2] = fmaf(a3, b2, acc[3][2]); acc[3][3] = fmaf(a3, b3, acc[3][3]);
        }
        __syncthreads();
    }

    const int nbase = n0 + (tx << 2);
    float4 muv = make_float4(0.f, 0.f, 0.f, 0.f), rsv = muv;
    if (MODE == 0) {
        muv = *(const float4*)(mu + (size_t)b * NHW + nbase);
        rsv = *(const float4*)(rstd + (size_t)b * NHW + nbase);
    }
    #pragma unroll
    for (int i = 0; i < 4; ++i) {
        int o = om + (ty << 2) + i;
        if (o >= O) continue;
        size_t yo = ((size_t)b * O + o) * NHW + nbase;
        if (MODE == 0) {
            float uo = uvec[(size_t)b * O + o], vo = v0vec[(size_t)b * O + o];
            float r0 = rsv.x * (acc[i][0] - muv.x * uo) + vo;
            float r1 = rsv.y * (acc[i][1] - muv.y * uo) + vo;
            float r2 = rsv.z * (acc[i][2] - muv.z * uo) + vo;
            float r3 = rsv.w * (acc[i][3] - muv.w * uo) + vo;
            bfu* Y = (bfu*)Yv;
            ushort4 pk;
            pk.x = f2b(r0); pk.y = f2b(r1); pk.z = f2b(r2); pk.w = f2b(r3);
            *(ushort4*)(Y + yo) = pk;
        } else {
            float4 rr = *(const float4*)(res + yo);
            float4 r;
            r.x = acc[i][0] + rr.x; r.y = acc[i][1] + rr.y;
            r.z = acc[i][2] + rr.z; r.w = acc[i][3] + rr.w;
            *(float4*)((float*)Yv + yo) = r;
        }
    }
}

// ---------------------------------------------------------------------------
// depthwise 3x3 bf16->bf16, SAME zero-pad, cross-correlation.
// block = 256 threads = 16 rows x (16 threads x 8 px). grid = nPlanes*8 stripes.
// ---------------------------------------------------------------------------
__global__ __launch_bounds__(256) void dwconv(
    const bfu* __restrict__ in, const float* __restrict__ w,
    bfu* __restrict__ out, int Cn)
{
    const int blk = blockIdx.x;
    const int stripe = blk & 7;
    const int plane = blk >> 3;         // local b * Cn + c
    const int c = plane % Cn;
    const int t = threadIdx.x;
    const int x0 = (t & 15) << 3;
    const int y = (stripe << 4) + (t >> 4);
    const bfu* base = in + ((size_t)plane << 14);
    const float* wp = w + (size_t)c * 9;
    float wv[9];
    #pragma unroll
    for (int i = 0; i < 9; ++i) wv[i] = wp[i];
    float acc[8] = {};
    #pragma unroll
    for (int dy = -1; dy <= 1; ++dy) {
        int yy = y + dy;
        if ((unsigned)yy >= (unsigned)NWIDTH) continue;
        const bfu* row = base + yy * NWIDTH;
        float L = (x0 > 0) ? b2f(row[x0 - 1]) : 0.f;
        float R = (x0 < 120) ? b2f(row[x0 + 8]) : 0.f;
        F8 v = load8(row + x0);
        const float w0 = wv[(dy + 1) * 3 + 0], w1 = wv[(dy + 1) * 3 + 1], w2 = wv[(dy + 1) * 3 + 2];
        #pragma unroll
        for (int j = 0; j < 8; ++j) {
            float l = j ? v.v[j - 1] : L;
            float r = (j < 7) ? v.v[j + 1] : R;
            acc[j] = fmaf(w0, l, fmaf(w1, v.v[j], fmaf(w2, r, acc[j])));
        }
    }
    store8(out + ((size_t)plane << 14) + y * NWIDTH + x0, acc);
}

// ---------------------------------------------------------------------------
// depthwise 3x3 on u_pre [b][1020][HW] + exact-GELU gate -> g [b][510][HW]
// ---------------------------------------------------------------------------
__global__ __launch_bounds__(256) void dwgate(
    const bfu* __restrict__ in, const float* __restrict__ w, bfu* __restrict__ g)
{
    const int blk = blockIdx.x;
    const int stripe = blk & 7;
    const int plane = blk >> 3;          // local b*510 + c
    const int c = plane % NHID;
    const int b = plane / NHID;
    const int t = threadIdx.x;
    const int x0 = (t & 15) << 3;
    const int y = (stripe << 4) + (t >> 4);
    const bfu* base1 = in + ((size_t)b * NO_PIN + c) * NHW;
    const bfu* base2 = base1 + (size_t)NHID * NHW;
    float w1v[9], w2v[9];
    #pragma unroll
    for (int i = 0; i < 9; ++i) { w1v[i] = w[(size_t)c * 9 + i]; w2v[i] = w[(size_t)(c + NHID) * 9 + i]; }
    float a1[8] = {}, a2[8] = {};
    #pragma unroll
    for (int dy = -1; dy <= 1; ++dy) {
        int yy = y + dy;
        if ((unsigned)yy >= (unsigned)NWIDTH) continue;
        const bfu* r1 = base1 + yy * NWIDTH;
        const bfu* r2 = base2 + yy * NWIDTH;
        float L1 = (x0 > 0) ? b2f(r1[x0 - 1]) : 0.f;
        float R1 = (x0 < 120) ? b2f(r1[x0 + 8]) : 0.f;
        float L2 = (x0 > 0) ? b2f(r2[x0 - 1]) : 0.f;
        float R2 = (x0 < 120) ? b2f(r2[x0 + 8]) : 0.f;
        F8 v1 = load8(r1 + x0);
        F8 v2 = load8(r2 + x0);
        const float u0 = w1v[(dy + 1) * 3 + 0], u1 = w1v[(dy + 1) * 3 + 1], u2 = w1v[(dy + 1) * 3 + 2];
        const float q0 = w2v[(dy + 1) * 3 + 0], q1 = w2v[(dy + 1) * 3 + 1], q2 = w2v[(dy + 1) * 3 + 2];
        #pragma unroll
        for (int j = 0; j < 8; ++j) {
            float l1 = j ? v1.v[j - 1] : L1, rr1 = (j < 7) ? v1.v[j + 1] : R1;
            float l2 = j ? v2.v[j - 1] : L2, rr2 = (j < 7) ? v2.v[j + 1] : R2;
            a1[j] = fmaf(u0, l1, fmaf(u1, v1.v[j], fmaf(u2, rr1, a1[j])));
            a2[j] = fmaf(q0, l2, fmaf(q1, v2.v[j], fmaf(q2, rr2, a2[j])));
        }
    }
    float res[8];
    #pragma unroll
    for (int j = 0; j < 8; ++j) res[j] = geluf(a1[j]) * a2[j];
    store8(g + ((size_t)b * NHID + c) * NHW + y * NWIDTH + x0, res);
}

// ---------------------------------------------------------------------------
// Gram S[b,h,c,d] = sum_n q[c,n]k[d,n] + row norms^2. atomics over 8 n-chunks.
// ---------------------------------------------------------------------------
__global__ __launch_bounds__(256) void gram_kernel(
    const bfu* __restrict__ qkv,
    float* __restrict__ S, float* __restrict__ Q2, float* __restrict__ K2)
{
    __shared__ float qs[NCF][257];
    __shared__ float ks[NCF][257];
    const int chunk = blockIdx.x, h = blockIdx.y, b = blockIdx.z;
    const int tid = threadIdx.x;
    const int CLEN = NHW / 8;
    const bfu* qb = qkv + ((size_t)b * NO_QKV + h * NCF) * NHW + (size_t)chunk * CLEN;
    const bfu* kb = qb + (size_t)NC * NHW;
    float a00 = 0.f, a01 = 0.f, a10 = 0.f, a11 = 0.f, nacc = 0.f;
    const int ci = tid / 12, dj = tid % 12;
    const int c0 = ci * 2, d0 = dj * 2;
    const float* nrow = &qs[0][0];
    if (tid >= 144 && tid < 192) {
        int c = tid - 144;
        nrow = (c < NCF) ? &qs[c][0] : &ks[c - NCF][0];
    }
    for (int s0 = 0; s0 < CLEN; s0 += 256) {
        #pragma unroll
        for (int i = 0; i < NCF; ++i) {
            qs[i][tid] = b2f(qb[(size_t)i * NHW + s0 + tid]);
            ks[i][tid] = b2f(kb[(size_t)i * NHW + s0 + tid]);
        }
        __syncthreads();
        if (tid < 144) {
            #pragma unroll 4
            for (int j = 0; j < 256; ++j) {
                float q0 = qs[c0][j], q1 = qs[c0 + 1][j];
                float k0 = ks[d0][j], k1 = ks[d0 + 1][j];
                a00 = fmaf(q0, k0, a00); a01 = fmaf(q0, k1, a01);
                a10 = fmaf(q1, k0, a10); a11 = fmaf(q1, k1, a11);
            }
        } else if (tid < 192) {
            #pragma unroll 4
            for (int j = 0; j < 256; ++j) { float v = nrow[j]; nacc = fmaf(v, v, nacc); }
        }
        __syncthreads();
    }
    if (tid < 144) {
        float* Sp = S + ((size_t)b * NHEADS + h) * (NCF * NCF);
        atomicAdd(&Sp[c0 * NCF + d0], a00);
        atomicAdd(&Sp[c0 * NCF + d0 + 1], a01);
        atomicAdd(&Sp[(c0 + 1) * NCF + d0], a10);
        atomicAdd(&Sp[(c0 + 1) * NCF + d0 + 1], a11);
    } else if (tid < 192) {
        int c = tid - 144;
        float* dst = (c < NCF) ? &Q2[((size_t)b * NHEADS + h) * NCF + c]
                               : &K2[((size_t)b * NHEADS + h) * NCF + (c - NCF)];
        atomicAdd(dst, nacc);
    }
}

// ---------------------------------------------------------------------------
// normalize Gram -> softmax -> fold with proj_w into per-batch M [192][192]
// ---------------------------------------------------------------------------
__global__ __launch_bounds__(256) void attn_fold(
    const float* __restrict__ S, const float* __restrict__ Q2, const float* __restrict__ K2,
    const float* __restrict__ temp, const float* __restrict__ projw, float* __restrict__ M)
{
    const int b = blockIdx.x, tid = threadIdx.x;
    __shared__ float P[NHEADS * NCF * NCF];
    const float* Sb = S + (size_t)b * NHEADS * NCF * NCF;
    for (int e = tid; e < NHEADS * NCF * NCF; e += 256) {
        int h = e / (NCF * NCF);
        int r = e % (NCF * NCF);
        int c = r / NCF, d = r % NCF;
        float rq = sqrtf(Q2[((size_t)b * NHEADS + h) * NCF + c]);
        float rk = sqrtf(K2[((size_t)b * NHEADS + h) * NCF + d]);
        P[e] = Sb[e] / (rq * rk) * temp[h];
    }
    __syncthreads();
    if (tid < NHEADS * NCF) {
        float* row = P + tid * NCF;
        float mx = row[0];
        #pragma unroll
        for (int d = 1; d < NCF; ++d) mx = fmaxf(mx, row[d]);
        float sum = 0.f;
        #pragma unroll
        for (int d = 0; d < NCF; ++d) { float e2 = __expf(row[d] - mx); row[d] = e2; sum += e2; }
        float inv = 1.f / sum;
        #pragma unroll
        for (int d = 0; d < NCF; ++d) row[d] *= inv;
    }
    __syncthreads();
    if (tid < NC) {
        int o = tid;
        float* Mo = M + (size_t)b * NC * NC + (size_t)o * NC;
        for (int h = 0; h < NHEADS; ++h) {
            float pw[NCF];
            #pragma unroll
            for (int c = 0; c < NCF; ++c) pw[c] = projw[(size_t)o * NC + h * NCF + c];
            #pragma unroll
            for (int d = 0; d < NCF; ++d) {
                float acc = 0.f;
                #pragma unroll
                for (int c = 0; c < NCF; ++c) acc = fmaf(pw[c], P[h * (NCF * NCF) + c * NCF + d], acc);
                Mo[h * NCF + d] = acc;
            }
        }
    }
}

// ---------------------------------------------------------------------------
extern "C" void kernel_launch(void* const* d_in, const int* in_sizes, int n_in,
                              void* d_out, int out_size, void* d_ws, size_t ws_size,
                              hipStream_t stream)
{
    const float* x     = (const float*)d_in[0];
    const float* kv    = (const float*)d_in[1];
    const float* ln1w  = (const float*)d_in[2];
    const float* ln1b  = (const float*)d_in[3];
    const float* akern = (const float*)d_in[4];
    const float* qkvw  = (const float*)d_in[5];
    const float* qkvdw = (const float*)d_in[6];
    const float* projw = (const float*)d_in[7];
    const float* temp  = (const float*)d_in[8];
    const float* ln2w  = (const float*)d_in[9];
    const float* ln2b  = (const float*)d_in[10];
    const float* fkern = (const float*)d_in[11];
    const float* pinw  = (const float*)d_in[12];
    const float* ffndw = (const float*)d_in[13];
    const float* poutw = (const float*)d_in[14];
    float* out = (float*)d_out;

    char* wp = (char*)d_ws;
    size_t off = 0;
    auto take = [&](size_t bytes) {
        char* r = wp + off;
        off = (off + bytes + 255) & ~(size_t)255;
        return (float*)r;
    };
    // small fixed buffers (~3.6 MB)
    float* mu1   = take((size_t)NB * NHW * 4);
    float* rstd1 = take((size_t)NB * NHW * 4);
    float* mu2   = take((size_t)NB * NHW * 4);
    float* rstd2 = take((size_t)NB * NHW * 4);
    float* s1 = take(NB * NC * 4);  float* t1 = take(NB * NC * 4);
    float* s2 = take(NB * NC * 4);  float* t2 = take(NB * NC * 4);
    float* uv1 = take(NB * NO_QKV * 4); float* v01 = take(NB * NO_QKV * 4);
    float* uv2 = take(NB * NO_PIN * 4); float* v02 = take(NB * NO_PIN * 4);
    float* Sb  = take((size_t)NB * NHEADS * NCF * NCF * 4);
    float* Q2b = take((size_t)NB * NHEADS * NCF * 4);
    float* K2b = take((size_t)NB * NHEADS * NCF * 4);
    float* Mb  = take((size_t)NB * NC * NC * 4);
    const size_t bigoff = off;

    // per-batch big-buffer footprint (bf16)
    const size_t PB_ATT  = (size_t)NO_QKV * NHW * 2;           // qkv_pre or qkv
    const size_t PB_UPRE = (size_t)NO_PIN * NHW * 2;
    const size_t PB_G    = (size_t)NHID  * NHW * 2;
    const size_t PB_MAX  = PB_UPRE + PB_G;                      // > 2*PB_ATT
    size_t avail = (ws_size > bigoff) ? ws_size - bigoff : 0;
    int CB = 8;
    while (CB > 1 && (size_t)CB * PB_MAX > avail) CB >>= 1;

    dim3 blk(256);

    // FiLM / LN fold coefficients (activation-independent), full batch
    prep_film<<<dim3(3, NB), blk, 0, stream>>>(kv, akern, ln1w, ln1b, qkvw, NO_QKV, s1, t1, uv1, v01);
    prep_film<<<dim3(4, NB), blk, 0, stream>>>(kv, fkern, ln2w, ln2b, pinw, NO_PIN, s2, t2, uv2, v02);

    // zero Gram accumulators (contiguous: Sb | Q2b | K2b)
    {
        int nz = (NB * NHEADS * NCF * NCF) + 2 * (NB * NHEADS * NCF);
        zfill<<<(nz + 255) / 256, blk, 0, stream>>>(Sb, nz);
    }

    for (int b0 = 0; b0 < NB; b0 += CB) {
        const float* xb = x + (size_t)b0 * NC * NHW;
        float* outb = out + (size_t)b0 * NC * NHW;
        float* mu1b = mu1 + (size_t)b0 * NHW;
        float* rs1b = rstd1 + (size_t)b0 * NHW;
        float* mu2b = mu2 + (size_t)b0 * NHW;
        float* rs2b = rstd2 + (size_t)b0 * NHW;
        bfu* qkv_pre = (bfu*)(wp + bigoff);
        bfu* qkvb    = (bfu*)(wp + bigoff + (size_t)CB * PB_ATT);
        bfu* u_pre   = (bfu*)(wp + bigoff);
        bfu* gbuf    = (bfu*)(wp + bigoff + (size_t)CB * PB_UPRE);

        // ---- attention branch ----
        ln_stats<<<CB * 64, blk, 0, stream>>>(xb, mu1b, rs1b, CB);
        gemm_cc<0><<<dim3(256, 9, CB), blk, 0, stream>>>(qkvw, NO_QKV, NC, xb, NC, 0,
            qkv_pre, s1 + (size_t)b0 * NC, mu1b, rs1b,
            uv1 + (size_t)b0 * NO_QKV, v01 + (size_t)b0 * NO_QKV, nullptr);
        dwconv<<<CB * NO_QKV * 8, blk, 0, stream>>>(qkv_pre, qkvdw, qkvb, NO_QKV);
        gram_kernel<<<dim3(8, NHEADS, CB), blk, 0, stream>>>(qkvb,
            Sb + (size_t)b0 * NHEADS * NCF * NCF,
            Q2b + (size_t)b0 * NHEADS * NCF, K2b + (size_t)b0 * NHEADS * NCF);
        attn_fold<<<CB, blk, 0, stream>>>(
            Sb + (size_t)b0 * NHEADS * NCF * NCF,
            Q2b + (size_t)b0 * NHEADS * NCF, K2b + (size_t)b0 * NHEADS * NCF,
            temp, projw, Mb + (size_t)b0 * NC * NC);
        gemm_cc<1><<<dim3(256, 3, CB), blk, 0, stream>>>(Mb + (size_t)b0 * NC * NC, NC, NC,
            qkvb, NO_QKV, 384, outb,
            nullptr, nullptr, nullptr, nullptr, nullptr, xb);

        // ---- FFN branch ----
        ln_stats<<<CB * 64, blk, 0, stream>>>(outb, mu2b, rs2b, CB);
        gemm_cc<0><<<dim3(256, 16, CB), blk, 0, stream>>>(pinw, NO_PIN, NC, outb, NC, 0,
            u_pre, s2 + (size_t)b0 * NC, mu2b, rs2b,
            uv2 + (size_t)b0 * NO_PIN, v02 + (size_t)b0 * NO_PIN, nullptr);
        dwgate<<<CB * NHID * 8, blk, 0, stream>>>(u_pre, ffndw, gbuf);
        gemm_cc<2><<<dim3(256, 3, CB), blk, 0, stream>>>(poutw, NC, NHID,
            gbuf, NHID, 0, outb,
            nullptr, nullptr, nullptr, nullptr, nullptr, outb);
    }
}

// Round 3
// 1685.890 us; speedup vs baseline: 1.6738x; 1.6738x over previous
//
#include <hip/hip_runtime.h>
#include <math.h>

#define NB 8
#define NC 192
#define NHEADS 8
#define NCF 24
#define NHW 16384
#define NWID 128
#define CQKV 576
#define OQKV_PAD 640
#define CPIN 1024
#define CG 512
#define OM_PAD 256

typedef unsigned short bfu;
typedef __bf16 bf16x8 __attribute__((ext_vector_type(8)));
typedef float f32x4 __attribute__((ext_vector_type(4)));

__device__ __forceinline__ float b2f(unsigned short u) { return __uint_as_float(((unsigned)u) << 16); }
__device__ __forceinline__ unsigned short f2b(float f) {
    unsigned u = __float_as_uint(f);
    u += 0x7FFFu + ((u >> 16) & 1u);
    return (unsigned short)(u >> 16);
}
__device__ __forceinline__ float geluf(float v) {
    return 0.5f * v * (1.0f + erff(v * 0.70710678118654752440f));
}

struct F8 { float v[8]; };
__device__ __forceinline__ F8 load8(const bfu* p) {
    uint4 r = *(const uint4*)p;
    F8 o;
    o.v[0] = b2f((unsigned short)(r.x & 0xffff)); o.v[1] = b2f((unsigned short)(r.x >> 16));
    o.v[2] = b2f((unsigned short)(r.y & 0xffff)); o.v[3] = b2f((unsigned short)(r.y >> 16));
    o.v[4] = b2f((unsigned short)(r.z & 0xffff)); o.v[5] = b2f((unsigned short)(r.z >> 16));
    o.v[6] = b2f((unsigned short)(r.w & 0xffff)); o.v[7] = b2f((unsigned short)(r.w >> 16));
    return o;
}
__device__ __forceinline__ void store8(bfu* p, const float* a) {
    uint4 r;
    r.x = (unsigned)f2b(a[0]) | ((unsigned)f2b(a[1]) << 16);
    r.y = (unsigned)f2b(a[2]) | ((unsigned)f2b(a[3]) << 16);
    r.z = (unsigned)f2b(a[4]) | ((unsigned)f2b(a[5]) << 16);
    r.w = (unsigned)f2b(a[6]) | ((unsigned)f2b(a[7]) << 16);
    *(uint4*)p = r;
}

__global__ __launch_bounds__(256) void zfill(float* __restrict__ p, int n) {
    int i = blockIdx.x * 256 + threadIdx.x;
    if (i < n) p[i] = 0.f;
}

// ---------------------------------------------------------------------------
// s[c]=ln_w[c]*m[c]; t[c]=ln_b[c]*m[c]+m[192+c], m = kern @ k_v. grid(NB)
// ---------------------------------------------------------------------------
__global__ __launch_bounds__(256) void prep_film(
    const float* __restrict__ kv, const float* __restrict__ kern,
    const float* __restrict__ lnw, const float* __restrict__ lnb,
    float* __restrict__ sArr, float* __restrict__ tArr)
{
    const int b = blockIdx.x, t = threadIdx.x;
    __shared__ float m[2 * NC];
    const float* kvb = kv + b * 256;
    for (int r = t; r < 2 * NC; r += 256) {
        const float* kr = kern + (size_t)r * 256;
        float acc = 0.f;
        for (int i = 0; i < 256; ++i) acc = fmaf(kvb[i], kr[i], acc);
        m[r] = acc;
    }
    __syncthreads();
    if (t < NC) {
        float ma = m[t], mb2 = m[NC + t];
        sArr[b * NC + t] = lnw[t] * ma;
        tArr[b * NC + t] = lnb[t] * ma + mb2;
    }
}

// ---------------------------------------------------------------------------
// Build bf16 A matrices (scaled, padded, remapped) + u=sum(bf16 A), v0=W@t.
// mode 0: qkv  (Opad 640, src o<576, K=192, scale)
// mode 1: pin  (Opad 1024, split remap 510|2pad|510|2pad, K=192, scale)
// mode 2: pout (Opad 256, src o<192, Kr=510 pad->512, no scale/u/v0)
// ---------------------------------------------------------------------------
__global__ __launch_bounds__(256) void wprep(
    const float* __restrict__ W, const float* __restrict__ sA, const float* __restrict__ tA,
    bfu* __restrict__ Abf, float* __restrict__ u, float* __restrict__ v0, int mode)
{
    const int o = blockIdx.x * 256 + threadIdx.x;
    const int b = blockIdx.y;
    const int Opad = (mode == 0) ? OQKV_PAD : (mode == 1 ? CPIN : OM_PAD);
    if (o >= Opad) return;
    const int K = (mode == 2) ? 512 : 192;
    const int Kr = (mode == 2) ? 510 : 192;
    int src;
    if (mode == 0) src = (o < 576) ? o : -1;
    else if (mode == 1) src = (o < 510) ? o : (o < 512 ? -1 : (o < 1022 ? o - 2 : -1));
    else src = (o < 192) ? o : -1;
    const float* wr = (src >= 0) ? W + (size_t)src * Kr : nullptr;
    const float* sb = sA + b * NC;
    const float* tb = tA + b * NC;
    bfu* arow = Abf + ((size_t)b * Opad + o) * K;
    float au = 0.f, av = 0.f;
    for (int c = 0; c < K; ++c) {
        float a = 0.f;
        if (src >= 0 && c < Kr) {
            float w = wr[c];
            if (mode == 2) a = w;
            else { a = w * sb[c]; av = fmaf(w, tb[c], av); }
        }
        bfu ab = f2b(a);
        arow[c] = ab;
        au += b2f(ab);
    }
    if (mode < 2) {
        u[(size_t)b * Opad + o] = au;
        v0[(size_t)b * Opad + o] = (src >= 0) ? av : 0.f;
    }
}

// transpose dw weights: mode 0: [C][9]->[9][C]; mode 1: ffn remap to [9][1024]
__global__ __launch_bounds__(256) void wdw_prep(
    const float* __restrict__ src, float* __restrict__ dstT, int C, int mode)
{
    int i = blockIdx.x * 256 + threadIdx.x;
    if (i >= 9 * C) return;
    int tap = i / C, col = i % C;
    float v;
    if (mode == 0) v = src[(size_t)col * 9 + tap];
    else {
        if (col < 512) v = (col < 510) ? src[(size_t)col * 9 + tap] : 0.f;
        else { int c2 = col - 512; v = (c2 < 510) ? src[(size_t)(510 + c2) * 9 + tap] : 0.f; }
    }
    dstT[(size_t)tap * C + col] = v;
}

// ---------------------------------------------------------------------------
// LN stats + bf16 convert. CM variant reads channel-major fp32 input;
// PM variant reads pixel-major fp32. Output xbf pixel-major [n][192] bf16.
// ---------------------------------------------------------------------------
__global__ __launch_bounds__(256) void ln_cvt_cm(
    const float* __restrict__ x, float* __restrict__ mu, float* __restrict__ rstd,
    bfu* __restrict__ xbf, int cb)
{
    int idx = blockIdx.x * 256 + threadIdx.x;
    if (idx >= cb * NHW) return;
    int b = idx >> 14, n = idx & (NHW - 1);
    const float* p = x + (size_t)b * NC * NHW + n;
    bfu* orow = xbf + ((size_t)b * NHW + n) * NC;
    float s = 0.f, ss = 0.f;
    for (int c0 = 0; c0 < NC; c0 += 8) {
        float v[8];
        #pragma unroll
        for (int j = 0; j < 8; ++j) {
            v[j] = p[(size_t)(c0 + j) * NHW];
            s += v[j]; ss = fmaf(v[j], v[j], ss);
        }
        store8(orow + c0, v);
    }
    float m = s * (1.f / 192.f);
    float var = ss * (1.f / 192.f) - m * m;
    mu[idx] = m;
    rstd[idx] = rsqrtf(var + 1e-5f);
}

__global__ __launch_bounds__(256) void ln_cvt_pm(
    const float* __restrict__ x, float* __restrict__ mu, float* __restrict__ rstd,
    bfu* __restrict__ xbf, int cb)
{
    int idx = blockIdx.x * 256 + threadIdx.x;
    if (idx >= cb * NHW) return;
    const float* p = x + (size_t)idx * NC;
    bfu* orow = xbf + (size_t)idx * NC;
    float s = 0.f, ss = 0.f;
    for (int c0 = 0; c0 < NC; c0 += 8) {
        float4 v0 = *(const float4*)(p + c0);
        float4 v1 = *(const float4*)(p + c0 + 4);
        float v[8] = {v0.x, v0.y, v0.z, v0.w, v1.x, v1.y, v1.z, v1.w};
        #pragma unroll
        for (int j = 0; j < 8; ++j) { s += v[j]; ss = fmaf(v[j], v[j], ss); }
        store8(orow + c0, v);
    }
    float m = s * (1.f / 192.f);
    float var = ss * (1.f / 192.f) - m * m;
    mu[idx] = m;
    rstd[idx] = rsqrtf(var + 1e-5f);
}

// ---------------------------------------------------------------------------
// MFMA GEMM, pixel-major X: Y[n][o] = epi( sum_k A[o][k] * X[n][k] ).
// Direct global fragment loads (no LDS in main loop); LDS-staged epilogue.
// EPI 0: LN -> bf16 Y; EPI 1: + bf16 res -> f32 Y; EPI 2: + f32 res -> f32 Y.
// block 256 = 4 waves (2x2), tile 128(o) x 128(n). grid (N/128, Opad/128, CB)
// ---------------------------------------------------------------------------
template<int EPI>
__global__ __launch_bounds__(256) void gemm_pm(
    const bfu* __restrict__ A, long aBStride, int Opad, int Oreal, int K,
    const bfu* __restrict__ X, int xRow, int xOff,
    void* __restrict__ Y, int yRow,
    const void* __restrict__ res, int resRow,
    const float* __restrict__ mu, const float* __restrict__ rstd,
    const float* __restrict__ uvec, const float* __restrict__ v0vec, int uStride)
{
    __shared__ bfu stage[128][136];
    const int b = blockIdx.z;
    const int om = blockIdx.y * 128;
    const int n0 = blockIdx.x * 128;
    const int tid = threadIdx.x;
    const int lane = tid & 63, wave = tid >> 6;
    const int wy = wave >> 1, wx = wave & 1;
    const int l15 = lane & 15, kg = lane >> 4;

    const bfu* Ab = A + (size_t)b * aBStride;
    const bfu* Arow[4];
    #pragma unroll
    for (int mf = 0; mf < 4; ++mf)
        Arow[mf] = Ab + (size_t)(om + wy * 64 + mf * 16 + l15) * K + kg * 8;
    const bfu* Xb = X + ((size_t)b * NHW + n0 + wx * 64 + l15) * xRow + xOff + kg * 8;

    f32x4 acc[4][4];
    #pragma unroll
    for (int i = 0; i < 4; ++i)
        #pragma unroll
        for (int j = 0; j < 4; ++j) acc[i][j] = (f32x4){0.f, 0.f, 0.f, 0.f};

    for (int kk = 0; kk < K; kk += 32) {
        bf16x8 af[4], bfr[4];
        #pragma unroll
        for (int mf = 0; mf < 4; ++mf) af[mf] = *(const bf16x8*)(Arow[mf] + kk);
        #pragma unroll
        for (int nf = 0; nf < 4; ++nf) bfr[nf] = *(const bf16x8*)(Xb + (size_t)(nf * 16) * xRow + kk);
        #pragma unroll
        for (int mf = 0; mf < 4; ++mf)
            #pragma unroll
            for (int nf = 0; nf < 4; ++nf)
                acc[mf][nf] = __builtin_amdgcn_mfma_f32_16x16x32_bf16(af[mf], bfr[nf], acc[mf][nf], 0, 0, 0);
    }

    // stage to LDS as [n_local][o_local] bf16
    #pragma unroll
    for (int nf = 0; nf < 4; ++nf) {
        const int nl = wx * 64 + nf * 16 + l15;
        float muv = 0.f, rsv = 0.f;
        if (EPI == 0) {
            muv = mu[(size_t)b * NHW + n0 + nl];
            rsv = rstd[(size_t)b * NHW + n0 + nl];
        }
        #pragma unroll
        for (int mf = 0; mf < 4; ++mf) {
            const int obl = wy * 64 + mf * 16 + kg * 4;
            float r0, r1, r2, r3;
            if (EPI == 0) {
                float4 uv = *(const float4*)(uvec + (size_t)b * uStride + om + obl);
                float4 vv = *(const float4*)(v0vec + (size_t)b * uStride + om + obl);
                r0 = rsv * (acc[mf][nf][0] - muv * uv.x) + vv.x;
                r1 = rsv * (acc[mf][nf][1] - muv * uv.y) + vv.y;
                r2 = rsv * (acc[mf][nf][2] - muv * uv.z) + vv.z;
                r3 = rsv * (acc[mf][nf][3] - muv * uv.w) + vv.w;
            } else {
                r0 = acc[mf][nf][0]; r1 = acc[mf][nf][1];
                r2 = acc[mf][nf][2]; r3 = acc[mf][nf][3];
            }
            ushort4 pk;
            pk.x = f2b(r0); pk.y = f2b(r1); pk.z = f2b(r2); pk.w = f2b(r3);
            *(ushort4*)&stage[nl][obl] = pk;
        }
    }
    __syncthreads();

    // coalesced writeout
    #pragma unroll
    for (int it = 0; it < 8; ++it) {
        int task = it * 256 + tid;
        int nl = task >> 4, ch = task & 15;
        int oc = om + ch * 8;
        if (oc >= Oreal) continue;
        uint4 sv = *(const uint4*)&stage[nl][ch * 8];
        size_t nglob = (size_t)b * NHW + n0 + nl;
        if (EPI == 0) {
            *(uint4*)((bfu*)Y + nglob * yRow + oc) = sv;
        } else {
            float a[8];
            a[0] = b2f((unsigned short)(sv.x & 0xffff)); a[1] = b2f((unsigned short)(sv.x >> 16));
            a[2] = b2f((unsigned short)(sv.y & 0xffff)); a[3] = b2f((unsigned short)(sv.y >> 16));
            a[4] = b2f((unsigned short)(sv.z & 0xffff)); a[5] = b2f((unsigned short)(sv.z >> 16));
            a[6] = b2f((unsigned short)(sv.w & 0xffff)); a[7] = b2f((unsigned short)(sv.w >> 16));
            if (EPI == 1) {
                F8 rv = load8((const bfu*)res + nglob * resRow + oc);
                #pragma unroll
                for (int j = 0; j < 8; ++j) a[j] += rv.v[j];
            } else {
                const float* rp = (const float*)res + nglob * resRow + oc;
                float4 q0 = *(const float4*)rp, q1 = *(const float4*)(rp + 4);
                a[0] += q0.x; a[1] += q0.y; a[2] += q0.z; a[3] += q0.w;
                a[4] += q1.x; a[5] += q1.y; a[6] += q1.z; a[7] += q1.w;
            }
            float* yp = (float*)Y + nglob * yRow + oc;
            *(float4*)yp = make_float4(a[0], a[1], a[2], a[3]);
            *(float4*)(yp + 4) = make_float4(a[4], a[5], a[6], a[7]);
        }
    }
}

// ---------------------------------------------------------------------------
// pixel-major depthwise 3x3 (+ optional GELU gate). thread = 8ch x 1px.
// ---------------------------------------------------------------------------
template<int CIN, int COUT, bool GATE>
__global__ __launch_bounds__(256) void dw_pm(
    const bfu* __restrict__ in, const float* __restrict__ wT, bfu* __restrict__ out, int cb)
{
    const int CHUNKS = COUT / 8;
    int f = blockIdx.x * 256 + threadIdx.x;
    if (f >= cb * NHW * CHUNKS) return;
    int ch = f % CHUNKS;
    int pn = f / CHUNKS;             // b*NHW + n
    int n = pn & (NHW - 1);
    int y = n >> 7, x = n & (NWID - 1);
    const bfu* base = in + (size_t)pn * CIN;
    float a1[8] = {}, a2[8] = {};
    #pragma unroll
    for (int dy = -1; dy <= 1; ++dy) {
        int yy = y + dy;
        if ((unsigned)yy >= (unsigned)NWID) continue;
        #pragma unroll
        for (int dx = -1; dx <= 1; ++dx) {
            int xx = x + dx;
            if ((unsigned)xx >= (unsigned)NWID) continue;
            int tap = (dy + 1) * 3 + dx + 1;
            long off = (long)(dy * NWID + dx) * CIN;
            F8 v1 = load8(base + off + ch * 8);
            const float* w1 = wT + (size_t)tap * CIN + ch * 8;
            float4 wa = *(const float4*)w1, wb = *(const float4*)(w1 + 4);
            float w1v[8] = {wa.x, wa.y, wa.z, wa.w, wb.x, wb.y, wb.z, wb.w};
            #pragma unroll
            for (int j = 0; j < 8; ++j) a1[j] = fmaf(w1v[j], v1.v[j], a1[j]);
            if (GATE) {
                F8 v2 = load8(base + off + 512 + ch * 8);
                const float* w2 = wT + (size_t)tap * CIN + 512 + ch * 8;
                float4 wc = *(const float4*)w2, wd = *(const float4*)(w2 + 4);
                float w2v[8] = {wc.x, wc.y, wc.z, wc.w, wd.x, wd.y, wd.z, wd.w};
                #pragma unroll
                for (int j = 0; j < 8; ++j) a2[j] = fmaf(w2v[j], v2.v[j], a2[j]);
            }
        }
    }
    float r[8];
    if (GATE) {
        #pragma unroll
        for (int j = 0; j < 8; ++j) r[j] = geluf(a1[j]) * a2[j];
    } else {
        #pragma unroll
        for (int j = 0; j < 8; ++j) r[j] = a1[j];
    }
    store8(out + (size_t)pn * COUT + ch * 8, r);
}

// ---------------------------------------------------------------------------
// MFMA Gram: S32[b][h][32][32] += q qT-style products over pixels; diag norms.
// LDS: transposed [c 392][n 64 (u32-paired)] bf16 tile of qkv cols 0..383.
// grid (16 n-chunks, CB). 4 waves x 2 heads each.
// ---------------------------------------------------------------------------
__global__ __launch_bounds__(256) void gram_pm(
    const bfu* __restrict__ qkv, float* __restrict__ S32,
    float* __restrict__ Q2, float* __restrict__ K2, int b0)
{
    __shared__ bfu lds[392 * 72];
    const int b = blockIdx.y;
    const int nc = blockIdx.x;
    const int tid = threadIdx.x;
    const int lane = tid & 63, wave = tid >> 6;
    const int l15 = lane & 15, kg = lane >> 4;

    f32x4 sAcc[2][2][2], qAcc[2][2], kAcc[2][2];
    #pragma unroll
    for (int h = 0; h < 2; ++h)
        #pragma unroll
        for (int i = 0; i < 2; ++i) {
            qAcc[h][i] = (f32x4){0.f, 0.f, 0.f, 0.f};
            kAcc[h][i] = (f32x4){0.f, 0.f, 0.f, 0.f};
            #pragma unroll
            for (int j = 0; j < 2; ++j) sAcc[h][i][j] = (f32x4){0.f, 0.f, 0.f, 0.f};
        }

    const size_t pbase = (size_t)b * NHW + (size_t)nc * 1024;
    unsigned* ldsw = (unsigned*)lds;

    for (int it = 0; it < 16; ++it) {
        const size_t nb = pbase + it * 64;
        #pragma unroll
        for (int i = 0; i < 6; ++i) {
            int task = i * 256 + tid;          // 1536 tasks: 32 n-pairs x 48 chunks
            int np = task & 31, ch = task >> 5;
            const bfu* r0 = qkv + (nb + np * 2) * CQKV + ch * 8;
            uint4 v0 = *(const uint4*)r0;
            uint4 v1 = *(const uint4*)(r0 + CQKV);
            int cb8 = ch * 8;
            ldsw[(cb8 + 0) * 36 + np] = (v0.x & 0xffffu) | (v1.x << 16);
            ldsw[(cb8 + 1) * 36 + np] = (v0.x >> 16) | (v1.x & 0xffff0000u);
            ldsw[(cb8 + 2) * 36 + np] = (v0.y & 0xffffu) | (v1.y << 16);
            ldsw[(cb8 + 3) * 36 + np] = (v0.y >> 16) | (v1.y & 0xffff0000u);
            ldsw[(cb8 + 4) * 36 + np] = (v0.z & 0xffffu) | (v1.z << 16);
            ldsw[(cb8 + 5) * 36 + np] = (v0.z >> 16) | (v1.z & 0xffff0000u);
            ldsw[(cb8 + 6) * 36 + np] = (v0.w & 0xffffu) | (v1.w << 16);
            ldsw[(cb8 + 7) * 36 + np] = (v0.w >> 16) | (v1.w & 0xffff0000u);
        }
        // zero pad rows 384..391
        ldsw[(384 + (tid >> 5)) * 36 + (tid & 31)] = 0;
        __syncthreads();
        #pragma unroll
        for (int hh = 0; hh < 2; ++hh) {
            const int h = wave * 2 + hh;
            const int qr = h * NCF, kr = NC + h * NCF;
            #pragma unroll
            for (int ks = 0; ks < 2; ++ks) {
                const int nsub = ks * 32 + kg * 8;
                bf16x8 aq0 = *(const bf16x8*)(lds + (qr + l15) * 72 + nsub);
                bf16x8 aq1 = *(const bf16x8*)(lds + (qr + 16 + l15) * 72 + nsub);
                bf16x8 bk0 = *(const bf16x8*)(lds + (kr + l15) * 72 + nsub);
                bf16x8 bk1 = *(const bf16x8*)(lds + (kr + 16 + l15) * 72 + nsub);
                sAcc[hh][0][0] = __builtin_amdgcn_mfma_f32_16x16x32_bf16(aq0, bk0, sAcc[hh][0][0], 0, 0, 0);
                sAcc[hh][0][1] = __builtin_amdgcn_mfma_f32_16x16x32_bf16(aq0, bk1, sAcc[hh][0][1], 0, 0, 0);
                sAcc[hh][1][0] = __builtin_amdgcn_mfma_f32_16x16x32_bf16(aq1, bk0, sAcc[hh][1][0], 0, 0, 0);
                sAcc[hh][1][1] = __builtin_amdgcn_mfma_f32_16x16x32_bf16(aq1, bk1, sAcc[hh][1][1], 0, 0, 0);
                qAcc[hh][0] = __builtin_amdgcn_mfma_f32_16x16x32_bf16(aq0, aq0, qAcc[hh][0], 0, 0, 0);
                qAcc[hh][1] = __builtin_amdgcn_mfma_f32_16x16x32_bf16(aq1, aq1, qAcc[hh][1], 0, 0, 0);
                kAcc[hh][0] = __builtin_amdgcn_mfma_f32_16x16x32_bf16(bk0, bk0, kAcc[hh][0], 0, 0, 0);
                kAcc[hh][1] = __builtin_amdgcn_mfma_f32_16x16x32_bf16(bk1, bk1, kAcc[hh][1], 0, 0, 0);
            }
        }
        __syncthreads();
    }

    const int gb = b0 + b;
    #pragma unroll
    for (int hh = 0; hh < 2; ++hh) {
        const int h = wave * 2 + hh;
        float* Sp = S32 + ((size_t)gb * NHEADS + h) * 1024;
        #pragma unroll
        for (int mt = 0; mt < 2; ++mt)
            #pragma unroll
            for (int nt = 0; nt < 2; ++nt)
                #pragma unroll
                for (int r = 0; r < 4; ++r) {
                    int c = mt * 16 + kg * 4 + r, d = nt * 16 + l15;
                    atomicAdd(&Sp[c * 32 + d], sAcc[hh][mt][nt][r]);
                }
        #pragma unroll
        for (int t = 0; t < 2; ++t)
            #pragma unroll
            for (int r = 0; r < 4; ++r) {
                int row = t * 16 + kg * 4 + r, col = t * 16 + l15;
                if (row == col && row < NCF) {
                    atomicAdd(&Q2[((size_t)gb * NHEADS + h) * NCF + row], qAcc[hh][t][r]);
                    atomicAdd(&K2[((size_t)gb * NHEADS + h) * NCF + row], kAcc[hh][t][r]);
                }
            }
    }
}

// ---------------------------------------------------------------------------
// normalize -> softmax -> fold proj_w -> Mbf [b][256pad][192] bf16. grid(CB)
// ---------------------------------------------------------------------------
__global__ __launch_bounds__(256) void attn_fold(
    const float* __restrict__ S32, const float* __restrict__ Q2, const float* __restrict__ K2,
    const float* __restrict__ temp, const float* __restrict__ projw, bfu* __restrict__ Mbf, int b0)
{
    const int gb = b0 + blockIdx.x, tid = threadIdx.x;
    __shared__ float P[NHEADS * NCF * NCF];
    for (int e = tid; e < NHEADS * NCF * NCF; e += 256) {
        int h = e / (NCF * NCF);
        int r = e % (NCF * NCF);
        int c = r / NCF, d = r % NCF;
        float sv = S32[((size_t)gb * NHEADS + h) * 1024 + c * 32 + d];
        float rq = sqrtf(Q2[((size_t)gb * NHEADS + h) * NCF + c]);
        float rk = sqrtf(K2[((size_t)gb * NHEADS + h) * NCF + d]);
        P[e] = sv / (rq * rk) * temp[h];
    }
    __syncthreads();
    if (tid < NHEADS * NCF) {
        int h = tid / NCF, c = tid % NCF;
        float* row = P + h * (NCF * NCF) + c * NCF;
        float mx = row[0];
        #pragma unroll
        for (int d = 1; d < NCF; ++d) mx = fmaxf(mx, row[d]);
        float sum = 0.f;
        #pragma unroll
        for (int d = 0; d < NCF; ++d) { float e2 = __expf(row[d] - mx); row[d] = e2; sum += e2; }
        float inv = 1.f / sum;
        #pragma unroll
        for (int d = 0; d < NCF; ++d) row[d] *= inv;
    }
    __syncthreads();
    bfu* Mb = Mbf + (size_t)gb * OM_PAD * NC;
    if (tid < NC) {
        int o = tid;
        for (int h = 0; h < NHEADS; ++h) {
            float pw[NCF];
            #pragma unroll
            for (int c = 0; c < NCF; ++c) pw[c] = projw[(size_t)o * NC + h * NCF + c];
            #pragma unroll
            for (int d = 0; d < NCF; ++d) {
                float acc = 0.f;
                #pragma unroll
                for (int c = 0; c < NCF; ++c) acc = fmaf(pw[c], P[h * (NCF * NCF) + c * NCF + d], acc);
                Mb[(size_t)o * NC + h * NCF + d] = f2b(acc);
            }
        }
    }
    for (int e = tid; e < (OM_PAD - NC) * NC; e += 256) Mb[NC * NC + e] = 0;
}

// ---------------------------------------------------------------------------
// final: out2 pixel-major [n][192] f32 -> d_out channel-major [192][n]
// ---------------------------------------------------------------------------
__global__ __launch_bounds__(256) void transpose_out(
    const float* __restrict__ src, float* __restrict__ dst, int cb)
{
    __shared__ float t[64][196];
    const int nb = blockIdx.x;      // 256 tiles of 64 px
    const int b = blockIdx.y;
    const int tid = threadIdx.x;
    #pragma unroll
    for (int i = 0; i < 12; ++i) {
        int task = i * 256 + tid;    // 3072 = 64 rows x 48 float4
        int nl = task / 48, ch = task % 48;
        float4 v = *(const float4*)(src + ((size_t)b * NHW + nb * 64 + nl) * NC + ch * 4);
        *(float4*)&t[nl][ch * 4] = v;
    }
    __syncthreads();
    #pragma unroll
    for (int i = 0; i < 12; ++i) {
        int task = i * 256 + tid;    // 3072 = 192 c x 16 n-chunks
        int c = task / 16, nch = task % 16;
        float4 v = make_float4(t[nch * 4 + 0][c], t[nch * 4 + 1][c], t[nch * 4 + 2][c], t[nch * 4 + 3][c]);
        *(float4*)(dst + ((size_t)b * NC + c) * NHW + nb * 64 + nch * 4) = v;
    }
}

// ---------------------------------------------------------------------------
extern "C" void kernel_launch(void* const* d_in, const int* in_sizes, int n_in,
                              void* d_out, int out_size, void* d_ws, size_t ws_size,
                              hipStream_t stream)
{
    const float* x     = (const float*)d_in[0];
    const float* kv    = (const float*)d_in[1];
    const float* ln1w  = (const float*)d_in[2];
    const float* ln1b  = (const float*)d_in[3];
    const float* akern = (const float*)d_in[4];
    const float* qkvw  = (const float*)d_in[5];
    const float* qkvdw = (const float*)d_in[6];
    const float* projw = (const float*)d_in[7];
    const float* temp  = (const float*)d_in[8];
    const float* ln2w  = (const float*)d_in[9];
    const float* ln2b  = (const float*)d_in[10];
    const float* fkern = (const float*)d_in[11];
    const float* pinw  = (const float*)d_in[12];
    const float* ffndw = (const float*)d_in[13];
    const float* poutw = (const float*)d_in[14];
    float* out = (float*)d_out;

    char* wp = (char*)d_ws;
    size_t off = 0;
    auto take = [&](size_t bytes) {
        char* r = wp + off;
        off = (off + bytes + 255) & ~(size_t)255;
        return r;
    };
    float* mu1   = (float*)take((size_t)NB * NHW * 4);
    float* rstd1 = (float*)take((size_t)NB * NHW * 4);
    float* mu2   = (float*)take((size_t)NB * NHW * 4);
    float* rstd2 = (float*)take((size_t)NB * NHW * 4);
    float* s1 = (float*)take(NB * NC * 4);  float* t1 = (float*)take(NB * NC * 4);
    float* s2 = (float*)take(NB * NC * 4);  float* t2 = (float*)take(NB * NC * 4);
    bfu* A1 = (bfu*)take((size_t)NB * OQKV_PAD * 192 * 2);
    bfu* A2 = (bfu*)take((size_t)NB * CPIN * 192 * 2);
    bfu* A3 = (bfu*)take((size_t)OM_PAD * 512 * 2);
    bfu* Mbf = (bfu*)take((size_t)NB * OM_PAD * NC * 2);
    float* u1  = (float*)take((size_t)NB * OQKV_PAD * 4);
    float* v01 = (float*)take((size_t)NB * OQKV_PAD * 4);
    float* u2  = (float*)take((size_t)NB * CPIN * 4);
    float* v02 = (float*)take((size_t)NB * CPIN * 4);
    float* wdwT1 = (float*)take(9 * CQKV * 4);
    float* wdwT2 = (float*)take(9 * CPIN * 4);
    float* S32 = (float*)take((size_t)NB * NHEADS * 1024 * 4);
    float* Q2  = (float*)take((size_t)NB * NHEADS * NCF * 4);
    float* K2  = (float*)take((size_t)NB * NHEADS * NCF * 4);
    const size_t bigoff = off;

    // per-batch big buffers (pixel-major): out1(768B) bfX(384B) big1(2048B) big2(1152B)
    const size_t PB = (size_t)NHW * (768 + 384 + 2048 + 1152);
    size_t avail = (ws_size > bigoff) ? ws_size - bigoff : 0;
    int CB = 8;
    while (CB > 1 && (size_t)CB * PB > avail) CB >>= 1;

    dim3 blk(256);

    prep_film<<<NB, blk, 0, stream>>>(kv, akern, ln1w, ln1b, s1, t1);
    prep_film<<<NB, blk, 0, stream>>>(kv, fkern, ln2w, ln2b, s2, t2);
    wprep<<<dim3(3, NB), blk, 0, stream>>>(qkvw, s1, t1, A1, u1, v01, 0);
    wprep<<<dim3(4, NB), blk, 0, stream>>>(pinw, s2, t2, A2, u2, v02, 1);
    wprep<<<dim3(1, 1), blk, 0, stream>>>(poutw, s1, t1, A3, nullptr, nullptr, 2);
    wdw_prep<<<(9 * CQKV + 255) / 256, blk, 0, stream>>>(qkvdw, wdwT1, CQKV, 0);
    wdw_prep<<<(9 * CPIN + 255) / 256, blk, 0, stream>>>(ffndw, wdwT2, CPIN, 1);
    {
        int nz = NB * NHEADS * 1024 + 2 * NB * NHEADS * NCF + 256;
        zfill<<<(nz + 255) / 256, blk, 0, stream>>>(S32, nz);
    }

    for (int b0 = 0; b0 < NB; b0 += CB) {
        float* out1 = (float*)(wp + bigoff);
        bfu* bfX   = (bfu*)(wp + bigoff + (size_t)CB * NHW * 768);
        char* big1 = wp + bigoff + (size_t)CB * NHW * (768 + 384);
        char* big2 = big1 + (size_t)CB * NHW * 2048;
        bfu* qkv_pre = (bfu*)big1;
        bfu* qkvb    = (bfu*)big2;
        bfu* u_pre   = (bfu*)big1;
        bfu* gbuf    = (bfu*)big2;
        float* out2  = (float*)big1;

        const float* xb = x + (size_t)b0 * NC * NHW;
        float* mu1b = mu1 + (size_t)b0 * NHW;   float* rs1b = rstd1 + (size_t)b0 * NHW;
        float* mu2b = mu2 + (size_t)b0 * NHW;   float* rs2b = rstd2 + (size_t)b0 * NHW;

        // ---- attention branch ----
        ln_cvt_cm<<<CB * 64, blk, 0, stream>>>(xb, mu1b, rs1b, bfX, CB);
        gemm_pm<0><<<dim3(128, OQKV_PAD / 128, CB), blk, 0, stream>>>(
            A1 + (size_t)b0 * OQKV_PAD * 192, (long)OQKV_PAD * 192, OQKV_PAD, CQKV, 192,
            bfX, NC, 0, qkv_pre, CQKV, nullptr, 0,
            mu1b, rs1b, u1 + (size_t)b0 * OQKV_PAD, v01 + (size_t)b0 * OQKV_PAD, OQKV_PAD);
        dw_pm<CQKV, CQKV, false><<<CB * 4608, blk, 0, stream>>>(qkv_pre, wdwT1, qkvb, CB);
        gram_pm<<<dim3(16, CB), blk, 0, stream>>>(qkvb, S32, Q2, K2, b0);
        attn_fold<<<CB, blk, 0, stream>>>(S32, Q2, K2, temp, projw, Mbf, b0);
        gemm_pm<1><<<dim3(128, OM_PAD / 128, CB), blk, 0, stream>>>(
            Mbf + (size_t)b0 * OM_PAD * NC, (long)OM_PAD * NC, OM_PAD, NC, 192,
            qkvb, CQKV, 384, out1, NC, bfX, NC,
            nullptr, nullptr, nullptr, nullptr, 0);

        // ---- FFN branch ----
        ln_cvt_pm<<<CB * 64, blk, 0, stream>>>(out1, mu2b, rs2b, bfX, CB);
        gemm_pm<0><<<dim3(128, CPIN / 128, CB), blk, 0, stream>>>(
            A2 + (size_t)b0 * CPIN * 192, (long)CPIN * 192, CPIN, CPIN, 192,
            bfX, NC, 0, u_pre, CPIN, nullptr, 0,
            mu2b, rs2b, u2 + (size_t)b0 * CPIN, v02 + (size_t)b0 * CPIN, CPIN);
        dw_pm<CPIN, CG, true><<<CB * 4096, blk, 0, stream>>>(u_pre, wdwT2, gbuf, CB);
        gemm_pm<2><<<dim3(128, OM_PAD / 128, CB), blk, 0, stream>>>(
            A3, 0, OM_PAD, NC, 512,
            gbuf, CG, 0, out2, NC, out1, NC,
            nullptr, nullptr, nullptr, nullptr, 0);
        transpose_out<<<dim3(256, CB), blk, 0, stream>>>(out2, out + (size_t)b0 * NC * NHW, CB);
    }
}

// Round 4
// 1275.125 us; speedup vs baseline: 2.2130x; 1.3221x over previous
//
#include <hip/hip_runtime.h>
#include <math.h>

#define NB 8
#define NC 192
#define NHEADS 8
#define NCF 24
#define NHW 16384
#define NWID 128
#define CQKV 576
#define OQKV_PAD 640
#define CPIN 1024
#define CG 512
#define OM_PAD 256

typedef unsigned short bfu;
typedef __bf16 bf16x8 __attribute__((ext_vector_type(8)));
typedef float f32x4 __attribute__((ext_vector_type(4)));

__device__ __forceinline__ float b2f(unsigned short u) { return __uint_as_float(((unsigned)u) << 16); }
__device__ __forceinline__ unsigned short f2b(float f) {
    unsigned u = __float_as_uint(f);
    u += 0x7FFFu + ((u >> 16) & 1u);
    return (unsigned short)(u >> 16);
}
__device__ __forceinline__ float geluf(float v) {
    return 0.5f * v * (1.0f + erff(v * 0.70710678118654752440f));
}

struct F8 { float v[8]; };
__device__ __forceinline__ F8 load8(const bfu* p) {
    uint4 r = *(const uint4*)p;
    F8 o;
    o.v[0] = b2f((unsigned short)(r.x & 0xffff)); o.v[1] = b2f((unsigned short)(r.x >> 16));
    o.v[2] = b2f((unsigned short)(r.y & 0xffff)); o.v[3] = b2f((unsigned short)(r.y >> 16));
    o.v[4] = b2f((unsigned short)(r.z & 0xffff)); o.v[5] = b2f((unsigned short)(r.z >> 16));
    o.v[6] = b2f((unsigned short)(r.w & 0xffff)); o.v[7] = b2f((unsigned short)(r.w >> 16));
    return o;
}
__device__ __forceinline__ void store8(bfu* p, const float* a) {
    uint4 r;
    r.x = (unsigned)f2b(a[0]) | ((unsigned)f2b(a[1]) << 16);
    r.y = (unsigned)f2b(a[2]) | ((unsigned)f2b(a[3]) << 16);
    r.z = (unsigned)f2b(a[4]) | ((unsigned)f2b(a[5]) << 16);
    r.w = (unsigned)f2b(a[6]) | ((unsigned)f2b(a[7]) << 16);
    *(uint4*)p = r;
}

__global__ __launch_bounds__(256) void zfill(float* __restrict__ p, int n) {
    int i = blockIdx.x * 256 + threadIdx.x;
    if (i < n) p[i] = 0.f;
}

// ---------------------------------------------------------------------------
// prep_film, wave-parallel: wave handles channel r; computes both dot
// products kern[r].kv and kern[r+192].kv via 64x4 lane loads + shfl reduce.
// grid (48, NB) x 256 threads (4 waves) -> 192 channels.
// ---------------------------------------------------------------------------
__global__ __launch_bounds__(256) void prep_film(
    const float* __restrict__ kv, const float* __restrict__ kern,
    const float* __restrict__ lnw, const float* __restrict__ lnb,
    float* __restrict__ sArr, float* __restrict__ tArr)
{
    const int b = blockIdx.y;
    const int wave = threadIdx.x >> 6, lane = threadIdx.x & 63;
    const int r = blockIdx.x * 4 + wave;           // 0..191
    const float* kvb = kv + b * 256;
    float4 kvv = *(const float4*)(kvb + lane * 4);
    float4 k1 = *(const float4*)(kern + (size_t)r * 256 + lane * 4);
    float4 k2 = *(const float4*)(kern + (size_t)(r + NC) * 256 + lane * 4);
    float d1 = kvv.x * k1.x + kvv.y * k1.y + kvv.z * k1.z + kvv.w * k1.w;
    float d2 = kvv.x * k2.x + kvv.y * k2.y + kvv.z * k2.z + kvv.w * k2.w;
    #pragma unroll
    for (int off = 32; off; off >>= 1) {
        d1 += __shfl_down(d1, off, 64);
        d2 += __shfl_down(d2, off, 64);
    }
    if (lane == 0) {
        sArr[b * NC + r] = lnw[r] * d1;
        tArr[b * NC + r] = lnb[r] * d1 + d2;
    }
}

// ---------------------------------------------------------------------------
// Build bf16 A matrices (scaled, padded, remapped) + u=sum(bf16 A), v0=W@t.
// Wave-per-row: lane l handles c = 4l..4l+3 (looped for K>256).
// mode 0: qkv  (Opad 640, src o<576, K=192, scale)
// mode 1: pin  (Opad 1024, split remap 510|2pad|510|2pad, K=192, scale)
// mode 2: pout (Opad 256, src o<192, Kr=510 pad->512, no scale/u/v0)
// grid (Opad/4, NBatch) x 256 threads.
// ---------------------------------------------------------------------------
__global__ __launch_bounds__(256) void wprep(
    const float* __restrict__ W, const float* __restrict__ sA, const float* __restrict__ tA,
    bfu* __restrict__ Abf, float* __restrict__ u, float* __restrict__ v0, int mode)
{
    const int wave = threadIdx.x >> 6, lane = threadIdx.x & 63;
    const int o = blockIdx.x * 4 + wave;
    const int b = blockIdx.y;
    const int Opad = (mode == 0) ? OQKV_PAD : (mode == 1 ? CPIN : OM_PAD);
    const int K = (mode == 2) ? 512 : 192;
    const int Kr = (mode == 2) ? 510 : 192;
    int src;
    if (mode == 0) src = (o < 576) ? o : -1;
    else if (mode == 1) src = (o < 510) ? o : (o < 512 ? -1 : (o < 1022 ? o - 2 : -1));
    else src = (o < 192) ? o : -1;
    const float* wr = (src >= 0) ? W + (size_t)src * Kr : nullptr;
    const float* sb = sA + b * NC;
    const float* tb = tA + b * NC;
    bfu* arow = Abf + ((size_t)b * Opad + o) * K;
    float au = 0.f, av = 0.f;
    for (int c0 = lane * 4; c0 < K; c0 += 256) {
        float a[4] = {0.f, 0.f, 0.f, 0.f};
        if (src >= 0) {
            #pragma unroll
            for (int j = 0; j < 4; ++j) {
                int c = c0 + j;
                if (c < Kr) {
                    float w = wr[c];
                    if (mode == 2) a[j] = w;
                    else { a[j] = w * sb[c]; av = fmaf(w, tb[c], av); }
                }
            }
        }
        ushort4 pk;
        bfu b0 = f2b(a[0]), b1 = f2b(a[1]), b2 = f2b(a[2]), b3 = f2b(a[3]);
        pk.x = b0; pk.y = b1; pk.z = b2; pk.w = b3;
        au += b2f(b0) + b2f(b1) + b2f(b2) + b2f(b3);
        *(ushort4*)(arow + c0) = pk;
    }
    if (mode < 2) {
        #pragma unroll
        for (int off = 32; off; off >>= 1) {
            au += __shfl_down(au, off, 64);
            av += __shfl_down(av, off, 64);
        }
        if (lane == 0) {
            u[(size_t)b * Opad + o] = au;
            v0[(size_t)b * Opad + o] = (src >= 0) ? av : 0.f;
        }
    }
}

// transpose dw weights: mode 0: [C][9]->[9][C]; mode 1: ffn remap to [9][1024]
__global__ __launch_bounds__(256) void wdw_prep(
    const float* __restrict__ src, float* __restrict__ dstT, int C, int mode)
{
    int i = blockIdx.x * 256 + threadIdx.x;
    if (i >= 9 * C) return;
    int tap = i / C, col = i % C;
    float v;
    if (mode == 0) v = src[(size_t)col * 9 + tap];
    else {
        if (col < 512) v = (col < 510) ? src[(size_t)col * 9 + tap] : 0.f;
        else { int c2 = col - 512; v = (c2 < 510) ? src[(size_t)(510 + c2) * 9 + tap] : 0.f; }
    }
    dstT[(size_t)tap * C + col] = v;
}

// ---------------------------------------------------------------------------
// LN stats + bf16 convert. CM variant reads channel-major fp32 input;
// PM variant reads pixel-major fp32. Output xbf pixel-major [n][192] bf16.
// ---------------------------------------------------------------------------
__global__ __launch_bounds__(256) void ln_cvt_cm(
    const float* __restrict__ x, float* __restrict__ mu, float* __restrict__ rstd,
    bfu* __restrict__ xbf, int cb)
{
    int idx = blockIdx.x * 256 + threadIdx.x;
    if (idx >= cb * NHW) return;
    int b = idx >> 14, n = idx & (NHW - 1);
    const float* p = x + (size_t)b * NC * NHW + n;
    bfu* orow = xbf + ((size_t)b * NHW + n) * NC;
    float s = 0.f, ss = 0.f;
    for (int c0 = 0; c0 < NC; c0 += 8) {
        float v[8];
        #pragma unroll
        for (int j = 0; j < 8; ++j) {
            v[j] = p[(size_t)(c0 + j) * NHW];
            s += v[j]; ss = fmaf(v[j], v[j], ss);
        }
        store8(orow + c0, v);
    }
    float m = s * (1.f / 192.f);
    float var = ss * (1.f / 192.f) - m * m;
    mu[idx] = m;
    rstd[idx] = rsqrtf(var + 1e-5f);
}

__global__ __launch_bounds__(256) void ln_cvt_pm(
    const float* __restrict__ x, float* __restrict__ mu, float* __restrict__ rstd,
    bfu* __restrict__ xbf, int cb)
{
    int idx = blockIdx.x * 256 + threadIdx.x;
    if (idx >= cb * NHW) return;
    const float* p = x + (size_t)idx * NC;
    bfu* orow = xbf + (size_t)idx * NC;
    float s = 0.f, ss = 0.f;
    for (int c0 = 0; c0 < NC; c0 += 8) {
        float4 v0 = *(const float4*)(p + c0);
        float4 v1 = *(const float4*)(p + c0 + 4);
        float v[8] = {v0.x, v0.y, v0.z, v0.w, v1.x, v1.y, v1.z, v1.w};
        #pragma unroll
        for (int j = 0; j < 8; ++j) { s += v[j]; ss = fmaf(v[j], v[j], ss); }
        store8(orow + c0, v);
    }
    float m = s * (1.f / 192.f);
    float var = ss * (1.f / 192.f) - m * m;
    mu[idx] = m;
    rstd[idx] = rsqrtf(var + 1e-5f);
}

// ---------------------------------------------------------------------------
// MFMA GEMM, pixel-major X: Y[n][o] = epi( sum_k A[o][k] * X[n][k] ).
// Direct global fragment loads (no LDS in main loop); LDS-staged epilogue.
// EPI 0: LN -> bf16 Y; EPI 1: + bf16 res -> f32 Y; EPI 2: + f32 res -> f32 Y.
// block 256 = 4 waves (2x2), tile 128(o) x 128(n). grid (N/128, Opad/128, CB)
// ---------------------------------------------------------------------------
template<int EPI>
__global__ __launch_bounds__(256) void gemm_pm(
    const bfu* __restrict__ A, long aBStride, int Opad, int Oreal, int K,
    const bfu* __restrict__ X, int xRow, int xOff,
    void* __restrict__ Y, int yRow,
    const void* __restrict__ res, int resRow,
    const float* __restrict__ mu, const float* __restrict__ rstd,
    const float* __restrict__ uvec, const float* __restrict__ v0vec, int uStride)
{
    __shared__ bfu stage[128][136];
    const int b = blockIdx.z;
    const int om = blockIdx.y * 128;
    const int n0 = blockIdx.x * 128;
    const int tid = threadIdx.x;
    const int lane = tid & 63, wave = tid >> 6;
    const int wy = wave >> 1, wx = wave & 1;
    const int l15 = lane & 15, kg = lane >> 4;

    const bfu* Ab = A + (size_t)b * aBStride;
    const bfu* Arow[4];
    #pragma unroll
    for (int mf = 0; mf < 4; ++mf)
        Arow[mf] = Ab + (size_t)(om + wy * 64 + mf * 16 + l15) * K + kg * 8;
    const bfu* Xb = X + ((size_t)b * NHW + n0 + wx * 64 + l15) * xRow + xOff + kg * 8;

    f32x4 acc[4][4];
    #pragma unroll
    for (int i = 0; i < 4; ++i)
        #pragma unroll
        for (int j = 0; j < 4; ++j) acc[i][j] = (f32x4){0.f, 0.f, 0.f, 0.f};

    for (int kk = 0; kk < K; kk += 32) {
        bf16x8 af[4], bfr[4];
        #pragma unroll
        for (int mf = 0; mf < 4; ++mf) af[mf] = *(const bf16x8*)(Arow[mf] + kk);
        #pragma unroll
        for (int nf = 0; nf < 4; ++nf) bfr[nf] = *(const bf16x8*)(Xb + (size_t)(nf * 16) * xRow + kk);
        #pragma unroll
        for (int mf = 0; mf < 4; ++mf)
            #pragma unroll
            for (int nf = 0; nf < 4; ++nf)
                acc[mf][nf] = __builtin_amdgcn_mfma_f32_16x16x32_bf16(af[mf], bfr[nf], acc[mf][nf], 0, 0, 0);
    }

    // stage to LDS as [n_local][o_local] bf16
    #pragma unroll
    for (int nf = 0; nf < 4; ++nf) {
        const int nl = wx * 64 + nf * 16 + l15;
        float muv = 0.f, rsv = 0.f;
        if (EPI == 0) {
            muv = mu[(size_t)b * NHW + n0 + nl];
            rsv = rstd[(size_t)b * NHW + n0 + nl];
        }
        #pragma unroll
        for (int mf = 0; mf < 4; ++mf) {
            const int obl = wy * 64 + mf * 16 + kg * 4;
            float r0, r1, r2, r3;
            if (EPI == 0) {
                float4 uv = *(const float4*)(uvec + (size_t)b * uStride + om + obl);
                float4 vv = *(const float4*)(v0vec + (size_t)b * uStride + om + obl);
                r0 = rsv * (acc[mf][nf][0] - muv * uv.x) + vv.x;
                r1 = rsv * (acc[mf][nf][1] - muv * uv.y) + vv.y;
                r2 = rsv * (acc[mf][nf][2] - muv * uv.z) + vv.z;
                r3 = rsv * (acc[mf][nf][3] - muv * uv.w) + vv.w;
            } else {
                r0 = acc[mf][nf][0]; r1 = acc[mf][nf][1];
                r2 = acc[mf][nf][2]; r3 = acc[mf][nf][3];
            }
            ushort4 pk;
            pk.x = f2b(r0); pk.y = f2b(r1); pk.z = f2b(r2); pk.w = f2b(r3);
            *(ushort4*)&stage[nl][obl] = pk;
        }
    }
    __syncthreads();

    // coalesced writeout
    #pragma unroll
    for (int it = 0; it < 8; ++it) {
        int task = it * 256 + tid;
        int nl = task >> 4, ch = task & 15;
        int oc = om + ch * 8;
        if (oc >= Oreal) continue;
        uint4 sv = *(const uint4*)&stage[nl][ch * 8];
        size_t nglob = (size_t)b * NHW + n0 + nl;
        if (EPI == 0) {
            *(uint4*)((bfu*)Y + nglob * yRow + oc) = sv;
        } else {
            float a[8];
            a[0] = b2f((unsigned short)(sv.x & 0xffff)); a[1] = b2f((unsigned short)(sv.x >> 16));
            a[2] = b2f((unsigned short)(sv.y & 0xffff)); a[3] = b2f((unsigned short)(sv.y >> 16));
            a[4] = b2f((unsigned short)(sv.z & 0xffff)); a[5] = b2f((unsigned short)(sv.z >> 16));
            a[6] = b2f((unsigned short)(sv.w & 0xffff)); a[7] = b2f((unsigned short)(sv.w >> 16));
            if (EPI == 1) {
                F8 rv = load8((const bfu*)res + nglob * resRow + oc);
                #pragma unroll
                for (int j = 0; j < 8; ++j) a[j] += rv.v[j];
            } else {
                const float* rp = (const float*)res + nglob * resRow + oc;
                float4 q0 = *(const float4*)rp, q1 = *(const float4*)(rp + 4);
                a[0] += q0.x; a[1] += q0.y; a[2] += q0.z; a[3] += q0.w;
                a[4] += q1.x; a[5] += q1.y; a[6] += q1.z; a[7] += q1.w;
            }
            float* yp = (float*)Y + nglob * yRow + oc;
            *(float4*)yp = make_float4(a[0], a[1], a[2], a[3]);
            *(float4*)(yp + 4) = make_float4(a[4], a[5], a[6], a[7]);
        }
    }
}

// ---------------------------------------------------------------------------
// pixel-major depthwise 3x3 (+ optional GELU gate). thread = 8ch x 1px.
// ---------------------------------------------------------------------------
template<int CIN, int COUT, bool GATE>
__global__ __launch_bounds__(256) void dw_pm(
    const bfu* __restrict__ in, const float* __restrict__ wT, bfu* __restrict__ out, int cb)
{
    const int CHUNKS = COUT / 8;
    int f = blockIdx.x * 256 + threadIdx.x;
    if (f >= cb * NHW * CHUNKS) return;
    int ch = f % CHUNKS;
    int pn = f / CHUNKS;             // b*NHW + n
    int n = pn & (NHW - 1);
    int y = n >> 7, x = n & (NWID - 1);
    const bfu* base = in + (size_t)pn * CIN;
    float a1[8] = {}, a2[8] = {};
    #pragma unroll
    for (int dy = -1; dy <= 1; ++dy) {
        int yy = y + dy;
        if ((unsigned)yy >= (unsigned)NWID) continue;
        #pragma unroll
        for (int dx = -1; dx <= 1; ++dx) {
            int xx = x + dx;
            if ((unsigned)xx >= (unsigned)NWID) continue;
            int tap = (dy + 1) * 3 + dx + 1;
            long off = (long)(dy * NWID + dx) * CIN;
            F8 v1 = load8(base + off + ch * 8);
            const float* w1 = wT + (size_t)tap * CIN + ch * 8;
            float4 wa = *(const float4*)w1, wb = *(const float4*)(w1 + 4);
            float w1v[8] = {wa.x, wa.y, wa.z, wa.w, wb.x, wb.y, wb.z, wb.w};
            #pragma unroll
            for (int j = 0; j < 8; ++j) a1[j] = fmaf(w1v[j], v1.v[j], a1[j]);
            if (GATE) {
                F8 v2 = load8(base + off + 512 + ch * 8);
                const float* w2 = wT + (size_t)tap * CIN + 512 + ch * 8;
                float4 wc = *(const float4*)w2, wd = *(const float4*)(w2 + 4);
                float w2v[8] = {wc.x, wc.y, wc.z, wc.w, wd.x, wd.y, wd.z, wd.w};
                #pragma unroll
                for (int j = 0; j < 8; ++j) a2[j] = fmaf(w2v[j], v2.v[j], a2[j]);
            }
        }
    }
    float r[8];
    if (GATE) {
        #pragma unroll
        for (int j = 0; j < 8; ++j) r[j] = geluf(a1[j]) * a2[j];
    } else {
        #pragma unroll
        for (int j = 0; j < 8; ++j) r[j] = a1[j];
    }
    store8(out + (size_t)pn * COUT + ch * 8, r);
}

// ---------------------------------------------------------------------------
// MFMA Gram: S32[b][h][32][32] += q qT-style products over pixels; diag norms.
// LDS: transposed [c 392][n 64 (u32-paired)] bf16 tile of qkv cols 0..383.
// grid (16 n-chunks, CB). 4 waves x 2 heads each.
// ---------------------------------------------------------------------------
__global__ __launch_bounds__(256) void gram_pm(
    const bfu* __restrict__ qkv, float* __restrict__ S32,
    float* __restrict__ Q2, float* __restrict__ K2, int b0)
{
    __shared__ bfu lds[392 * 72];
    const int b = blockIdx.y;
    const int nc = blockIdx.x;
    const int tid = threadIdx.x;
    const int lane = tid & 63, wave = tid >> 6;
    const int l15 = lane & 15, kg = lane >> 4;

    f32x4 sAcc[2][2][2], qAcc[2][2], kAcc[2][2];
    #pragma unroll
    for (int h = 0; h < 2; ++h)
        #pragma unroll
        for (int i = 0; i < 2; ++i) {
            qAcc[h][i] = (f32x4){0.f, 0.f, 0.f, 0.f};
            kAcc[h][i] = (f32x4){0.f, 0.f, 0.f, 0.f};
            #pragma unroll
            for (int j = 0; j < 2; ++j) sAcc[h][i][j] = (f32x4){0.f, 0.f, 0.f, 0.f};
        }

    const size_t pbase = (size_t)b * NHW + (size_t)nc * 1024;
    unsigned* ldsw = (unsigned*)lds;

    for (int it = 0; it < 16; ++it) {
        const size_t nb = pbase + it * 64;
        #pragma unroll
        for (int i = 0; i < 6; ++i) {
            int task = i * 256 + tid;          // 1536 tasks: 32 n-pairs x 48 chunks
            int np = task & 31, ch = task >> 5;
            const bfu* r0 = qkv + (nb + np * 2) * CQKV + ch * 8;
            uint4 v0 = *(const uint4*)r0;
            uint4 v1 = *(const uint4*)(r0 + CQKV);
            int cb8 = ch * 8;
            ldsw[(cb8 + 0) * 36 + np] = (v0.x & 0xffffu) | (v1.x << 16);
            ldsw[(cb8 + 1) * 36 + np] = (v0.x >> 16) | (v1.x & 0xffff0000u);
            ldsw[(cb8 + 2) * 36 + np] = (v0.y & 0xffffu) | (v1.y << 16);
            ldsw[(cb8 + 3) * 36 + np] = (v0.y >> 16) | (v1.y & 0xffff0000u);
            ldsw[(cb8 + 4) * 36 + np] = (v0.z & 0xffffu) | (v1.z << 16);
            ldsw[(cb8 + 5) * 36 + np] = (v0.z >> 16) | (v1.z & 0xffff0000u);
            ldsw[(cb8 + 6) * 36 + np] = (v0.w & 0xffffu) | (v1.w << 16);
            ldsw[(cb8 + 7) * 36 + np] = (v0.w >> 16) | (v1.w & 0xffff0000u);
        }
        // zero pad rows 384..391
        ldsw[(384 + (tid >> 5)) * 36 + (tid & 31)] = 0;
        __syncthreads();
        #pragma unroll
        for (int hh = 0; hh < 2; ++hh) {
            const int h = wave * 2 + hh;
            const int qr = h * NCF, kr = NC + h * NCF;
            #pragma unroll
            for (int ks = 0; ks < 2; ++ks) {
                const int nsub = ks * 32 + kg * 8;
                bf16x8 aq0 = *(const bf16x8*)(lds + (qr + l15) * 72 + nsub);
                bf16x8 aq1 = *(const bf16x8*)(lds + (qr + 16 + l15) * 72 + nsub);
                bf16x8 bk0 = *(const bf16x8*)(lds + (kr + l15) * 72 + nsub);
                bf16x8 bk1 = *(const bf16x8*)(lds + (kr + 16 + l15) * 72 + nsub);
                sAcc[hh][0][0] = __builtin_amdgcn_mfma_f32_16x16x32_bf16(aq0, bk0, sAcc[hh][0][0], 0, 0, 0);
                sAcc[hh][0][1] = __builtin_amdgcn_mfma_f32_16x16x32_bf16(aq0, bk1, sAcc[hh][0][1], 0, 0, 0);
                sAcc[hh][1][0] = __builtin_amdgcn_mfma_f32_16x16x32_bf16(aq1, bk0, sAcc[hh][1][0], 0, 0, 0);
                sAcc[hh][1][1] = __builtin_amdgcn_mfma_f32_16x16x32_bf16(aq1, bk1, sAcc[hh][1][1], 0, 0, 0);
                qAcc[hh][0] = __builtin_amdgcn_mfma_f32_16x16x32_bf16(aq0, aq0, qAcc[hh][0], 0, 0, 0);
                qAcc[hh][1] = __builtin_amdgcn_mfma_f32_16x16x32_bf16(aq1, aq1, qAcc[hh][1], 0, 0, 0);
                kAcc[hh][0] = __builtin_amdgcn_mfma_f32_16x16x32_bf16(bk0, bk0, kAcc[hh][0], 0, 0, 0);
                kAcc[hh][1] = __builtin_amdgcn_mfma_f32_16x16x32_bf16(bk1, bk1, kAcc[hh][1], 0, 0, 0);
            }
        }
        __syncthreads();
    }

    const int gb = b0 + b;
    #pragma unroll
    for (int hh = 0; hh < 2; ++hh) {
        const int h = wave * 2 + hh;
        float* Sp = S32 + ((size_t)gb * NHEADS + h) * 1024;
        #pragma unroll
        for (int mt = 0; mt < 2; ++mt)
            #pragma unroll
            for (int nt = 0; nt < 2; ++nt)
                #pragma unroll
                for (int r = 0; r < 4; ++r) {
                    int c = mt * 16 + kg * 4 + r, d = nt * 16 + l15;
                    atomicAdd(&Sp[c * 32 + d], sAcc[hh][mt][nt][r]);
                }
        #pragma unroll
        for (int t = 0; t < 2; ++t)
            #pragma unroll
            for (int r = 0; r < 4; ++r) {
                int row = t * 16 + kg * 4 + r, col = t * 16 + l15;
                if (row == col && row < NCF) {
                    atomicAdd(&Q2[((size_t)gb * NHEADS + h) * NCF + row], qAcc[hh][t][r]);
                    atomicAdd(&K2[((size_t)gb * NHEADS + h) * NCF + row], kAcc[hh][t][r]);
                }
            }
    }
}

// ---------------------------------------------------------------------------
// normalize -> softmax -> fold proj_w -> Mbf [b][256pad][192] bf16. grid(CB)
// ---------------------------------------------------------------------------
__global__ __launch_bounds__(256) void attn_fold(
    const float* __restrict__ S32, const float* __restrict__ Q2, const float* __restrict__ K2,
    const float* __restrict__ temp, const float* __restrict__ projw, bfu* __restrict__ Mbf, int b0)
{
    const int gb = b0 + blockIdx.x, tid = threadIdx.x;
    __shared__ float P[NHEADS * NCF * NCF];
    for (int e = tid; e < NHEADS * NCF * NCF; e += 256) {
        int h = e / (NCF * NCF);
        int r = e % (NCF * NCF);
        int c = r / NCF, d = r % NCF;
        float sv = S32[((size_t)gb * NHEADS + h) * 1024 + c * 32 + d];
        float rq = sqrtf(Q2[((size_t)gb * NHEADS + h) * NCF + c]);
        float rk = sqrtf(K2[((size_t)gb * NHEADS + h) * NCF + d]);
        P[e] = sv / (rq * rk) * temp[h];
    }
    __syncthreads();
    if (tid < NHEADS * NCF) {
        int h = tid / NCF, c = tid % NCF;
        float* row = P + h * (NCF * NCF) + c * NCF;
        float mx = row[0];
        #pragma unroll
        for (int d = 1; d < NCF; ++d) mx = fmaxf(mx, row[d]);
        float sum = 0.f;
        #pragma unroll
        for (int d = 0; d < NCF; ++d) { float e2 = __expf(row[d] - mx); row[d] = e2; sum += e2; }
        float inv = 1.f / sum;
        #pragma unroll
        for (int d = 0; d < NCF; ++d) row[d] *= inv;
    }
    __syncthreads();
    bfu* Mb = Mbf + (size_t)gb * OM_PAD * NC;
    if (tid < NC) {
        int o = tid;
        for (int h = 0; h < NHEADS; ++h) {
            float pw[NCF];
            #pragma unroll
            for (int c = 0; c < NCF; ++c) pw[c] = projw[(size_t)o * NC + h * NCF + c];
            #pragma unroll
            for (int d = 0; d < NCF; ++d) {
                float acc = 0.f;
                #pragma unroll
                for (int c = 0; c < NCF; ++c) acc = fmaf(pw[c], P[h * (NCF * NCF) + c * NCF + d], acc);
                Mb[(size_t)o * NC + h * NCF + d] = f2b(acc);
            }
        }
    }
    for (int e = tid; e < (OM_PAD - NC) * NC; e += 256) Mb[NC * NC + e] = 0;
}

// ---------------------------------------------------------------------------
// final: out2 pixel-major [n][192] f32 -> d_out channel-major [192][n]
// ---------------------------------------------------------------------------
__global__ __launch_bounds__(256) void transpose_out(
    const float* __restrict__ src, float* __restrict__ dst, int cb)
{
    __shared__ float t[64][196];
    const int nb = blockIdx.x;      // 256 tiles of 64 px
    const int b = blockIdx.y;
    const int tid = threadIdx.x;
    #pragma unroll
    for (int i = 0; i < 12; ++i) {
        int task = i * 256 + tid;    // 3072 = 64 rows x 48 float4
        int nl = task / 48, ch = task % 48;
        float4 v = *(const float4*)(src + ((size_t)b * NHW + nb * 64 + nl) * NC + ch * 4);
        *(float4*)&t[nl][ch * 4] = v;
    }
    __syncthreads();
    #pragma unroll
    for (int i = 0; i < 12; ++i) {
        int task = i * 256 + tid;    // 3072 = 192 c x 16 n-chunks
        int c = task / 16, nch = task % 16;
        float4 v = make_float4(t[nch * 4 + 0][c], t[nch * 4 + 1][c], t[nch * 4 + 2][c], t[nch * 4 + 3][c]);
        *(float4*)(dst + ((size_t)b * NC + c) * NHW + nb * 64 + nch * 4) = v;
    }
}

// ---------------------------------------------------------------------------
extern "C" void kernel_launch(void* const* d_in, const int* in_sizes, int n_in,
                              void* d_out, int out_size, void* d_ws, size_t ws_size,
                              hipStream_t stream)
{
    const float* x     = (const float*)d_in[0];
    const float* kv    = (const float*)d_in[1];
    const float* ln1w  = (const float*)d_in[2];
    const float* ln1b  = (const float*)d_in[3];
    const float* akern = (const float*)d_in[4];
    const float* qkvw  = (const float*)d_in[5];
    const float* qkvdw = (const float*)d_in[6];
    const float* projw = (const float*)d_in[7];
    const float* temp  = (const float*)d_in[8];
    const float* ln2w  = (const float*)d_in[9];
    const float* ln2b  = (const float*)d_in[10];
    const float* fkern = (const float*)d_in[11];
    const float* pinw  = (const float*)d_in[12];
    const float* ffndw = (const float*)d_in[13];
    const float* poutw = (const float*)d_in[14];
    float* out = (float*)d_out;

    char* wp = (char*)d_ws;
    size_t off = 0;
    auto take = [&](size_t bytes) {
        char* r = wp + off;
        off = (off + bytes + 255) & ~(size_t)255;
        return r;
    };
    float* mu1   = (float*)take((size_t)NB * NHW * 4);
    float* rstd1 = (float*)take((size_t)NB * NHW * 4);
    float* mu2   = (float*)take((size_t)NB * NHW * 4);
    float* rstd2 = (float*)take((size_t)NB * NHW * 4);
    float* s1 = (float*)take(NB * NC * 4);  float* t1 = (float*)take(NB * NC * 4);
    float* s2 = (float*)take(NB * NC * 4);  float* t2 = (float*)take(NB * NC * 4);
    bfu* A1 = (bfu*)take((size_t)NB * OQKV_PAD * 192 * 2);
    bfu* A2 = (bfu*)take((size_t)NB * CPIN * 192 * 2);
    bfu* A3 = (bfu*)take((size_t)OM_PAD * 512 * 2);
    bfu* Mbf = (bfu*)take((size_t)NB * OM_PAD * NC * 2);
    float* u1  = (float*)take((size_t)NB * OQKV_PAD * 4);
    float* v01 = (float*)take((size_t)NB * OQKV_PAD * 4);
    float* u2  = (float*)take((size_t)NB * CPIN * 4);
    float* v02 = (float*)take((size_t)NB * CPIN * 4);
    float* wdwT1 = (float*)take(9 * CQKV * 4);
    float* wdwT2 = (float*)take(9 * CPIN * 4);
    float* S32 = (float*)take((size_t)NB * NHEADS * 1024 * 4);
    float* Q2  = (float*)take((size_t)NB * NHEADS * NCF * 4);
    float* K2  = (float*)take((size_t)NB * NHEADS * NCF * 4);
    const size_t bigoff = off;

    // per-batch big buffers (pixel-major): out1(768B) bfX(384B) big1(2048B) big2(1152B)
    const size_t PB = (size_t)NHW * (768 + 384 + 2048 + 1152);
    size_t avail = (ws_size > bigoff) ? ws_size - bigoff : 0;
    int CB = 8;
    while (CB > 1 && (size_t)CB * PB > avail) CB >>= 1;

    dim3 blk(256);

    prep_film<<<dim3(48, NB), blk, 0, stream>>>(kv, akern, ln1w, ln1b, s1, t1);
    prep_film<<<dim3(48, NB), blk, 0, stream>>>(kv, fkern, ln2w, ln2b, s2, t2);
    wprep<<<dim3(OQKV_PAD / 4, NB), blk, 0, stream>>>(qkvw, s1, t1, A1, u1, v01, 0);
    wprep<<<dim3(CPIN / 4, NB), blk, 0, stream>>>(pinw, s2, t2, A2, u2, v02, 1);
    wprep<<<dim3(OM_PAD / 4, 1), blk, 0, stream>>>(poutw, s1, t1, A3, nullptr, nullptr, 2);
    wdw_prep<<<(9 * CQKV + 255) / 256, blk, 0, stream>>>(qkvdw, wdwT1, CQKV, 0);
    wdw_prep<<<(9 * CPIN + 255) / 256, blk, 0, stream>>>(ffndw, wdwT2, CPIN, 1);
    {
        int nz = NB * NHEADS * 1024 + 2 * NB * NHEADS * NCF + 256;
        zfill<<<(nz + 255) / 256, blk, 0, stream>>>(S32, nz);
    }

    for (int b0 = 0; b0 < NB; b0 += CB) {
        float* out1 = (float*)(wp + bigoff);
        bfu* bfX   = (bfu*)(wp + bigoff + (size_t)CB * NHW * 768);
        char* big1 = wp + bigoff + (size_t)CB * NHW * (768 + 384);
        char* big2 = big1 + (size_t)CB * NHW * 2048;
        bfu* qkv_pre = (bfu*)big1;
        bfu* qkvb    = (bfu*)big2;
        bfu* u_pre   = (bfu*)big1;
        bfu* gbuf    = (bfu*)big2;
        float* out2  = (float*)big1;

        const float* xb = x + (size_t)b0 * NC * NHW;
        float* mu1b = mu1 + (size_t)b0 * NHW;   float* rs1b = rstd1 + (size_t)b0 * NHW;
        float* mu2b = mu2 + (size_t)b0 * NHW;   float* rs2b = rstd2 + (size_t)b0 * NHW;

        // ---- attention branch ----
        ln_cvt_cm<<<CB * 64, blk, 0, stream>>>(xb, mu1b, rs1b, bfX, CB);
        gemm_pm<0><<<dim3(128, OQKV_PAD / 128, CB), blk, 0, stream>>>(
            A1 + (size_t)b0 * OQKV_PAD * 192, (long)OQKV_PAD * 192, OQKV_PAD, CQKV, 192,
            bfX, NC, 0, qkv_pre, CQKV, nullptr, 0,
            mu1b, rs1b, u1 + (size_t)b0 * OQKV_PAD, v01 + (size_t)b0 * OQKV_PAD, OQKV_PAD);
        dw_pm<CQKV, CQKV, false><<<CB * 4608, blk, 0, stream>>>(qkv_pre, wdwT1, qkvb, CB);
        gram_pm<<<dim3(16, CB), blk, 0, stream>>>(qkvb, S32, Q2, K2, b0);
        attn_fold<<<CB, blk, 0, stream>>>(S32, Q2, K2, temp, projw, Mbf, b0);
        gemm_pm<1><<<dim3(128, OM_PAD / 128, CB), blk, 0, stream>>>(
            Mbf + (size_t)b0 * OM_PAD * NC, (long)OM_PAD * NC, OM_PAD, NC, 192,
            qkvb, CQKV, 384, out1, NC, bfX, NC,
            nullptr, nullptr, nullptr, nullptr, 0);

        // ---- FFN branch ----
        ln_cvt_pm<<<CB * 64, blk, 0, stream>>>(out1, mu2b, rs2b, bfX, CB);
        gemm_pm<0><<<dim3(128, CPIN / 128, CB), blk, 0, stream>>>(
            A2 + (size_t)b0 * CPIN * 192, (long)CPIN * 192, CPIN, CPIN, 192,
            bfX, NC, 0, u_pre, CPIN, nullptr, 0,
            mu2b, rs2b, u2 + (size_t)b0 * CPIN, v02 + (size_t)b0 * CPIN, CPIN);
        dw_pm<CPIN, CG, true><<<CB * 4096, blk, 0, stream>>>(u_pre, wdwT2, gbuf, CB);
        gemm_pm<2><<<dim3(128, OM_PAD / 128, CB), blk, 0, stream>>>(
            A3, 0, OM_PAD, NC, 512,
            gbuf, CG, 0, out2, NC, out1, NC,
            nullptr, nullptr, nullptr, nullptr, 0);
        transpose_out<<<dim3(256, CB), blk, 0, stream>>>(out2, out + (size_t)b0 * NC * NHW, CB);
    }
}

// Round 5
// 1116.651 us; speedup vs baseline: 2.5270x; 1.1419x over previous
//
#include <hip/hip_runtime.h>
#include <math.h>

#define NB 8
#define NC 192
#define NHEADS 8
#define NCF 24
#define NHW 16384
#define NWID 128
#define CQKV 576
#define OQKV_PAD 640
#define CPIN 1024
#define CG 512
#define OM_PAD 256

typedef unsigned short bfu;
typedef __bf16 bf16x8 __attribute__((ext_vector_type(8)));
typedef float f32x4 __attribute__((ext_vector_type(4)));

__device__ __forceinline__ float b2f(unsigned short u) { return __uint_as_float(((unsigned)u) << 16); }
__device__ __forceinline__ unsigned short f2b(float f) {
    unsigned u = __float_as_uint(f);
    u += 0x7FFFu + ((u >> 16) & 1u);
    return (unsigned short)(u >> 16);
}
// tanh-based GELU (max |err| vs exact ~3e-4; threshold margin is 0.077)
__device__ __forceinline__ float gelu_tanh(float x) {
    float x3 = x * x * x;
    float z = 0.7978845608028654f * fmaf(0.044715f, x3, x);
    float e = __expf(2.f * z);
    float th = 1.f - 2.f / (e + 1.f);
    return 0.5f * x * (1.f + th);
}

struct F8 { float v[8]; };
__device__ __forceinline__ F8 load8(const bfu* p) {
    uint4 r = *(const uint4*)p;
    F8 o;
    o.v[0] = b2f((unsigned short)(r.x & 0xffff)); o.v[1] = b2f((unsigned short)(r.x >> 16));
    o.v[2] = b2f((unsigned short)(r.y & 0xffff)); o.v[3] = b2f((unsigned short)(r.y >> 16));
    o.v[4] = b2f((unsigned short)(r.z & 0xffff)); o.v[5] = b2f((unsigned short)(r.z >> 16));
    o.v[6] = b2f((unsigned short)(r.w & 0xffff)); o.v[7] = b2f((unsigned short)(r.w >> 16));
    return o;
}
__device__ __forceinline__ void store8(bfu* p, const float* a) {
    uint4 r;
    r.x = (unsigned)f2b(a[0]) | ((unsigned)f2b(a[1]) << 16);
    r.y = (unsigned)f2b(a[2]) | ((unsigned)f2b(a[3]) << 16);
    r.z = (unsigned)f2b(a[4]) | ((unsigned)f2b(a[5]) << 16);
    r.w = (unsigned)f2b(a[6]) | ((unsigned)f2b(a[7]) << 16);
    *(uint4*)p = r;
}

__global__ __launch_bounds__(256) void zfill(float* __restrict__ p, int n) {
    int i = blockIdx.x * 256 + threadIdx.x;
    if (i < n) p[i] = 0.f;
}

// ---------------------------------------------------------------------------
// prep_film, wave-parallel. grid (48, NB) x 256.
// ---------------------------------------------------------------------------
__global__ __launch_bounds__(256) void prep_film(
    const float* __restrict__ kv, const float* __restrict__ kern,
    const float* __restrict__ lnw, const float* __restrict__ lnb,
    float* __restrict__ sArr, float* __restrict__ tArr)
{
    const int b = blockIdx.y;
    const int wave = threadIdx.x >> 6, lane = threadIdx.x & 63;
    const int r = blockIdx.x * 4 + wave;
    const float* kvb = kv + b * 256;
    float4 kvv = *(const float4*)(kvb + lane * 4);
    float4 k1 = *(const float4*)(kern + (size_t)r * 256 + lane * 4);
    float4 k2 = *(const float4*)(kern + (size_t)(r + NC) * 256 + lane * 4);
    float d1 = kvv.x * k1.x + kvv.y * k1.y + kvv.z * k1.z + kvv.w * k1.w;
    float d2 = kvv.x * k2.x + kvv.y * k2.y + kvv.z * k2.z + kvv.w * k2.w;
    #pragma unroll
    for (int off = 32; off; off >>= 1) {
        d1 += __shfl_down(d1, off, 64);
        d2 += __shfl_down(d2, off, 64);
    }
    if (lane == 0) {
        sArr[b * NC + r] = lnw[r] * d1;
        tArr[b * NC + r] = lnb[r] * d1 + d2;
    }
}

// ---------------------------------------------------------------------------
// Build bf16 A matrices + u=sum(bf16 A), v0=W@t. Wave-per-row.
// ---------------------------------------------------------------------------
__global__ __launch_bounds__(256) void wprep(
    const float* __restrict__ W, const float* __restrict__ sA, const float* __restrict__ tA,
    bfu* __restrict__ Abf, float* __restrict__ u, float* __restrict__ v0, int mode)
{
    const int wave = threadIdx.x >> 6, lane = threadIdx.x & 63;
    const int o = blockIdx.x * 4 + wave;
    const int b = blockIdx.y;
    const int Opad = (mode == 0) ? OQKV_PAD : (mode == 1 ? CPIN : OM_PAD);
    const int K = (mode == 2) ? 512 : 192;
    const int Kr = (mode == 2) ? 510 : 192;
    int src;
    if (mode == 0) src = (o < 576) ? o : -1;
    else if (mode == 1) src = (o < 510) ? o : (o < 512 ? -1 : (o < 1022 ? o - 2 : -1));
    else src = (o < 192) ? o : -1;
    const float* wr = (src >= 0) ? W + (size_t)src * Kr : nullptr;
    const float* sb = sA + b * NC;
    const float* tb = tA + b * NC;
    bfu* arow = Abf + ((size_t)b * Opad + o) * K;
    float au = 0.f, av = 0.f;
    for (int c0 = lane * 4; c0 < K; c0 += 256) {
        float a[4] = {0.f, 0.f, 0.f, 0.f};
        if (src >= 0) {
            #pragma unroll
            for (int j = 0; j < 4; ++j) {
                int c = c0 + j;
                if (c < Kr) {
                    float w = wr[c];
                    if (mode == 2) a[j] = w;
                    else { a[j] = w * sb[c]; av = fmaf(w, tb[c], av); }
                }
            }
        }
        ushort4 pk;
        bfu b0 = f2b(a[0]), b1 = f2b(a[1]), b2 = f2b(a[2]), b3 = f2b(a[3]);
        pk.x = b0; pk.y = b1; pk.z = b2; pk.w = b3;
        au += b2f(b0) + b2f(b1) + b2f(b2) + b2f(b3);
        *(ushort4*)(arow + c0) = pk;
    }
    if (mode < 2) {
        #pragma unroll
        for (int off = 32; off; off >>= 1) {
            au += __shfl_down(au, off, 64);
            av += __shfl_down(av, off, 64);
        }
        if (lane == 0) {
            u[(size_t)b * Opad + o] = au;
            v0[(size_t)b * Opad + o] = (src >= 0) ? av : 0.f;
        }
    }
}

// transpose dw weights: mode 0: [C][9]->[9][C]; mode 1: ffn remap to [9][1024]
__global__ __launch_bounds__(256) void wdw_prep(
    const float* __restrict__ src, float* __restrict__ dstT, int C, int mode)
{
    int i = blockIdx.x * 256 + threadIdx.x;
    if (i >= 9 * C) return;
    int tap = i / C, col = i % C;
    float v;
    if (mode == 0) v = src[(size_t)col * 9 + tap];
    else {
        if (col < 512) v = (col < 510) ? src[(size_t)col * 9 + tap] : 0.f;
        else { int c2 = col - 512; v = (c2 < 510) ? src[(size_t)(510 + c2) * 9 + tap] : 0.f; }
    }
    dstT[(size_t)tap * C + col] = v;
}

// ---------------------------------------------------------------------------
// LN stats + bf16 convert (channel-major / pixel-major input variants)
// ---------------------------------------------------------------------------
__global__ __launch_bounds__(256) void ln_cvt_cm(
    const float* __restrict__ x, float* __restrict__ mu, float* __restrict__ rstd,
    bfu* __restrict__ xbf, int cb)
{
    int idx = blockIdx.x * 256 + threadIdx.x;
    if (idx >= cb * NHW) return;
    int b = idx >> 14, n = idx & (NHW - 1);
    const float* p = x + (size_t)b * NC * NHW + n;
    bfu* orow = xbf + ((size_t)b * NHW + n) * NC;
    float s = 0.f, ss = 0.f;
    for (int c0 = 0; c0 < NC; c0 += 8) {
        float v[8];
        #pragma unroll
        for (int j = 0; j < 8; ++j) {
            v[j] = p[(size_t)(c0 + j) * NHW];
            s += v[j]; ss = fmaf(v[j], v[j], ss);
        }
        store8(orow + c0, v);
    }
    float m = s * (1.f / 192.f);
    float var = ss * (1.f / 192.f) - m * m;
    mu[idx] = m;
    rstd[idx] = rsqrtf(var + 1e-5f);
}

__global__ __launch_bounds__(256) void ln_cvt_pm(
    const float* __restrict__ x, float* __restrict__ mu, float* __restrict__ rstd,
    bfu* __restrict__ xbf, int cb)
{
    int idx = blockIdx.x * 256 + threadIdx.x;
    if (idx >= cb * NHW) return;
    const float* p = x + (size_t)idx * NC;
    bfu* orow = xbf + (size_t)idx * NC;
    float s = 0.f, ss = 0.f;
    for (int c0 = 0; c0 < NC; c0 += 8) {
        float4 v0 = *(const float4*)(p + c0);
        float4 v1 = *(const float4*)(p + c0 + 4);
        float v[8] = {v0.x, v0.y, v0.z, v0.w, v1.x, v1.y, v1.z, v1.w};
        #pragma unroll
        for (int j = 0; j < 8; ++j) { s += v[j]; ss = fmaf(v[j], v[j], ss); }
        store8(orow + c0, v);
    }
    float m = s * (1.f / 192.f);
    float var = ss * (1.f / 192.f) - m * m;
    mu[idx] = m;
    rstd[idx] = rsqrtf(var + 1e-5f);
}

// ---------------------------------------------------------------------------
// MFMA GEMM, pixel-major X (unchanged from R3)
// ---------------------------------------------------------------------------
template<int EPI>
__global__ __launch_bounds__(256) void gemm_pm(
    const bfu* __restrict__ A, long aBStride, int Opad, int Oreal, int K,
    const bfu* __restrict__ X, int xRow, int xOff,
    void* __restrict__ Y, int yRow,
    const void* __restrict__ res, int resRow,
    const float* __restrict__ mu, const float* __restrict__ rstd,
    const float* __restrict__ uvec, const float* __restrict__ v0vec, int uStride)
{
    __shared__ bfu stage[128][136];
    const int b = blockIdx.z;
    const int om = blockIdx.y * 128;
    const int n0 = blockIdx.x * 128;
    const int tid = threadIdx.x;
    const int lane = tid & 63, wave = tid >> 6;
    const int wy = wave >> 1, wx = wave & 1;
    const int l15 = lane & 15, kg = lane >> 4;

    const bfu* Ab = A + (size_t)b * aBStride;
    const bfu* Arow[4];
    #pragma unroll
    for (int mf = 0; mf < 4; ++mf)
        Arow[mf] = Ab + (size_t)(om + wy * 64 + mf * 16 + l15) * K + kg * 8;
    const bfu* Xb = X + ((size_t)b * NHW + n0 + wx * 64 + l15) * xRow + xOff + kg * 8;

    f32x4 acc[4][4];
    #pragma unroll
    for (int i = 0; i < 4; ++i)
        #pragma unroll
        for (int j = 0; j < 4; ++j) acc[i][j] = (f32x4){0.f, 0.f, 0.f, 0.f};

    for (int kk = 0; kk < K; kk += 32) {
        bf16x8 af[4], bfr[4];
        #pragma unroll
        for (int mf = 0; mf < 4; ++mf) af[mf] = *(const bf16x8*)(Arow[mf] + kk);
        #pragma unroll
        for (int nf = 0; nf < 4; ++nf) bfr[nf] = *(const bf16x8*)(Xb + (size_t)(nf * 16) * xRow + kk);
        #pragma unroll
        for (int mf = 0; mf < 4; ++mf)
            #pragma unroll
            for (int nf = 0; nf < 4; ++nf)
                acc[mf][nf] = __builtin_amdgcn_mfma_f32_16x16x32_bf16(af[mf], bfr[nf], acc[mf][nf], 0, 0, 0);
    }

    #pragma unroll
    for (int nf = 0; nf < 4; ++nf) {
        const int nl = wx * 64 + nf * 16 + l15;
        float muv = 0.f, rsv = 0.f;
        if (EPI == 0) {
            muv = mu[(size_t)b * NHW + n0 + nl];
            rsv = rstd[(size_t)b * NHW + n0 + nl];
        }
        #pragma unroll
        for (int mf = 0; mf < 4; ++mf) {
            const int obl = wy * 64 + mf * 16 + kg * 4;
            float r0, r1, r2, r3;
            if (EPI == 0) {
                float4 uv = *(const float4*)(uvec + (size_t)b * uStride + om + obl);
                float4 vv = *(const float4*)(v0vec + (size_t)b * uStride + om + obl);
                r0 = rsv * (acc[mf][nf][0] - muv * uv.x) + vv.x;
                r1 = rsv * (acc[mf][nf][1] - muv * uv.y) + vv.y;
                r2 = rsv * (acc[mf][nf][2] - muv * uv.z) + vv.z;
                r3 = rsv * (acc[mf][nf][3] - muv * uv.w) + vv.w;
            } else {
                r0 = acc[mf][nf][0]; r1 = acc[mf][nf][1];
                r2 = acc[mf][nf][2]; r3 = acc[mf][nf][3];
            }
            ushort4 pk;
            pk.x = f2b(r0); pk.y = f2b(r1); pk.z = f2b(r2); pk.w = f2b(r3);
            *(ushort4*)&stage[nl][obl] = pk;
        }
    }
    __syncthreads();

    #pragma unroll
    for (int it = 0; it < 8; ++it) {
        int task = it * 256 + tid;
        int nl = task >> 4, ch = task & 15;
        int oc = om + ch * 8;
        if (oc >= Oreal) continue;
        uint4 sv = *(const uint4*)&stage[nl][ch * 8];
        size_t nglob = (size_t)b * NHW + n0 + nl;
        if (EPI == 0) {
            *(uint4*)((bfu*)Y + nglob * yRow + oc) = sv;
        } else {
            float a[8];
            a[0] = b2f((unsigned short)(sv.x & 0xffff)); a[1] = b2f((unsigned short)(sv.x >> 16));
            a[2] = b2f((unsigned short)(sv.y & 0xffff)); a[3] = b2f((unsigned short)(sv.y >> 16));
            a[4] = b2f((unsigned short)(sv.z & 0xffff)); a[5] = b2f((unsigned short)(sv.z >> 16));
            a[6] = b2f((unsigned short)(sv.w & 0xffff)); a[7] = b2f((unsigned short)(sv.w >> 16));
            if (EPI == 1) {
                F8 rv = load8((const bfu*)res + nglob * resRow + oc);
                #pragma unroll
                for (int j = 0; j < 8; ++j) a[j] += rv.v[j];
            } else {
                const float* rp = (const float*)res + nglob * resRow + oc;
                float4 q0 = *(const float4*)rp, q1 = *(const float4*)(rp + 4);
                a[0] += q0.x; a[1] += q0.y; a[2] += q0.z; a[3] += q0.w;
                a[4] += q1.x; a[5] += q1.y; a[6] += q1.z; a[7] += q1.w;
            }
            float* yp = (float*)Y + nglob * yRow + oc;
            *(float4*)yp = make_float4(a[0], a[1], a[2], a[3]);
            *(float4*)(yp + 4) = make_float4(a[4], a[5], a[6], a[7]);
        }
    }
}

// ---------------------------------------------------------------------------
// depthwise 3x3 pixel-major, thread = 8ch x 4px, column-streaming.
// Weights per-dy in registers (amortized over 4 px); tanh-GELU gate.
// grid: cb * (NHW/4) * (COUT/8) / 256 blocks.
// ---------------------------------------------------------------------------
template<int CIN, int COUT, bool GATE>
__global__ __launch_bounds__(256) void dw_pm(
    const bfu* __restrict__ in, const float* __restrict__ wT, bfu* __restrict__ out, int cb)
{
    const int CHUNKS = COUT / 8;
    const int NPB = NHW / 4;
    int f = blockIdx.x * 256 + threadIdx.x;
    if (f >= cb * NPB * CHUNKS) return;
    int ch = f % CHUNKS;
    int pb = f / CHUNKS;
    int n4 = pb & (NPB - 1);
    int b  = pb >> 12;
    int xb = n4 & 31, y = n4 >> 5;
    int x0 = xb * 4;
    const int c8 = ch * 8;
    const bfu* rowb = in + ((size_t)b * NHW + (size_t)y * NWID) * CIN + c8;

    float a1[4][8] = {};
    float a2[4][8] = {};
    #pragma unroll
    for (int dy = -1; dy <= 1; ++dy) {
        int yy = y + dy;
        if ((unsigned)yy >= (unsigned)NWID) continue;
        const bfu* rb = rowb + (long)dy * NWID * CIN;
        float w1[3][8], w2[3][8];
        #pragma unroll
        for (int t = 0; t < 3; ++t) {
            const float* wp = wT + (size_t)((dy + 1) * 3 + t) * CIN + c8;
            *(float4*)&w1[t][0] = *(const float4*)wp;
            *(float4*)&w1[t][4] = *(const float4*)(wp + 4);
            if (GATE) {
                *(float4*)&w2[t][0] = *(const float4*)(wp + 512);
                *(float4*)&w2[t][4] = *(const float4*)(wp + 516);
            }
        }
        #pragma unroll
        for (int c = 0; c < 6; ++c) {
            int xx = x0 - 1 + c;
            if ((unsigned)xx >= (unsigned)NWID) continue;
            F8 v1 = load8(rb + (size_t)xx * CIN);
            F8 v2;
            if (GATE) v2 = load8(rb + (size_t)xx * CIN + 512);
            #pragma unroll
            for (int j = 0; j < 4; ++j) {
                int t = c - j;
                if (t < 0 || t > 2) continue;
                #pragma unroll
                for (int e = 0; e < 8; ++e) {
                    a1[j][e] = fmaf(w1[t][e], v1.v[e], a1[j][e]);
                    if (GATE) a2[j][e] = fmaf(w2[t][e], v2.v[e], a2[j][e]);
                }
            }
        }
    }
    #pragma unroll
    for (int j = 0; j < 4; ++j) {
        float r[8];
        if (GATE) {
            #pragma unroll
            for (int e = 0; e < 8; ++e) r[e] = gelu_tanh(a1[j][e]) * a2[j][e];
        } else {
            #pragma unroll
            for (int e = 0; e < 8; ++e) r[e] = a1[j][e];
        }
        store8(out + ((size_t)b * NHW + (size_t)y * NWID + x0 + j) * COUT + c8, r);
    }
}

// ---------------------------------------------------------------------------
// MFMA Gram. grid (64 n-chunks, CB). 4 waves x 2 heads each.
// ---------------------------------------------------------------------------
__global__ __launch_bounds__(256) void gram_pm(
    const bfu* __restrict__ qkv, float* __restrict__ S32,
    float* __restrict__ Q2, float* __restrict__ K2, int b0)
{
    __shared__ bfu lds[392 * 72];
    const int b = blockIdx.y;
    const int nc = blockIdx.x;
    const int tid = threadIdx.x;
    const int lane = tid & 63, wave = tid >> 6;
    const int l15 = lane & 15, kg = lane >> 4;

    f32x4 sAcc[2][2][2], qAcc[2][2], kAcc[2][2];
    #pragma unroll
    for (int h = 0; h < 2; ++h)
        #pragma unroll
        for (int i = 0; i < 2; ++i) {
            qAcc[h][i] = (f32x4){0.f, 0.f, 0.f, 0.f};
            kAcc[h][i] = (f32x4){0.f, 0.f, 0.f, 0.f};
            #pragma unroll
            for (int j = 0; j < 2; ++j) sAcc[h][i][j] = (f32x4){0.f, 0.f, 0.f, 0.f};
        }

    const size_t pbase = (size_t)b * NHW + (size_t)nc * 256;
    unsigned* ldsw = (unsigned*)lds;

    for (int it = 0; it < 4; ++it) {
        const size_t nb = pbase + it * 64;
        #pragma unroll
        for (int i = 0; i < 6; ++i) {
            int task = i * 256 + tid;
            int np = task & 31, ch = task >> 5;
            const bfu* r0 = qkv + (nb + np * 2) * CQKV + ch * 8;
            uint4 v0 = *(const uint4*)r0;
            uint4 v1 = *(const uint4*)(r0 + CQKV);
            int cb8 = ch * 8;
            ldsw[(cb8 + 0) * 36 + np] = (v0.x & 0xffffu) | (v1.x << 16);
            ldsw[(cb8 + 1) * 36 + np] = (v0.x >> 16) | (v1.x & 0xffff0000u);
            ldsw[(cb8 + 2) * 36 + np] = (v0.y & 0xffffu) | (v1.y << 16);
            ldsw[(cb8 + 3) * 36 + np] = (v0.y >> 16) | (v1.y & 0xffff0000u);
            ldsw[(cb8 + 4) * 36 + np] = (v0.z & 0xffffu) | (v1.z << 16);
            ldsw[(cb8 + 5) * 36 + np] = (v0.z >> 16) | (v1.z & 0xffff0000u);
            ldsw[(cb8 + 6) * 36 + np] = (v0.w & 0xffffu) | (v1.w << 16);
            ldsw[(cb8 + 7) * 36 + np] = (v0.w >> 16) | (v1.w & 0xffff0000u);
        }
        ldsw[(384 + (tid >> 5)) * 36 + (tid & 31)] = 0;
        __syncthreads();
        #pragma unroll
        for (int hh = 0; hh < 2; ++hh) {
            const int h = wave * 2 + hh;
            const int qr = h * NCF, kr = NC + h * NCF;
            #pragma unroll
            for (int ks = 0; ks < 2; ++ks) {
                const int nsub = ks * 32 + kg * 8;
                bf16x8 aq0 = *(const bf16x8*)(lds + (qr + l15) * 72 + nsub);
                bf16x8 aq1 = *(const bf16x8*)(lds + (qr + 16 + l15) * 72 + nsub);
                bf16x8 bk0 = *(const bf16x8*)(lds + (kr + l15) * 72 + nsub);
                bf16x8 bk1 = *(const bf16x8*)(lds + (kr + 16 + l15) * 72 + nsub);
                sAcc[hh][0][0] = __builtin_amdgcn_mfma_f32_16x16x32_bf16(aq0, bk0, sAcc[hh][0][0], 0, 0, 0);
                sAcc[hh][0][1] = __builtin_amdgcn_mfma_f32_16x16x32_bf16(aq0, bk1, sAcc[hh][0][1], 0, 0, 0);
                sAcc[hh][1][0] = __builtin_amdgcn_mfma_f32_16x16x32_bf16(aq1, bk0, sAcc[hh][1][0], 0, 0, 0);
                sAcc[hh][1][1] = __builtin_amdgcn_mfma_f32_16x16x32_bf16(aq1, bk1, sAcc[hh][1][1], 0, 0, 0);
                qAcc[hh][0] = __builtin_amdgcn_mfma_f32_16x16x32_bf16(aq0, aq0, qAcc[hh][0], 0, 0, 0);
                qAcc[hh][1] = __builtin_amdgcn_mfma_f32_16x16x32_bf16(aq1, aq1, qAcc[hh][1], 0, 0, 0);
                kAcc[hh][0] = __builtin_amdgcn_mfma_f32_16x16x32_bf16(bk0, bk0, kAcc[hh][0], 0, 0, 0);
                kAcc[hh][1] = __builtin_amdgcn_mfma_f32_16x16x32_bf16(bk1, bk1, kAcc[hh][1], 0, 0, 0);
            }
        }
        __syncthreads();
    }

    const int gb = b0 + b;
    #pragma unroll
    for (int hh = 0; hh < 2; ++hh) {
        const int h = wave * 2 + hh;
        float* Sp = S32 + ((size_t)gb * NHEADS + h) * 1024;
        #pragma unroll
        for (int mt = 0; mt < 2; ++mt)
            #pragma unroll
            for (int nt = 0; nt < 2; ++nt)
                #pragma unroll
                for (int r = 0; r < 4; ++r) {
                    int c = mt * 16 + kg * 4 + r, d = nt * 16 + l15;
                    atomicAdd(&Sp[c * 32 + d], sAcc[hh][mt][nt][r]);
                }
        #pragma unroll
        for (int t = 0; t < 2; ++t)
            #pragma unroll
            for (int r = 0; r < 4; ++r) {
                int row = t * 16 + kg * 4 + r, col = t * 16 + l15;
                if (row == col && row < NCF) {
                    atomicAdd(&Q2[((size_t)gb * NHEADS + h) * NCF + row], qAcc[hh][t][r]);
                    atomicAdd(&K2[((size_t)gb * NHEADS + h) * NCF + row], kAcc[hh][t][r]);
                }
            }
    }
}

// ---------------------------------------------------------------------------
// normalize -> softmax -> fold proj_w -> Mbf [b][256pad][192] bf16. grid(CB)
// ---------------------------------------------------------------------------
__global__ __launch_bounds__(256) void attn_fold(
    const float* __restrict__ S32, const float* __restrict__ Q2, const float* __restrict__ K2,
    const float* __restrict__ temp, const float* __restrict__ projw, bfu* __restrict__ Mbf, int b0)
{
    const int gb = b0 + blockIdx.x, tid = threadIdx.x;
    __shared__ float P[NHEADS * NCF * NCF];
    for (int e = tid; e < NHEADS * NCF * NCF; e += 256) {
        int h = e / (NCF * NCF);
        int r = e % (NCF * NCF);
        int c = r / NCF, d = r % NCF;
        float sv = S32[((size_t)gb * NHEADS + h) * 1024 + c * 32 + d];
        float rq = sqrtf(Q2[((size_t)gb * NHEADS + h) * NCF + c]);
        float rk = sqrtf(K2[((size_t)gb * NHEADS + h) * NCF + d]);
        P[e] = sv / (rq * rk) * temp[h];
    }
    __syncthreads();
    if (tid < NHEADS * NCF) {
        int h = tid / NCF, c = tid % NCF;
        float* row = P + h * (NCF * NCF) + c * NCF;
        float mx = row[0];
        #pragma unroll
        for (int d = 1; d < NCF; ++d) mx = fmaxf(mx, row[d]);
        float sum = 0.f;
        #pragma unroll
        for (int d = 0; d < NCF; ++d) { float e2 = __expf(row[d] - mx); row[d] = e2; sum += e2; }
        float inv = 1.f / sum;
        #pragma unroll
        for (int d = 0; d < NCF; ++d) row[d] *= inv;
    }
    __syncthreads();
    bfu* Mb = Mbf + (size_t)gb * OM_PAD * NC;
    if (tid < NC) {
        int o = tid;
        for (int h = 0; h < NHEADS; ++h) {
            float pw[NCF];
            #pragma unroll
            for (int c = 0; c < NCF; ++c) pw[c] = projw[(size_t)o * NC + h * NCF + c];
            #pragma unroll
            for (int d = 0; d < NCF; ++d) {
                float acc = 0.f;
                #pragma unroll
                for (int c = 0; c < NCF; ++c) acc = fmaf(pw[c], P[h * (NCF * NCF) + c * NCF + d], acc);
                Mb[(size_t)o * NC + h * NCF + d] = f2b(acc);
            }
        }
    }
    for (int e = tid; e < (OM_PAD - NC) * NC; e += 256) Mb[NC * NC + e] = 0;
}

// ---------------------------------------------------------------------------
// final: out2 pixel-major [n][192] f32 -> d_out channel-major [192][n]
// ---------------------------------------------------------------------------
__global__ __launch_bounds__(256) void transpose_out(
    const float* __restrict__ src, float* __restrict__ dst, int cb)
{
    __shared__ float t[64][196];
    const int nb = blockIdx.x;
    const int b = blockIdx.y;
    const int tid = threadIdx.x;
    #pragma unroll
    for (int i = 0; i < 12; ++i) {
        int task = i * 256 + tid;
        int nl = task / 48, ch = task % 48;
        float4 v = *(const float4*)(src + ((size_t)b * NHW + nb * 64 + nl) * NC + ch * 4);
        *(float4*)&t[nl][ch * 4] = v;
    }
    __syncthreads();
    #pragma unroll
    for (int i = 0; i < 12; ++i) {
        int task = i * 256 + tid;
        int c = task / 16, nch = task % 16;
        float4 v = make_float4(t[nch * 4 + 0][c], t[nch * 4 + 1][c], t[nch * 4 + 2][c], t[nch * 4 + 3][c]);
        *(float4*)(dst + ((size_t)b * NC + c) * NHW + nb * 64 + nch * 4) = v;
    }
}

// ---------------------------------------------------------------------------
extern "C" void kernel_launch(void* const* d_in, const int* in_sizes, int n_in,
                              void* d_out, int out_size, void* d_ws, size_t ws_size,
                              hipStream_t stream)
{
    const float* x     = (const float*)d_in[0];
    const float* kv    = (const float*)d_in[1];
    const float* ln1w  = (const float*)d_in[2];
    const float* ln1b  = (const float*)d_in[3];
    const float* akern = (const float*)d_in[4];
    const float* qkvw  = (const float*)d_in[5];
    const float* qkvdw = (const float*)d_in[6];
    const float* projw = (const float*)d_in[7];
    const float* temp  = (const float*)d_in[8];
    const float* ln2w  = (const float*)d_in[9];
    const float* ln2b  = (const float*)d_in[10];
    const float* fkern = (const float*)d_in[11];
    const float* pinw  = (const float*)d_in[12];
    const float* ffndw = (const float*)d_in[13];
    const float* poutw = (const float*)d_in[14];
    float* out = (float*)d_out;

    char* wp = (char*)d_ws;
    size_t off = 0;
    auto take = [&](size_t bytes) {
        char* r = wp + off;
        off = (off + bytes + 255) & ~(size_t)255;
        return r;
    };
    float* mu1   = (float*)take((size_t)NB * NHW * 4);
    float* rstd1 = (float*)take((size_t)NB * NHW * 4);
    float* mu2   = (float*)take((size_t)NB * NHW * 4);
    float* rstd2 = (float*)take((size_t)NB * NHW * 4);
    float* s1 = (float*)take(NB * NC * 4);  float* t1 = (float*)take(NB * NC * 4);
    float* s2 = (float*)take(NB * NC * 4);  float* t2 = (float*)take(NB * NC * 4);
    bfu* A1 = (bfu*)take((size_t)NB * OQKV_PAD * 192 * 2);
    bfu* A2 = (bfu*)take((size_t)NB * CPIN * 192 * 2);
    bfu* A3 = (bfu*)take((size_t)OM_PAD * 512 * 2);
    bfu* Mbf = (bfu*)take((size_t)NB * OM_PAD * NC * 2);
    float* u1  = (float*)take((size_t)NB * OQKV_PAD * 4);
    float* v01 = (float*)take((size_t)NB * OQKV_PAD * 4);
    float* u2  = (float*)take((size_t)NB * CPIN * 4);
    float* v02 = (float*)take((size_t)NB * CPIN * 4);
    float* wdwT1 = (float*)take(9 * CQKV * 4);
    float* wdwT2 = (float*)take(9 * CPIN * 4);
    float* S32 = (float*)take((size_t)NB * NHEADS * 1024 * 4);
    float* Q2  = (float*)take((size_t)NB * NHEADS * NCF * 4);
    float* K2  = (float*)take((size_t)NB * NHEADS * NCF * 4);
    const size_t bigoff = off;

    const size_t PB = (size_t)NHW * (768 + 384 + 2048 + 1152);
    size_t avail = (ws_size > bigoff) ? ws_size - bigoff : 0;
    int CB = 8;
    while (CB > 1 && (size_t)CB * PB > avail) CB >>= 1;

    dim3 blk(256);

    prep_film<<<dim3(48, NB), blk, 0, stream>>>(kv, akern, ln1w, ln1b, s1, t1);
    prep_film<<<dim3(48, NB), blk, 0, stream>>>(kv, fkern, ln2w, ln2b, s2, t2);
    wprep<<<dim3(OQKV_PAD / 4, NB), blk, 0, stream>>>(qkvw, s1, t1, A1, u1, v01, 0);
    wprep<<<dim3(CPIN / 4, NB), blk, 0, stream>>>(pinw, s2, t2, A2, u2, v02, 1);
    wprep<<<dim3(OM_PAD / 4, 1), blk, 0, stream>>>(poutw, s1, t1, A3, nullptr, nullptr, 2);
    wdw_prep<<<(9 * CQKV + 255) / 256, blk, 0, stream>>>(qkvdw, wdwT1, CQKV, 0);
    wdw_prep<<<(9 * CPIN + 255) / 256, blk, 0, stream>>>(ffndw, wdwT2, CPIN, 1);
    {
        int nz = NB * NHEADS * 1024 + 2 * NB * NHEADS * NCF + 256;
        zfill<<<(nz + 255) / 256, blk, 0, stream>>>(S32, nz);
    }

    for (int b0 = 0; b0 < NB; b0 += CB) {
        float* out1 = (float*)(wp + bigoff);
        bfu* bfX   = (bfu*)(wp + bigoff + (size_t)CB * NHW * 768);
        char* big1 = wp + bigoff + (size_t)CB * NHW * (768 + 384);
        char* big2 = big1 + (size_t)CB * NHW * 2048;
        bfu* qkv_pre = (bfu*)big1;
        bfu* qkvb    = (bfu*)big2;
        bfu* u_pre   = (bfu*)big1;
        bfu* gbuf    = (bfu*)big2;
        float* out2  = (float*)big1;

        const float* xb = x + (size_t)b0 * NC * NHW;
        float* mu1b = mu1 + (size_t)b0 * NHW;   float* rs1b = rstd1 + (size_t)b0 * NHW;
        float* mu2b = mu2 + (size_t)b0 * NHW;   float* rs2b = rstd2 + (size_t)b0 * NHW;

        // ---- attention branch ----
        ln_cvt_cm<<<CB * 64, blk, 0, stream>>>(xb, mu1b, rs1b, bfX, CB);
        gemm_pm<0><<<dim3(128, OQKV_PAD / 128, CB), blk, 0, stream>>>(
            A1 + (size_t)b0 * OQKV_PAD * 192, (long)OQKV_PAD * 192, OQKV_PAD, CQKV, 192,
            bfX, NC, 0, qkv_pre, CQKV, nullptr, 0,
            mu1b, rs1b, u1 + (size_t)b0 * OQKV_PAD, v01 + (size_t)b0 * OQKV_PAD, OQKV_PAD);
        dw_pm<CQKV, CQKV, false><<<CB * (NHW / 4) * (CQKV / 8) / 256, blk, 0, stream>>>(
            qkv_pre, wdwT1, qkvb, CB);
        gram_pm<<<dim3(64, CB), blk, 0, stream>>>(qkvb, S32, Q2, K2, b0);
        attn_fold<<<CB, blk, 0, stream>>>(S32, Q2, K2, temp, projw, Mbf, b0);
        gemm_pm<1><<<dim3(128, OM_PAD / 128, CB), blk, 0, stream>>>(
            Mbf + (size_t)b0 * OM_PAD * NC, (long)OM_PAD * NC, OM_PAD, NC, 192,
            qkvb, CQKV, 384, out1, NC, bfX, NC,
            nullptr, nullptr, nullptr, nullptr, 0);

        // ---- FFN branch ----
        ln_cvt_pm<<<CB * 64, blk, 0, stream>>>(out1, mu2b, rs2b, bfX, CB);
        gemm_pm<0><<<dim3(128, CPIN / 128, CB), blk, 0, stream>>>(
            A2 + (size_t)b0 * CPIN * 192, (long)CPIN * 192, CPIN, CPIN, 192,
            bfX, NC, 0, u_pre, CPIN, nullptr, 0,
            mu2b, rs2b, u2 + (size_t)b0 * CPIN, v02 + (size_t)b0 * CPIN, CPIN);
        dw_pm<CPIN, CG, true><<<CB * (NHW / 4) * (CG / 8) / 256, blk, 0, stream>>>(
            u_pre, wdwT2, gbuf, CB);
        gemm_pm<2><<<dim3(128, OM_PAD / 128, CB), blk, 0, stream>>>(
            A3, 0, OM_PAD, NC, 512,
            gbuf, CG, 0, out2, NC, out1, NC,
            nullptr, nullptr, nullptr, nullptr, 0);
        transpose_out<<<dim3(256, CB), blk, 0, stream>>>(out2, out + (size_t)b0 * NC * NHW, CB);
    }
}

// Round 6
// 929.851 us; speedup vs baseline: 3.0347x; 1.2009x over previous
//
#include <hip/hip_runtime.h>
#include <math.h>

#define NB 8
#define NC 192
#define NHEADS 8
#define NCF 24
#define NHW 16384
#define NWID 128
#define CQKV 576
#define OQKV_PAD 640
#define CPIN 1024
#define CG 512
#define OM_PAD 256

typedef unsigned short bfu;
typedef __bf16 bf16x8 __attribute__((ext_vector_type(8)));
typedef float f32x4 __attribute__((ext_vector_type(4)));

__device__ __forceinline__ float b2f(unsigned short u) { return __uint_as_float(((unsigned)u) << 16); }
__device__ __forceinline__ unsigned short f2b(float f) {
    unsigned u = __float_as_uint(f);
    u += 0x7FFFu + ((u >> 16) & 1u);
    return (unsigned short)(u >> 16);
}
// tanh-based GELU (max |err| vs exact ~3e-4; threshold margin is 0.077)
__device__ __forceinline__ float gelu_tanh(float x) {
    float x3 = x * x * x;
    float z = 0.7978845608028654f * fmaf(0.044715f, x3, x);
    float e = __expf(2.f * z);
    float th = 1.f - 2.f / (e + 1.f);
    return 0.5f * x * (1.f + th);
}

struct F8 { float v[8]; };
__device__ __forceinline__ F8 load8(const bfu* p) {
    uint4 r = *(const uint4*)p;
    F8 o;
    o.v[0] = b2f((unsigned short)(r.x & 0xffff)); o.v[1] = b2f((unsigned short)(r.x >> 16));
    o.v[2] = b2f((unsigned short)(r.y & 0xffff)); o.v[3] = b2f((unsigned short)(r.y >> 16));
    o.v[4] = b2f((unsigned short)(r.z & 0xffff)); o.v[5] = b2f((unsigned short)(r.z >> 16));
    o.v[6] = b2f((unsigned short)(r.w & 0xffff)); o.v[7] = b2f((unsigned short)(r.w >> 16));
    return o;
}
__device__ __forceinline__ void store8(bfu* p, const float* a) {
    uint4 r;
    r.x = (unsigned)f2b(a[0]) | ((unsigned)f2b(a[1]) << 16);
    r.y = (unsigned)f2b(a[2]) | ((unsigned)f2b(a[3]) << 16);
    r.z = (unsigned)f2b(a[4]) | ((unsigned)f2b(a[5]) << 16);
    r.w = (unsigned)f2b(a[6]) | ((unsigned)f2b(a[7]) << 16);
    *(uint4*)p = r;
}

__global__ __launch_bounds__(256) void zfill(float* __restrict__ p, int n) {
    int i = blockIdx.x * 256 + threadIdx.x;
    if (i < n) p[i] = 0.f;
}

// ---------------------------------------------------------------------------
// prep_film, wave-parallel. grid (48, NB) x 256.
// ---------------------------------------------------------------------------
__global__ __launch_bounds__(256) void prep_film(
    const float* __restrict__ kv, const float* __restrict__ kern,
    const float* __restrict__ lnw, const float* __restrict__ lnb,
    float* __restrict__ sArr, float* __restrict__ tArr)
{
    const int b = blockIdx.y;
    const int wave = threadIdx.x >> 6, lane = threadIdx.x & 63;
    const int r = blockIdx.x * 4 + wave;
    const float* kvb = kv + b * 256;
    float4 kvv = *(const float4*)(kvb + lane * 4);
    float4 k1 = *(const float4*)(kern + (size_t)r * 256 + lane * 4);
    float4 k2 = *(const float4*)(kern + (size_t)(r + NC) * 256 + lane * 4);
    float d1 = kvv.x * k1.x + kvv.y * k1.y + kvv.z * k1.z + kvv.w * k1.w;
    float d2 = kvv.x * k2.x + kvv.y * k2.y + kvv.z * k2.z + kvv.w * k2.w;
    #pragma unroll
    for (int off = 32; off; off >>= 1) {
        d1 += __shfl_down(d1, off, 64);
        d2 += __shfl_down(d2, off, 64);
    }
    if (lane == 0) {
        sArr[b * NC + r] = lnw[r] * d1;
        tArr[b * NC + r] = lnb[r] * d1 + d2;
    }
}

// ---------------------------------------------------------------------------
// Build bf16 A in MFMA-fragment-packed layout:
//   frag = (o/16)*K32 + (c/32); within = ((c>>3)&3)*128 + (o&15)*8 + (c&7)
// + u=sum(bf16 A row), v0=W@t. Wave-per-row.
// ---------------------------------------------------------------------------
__global__ __launch_bounds__(256) void wprep(
    const float* __restrict__ W, const float* __restrict__ sA, const float* __restrict__ tA,
    bfu* __restrict__ Abf, float* __restrict__ u, float* __restrict__ v0, int mode)
{
    const int wave = threadIdx.x >> 6, lane = threadIdx.x & 63;
    const int o = blockIdx.x * 4 + wave;
    const int b = blockIdx.y;
    const int Opad = (mode == 0) ? OQKV_PAD : (mode == 1 ? CPIN : OM_PAD);
    const int K = (mode == 2) ? 512 : 192;
    const int Kr = (mode == 2) ? 510 : 192;
    const int K32 = K >> 5;
    int src;
    if (mode == 0) src = (o < 576) ? o : -1;
    else if (mode == 1) src = (o < 510) ? o : (o < 512 ? -1 : (o < 1022 ? o - 2 : -1));
    else src = (o < 192) ? o : -1;
    const float* wr = (src >= 0) ? W + (size_t)src * Kr : nullptr;
    const float* sb = sA + b * NC;
    const float* tb = tA + b * NC;
    bfu* abase = Abf + (size_t)b * Opad * K;
    float au = 0.f, av = 0.f;
    for (int c0 = lane * 4; c0 < K; c0 += 256) {
        float a[4] = {0.f, 0.f, 0.f, 0.f};
        if (src >= 0) {
            #pragma unroll
            for (int j = 0; j < 4; ++j) {
                int c = c0 + j;
                if (c < Kr) {
                    float w = wr[c];
                    if (mode == 2) a[j] = w;
                    else { a[j] = w * sb[c]; av = fmaf(w, tb[c], av); }
                }
            }
        }
        ushort4 pk;
        bfu b0 = f2b(a[0]), b1 = f2b(a[1]), b2 = f2b(a[2]), b3 = f2b(a[3]);
        pk.x = b0; pk.y = b1; pk.z = b2; pk.w = b3;
        au += b2f(b0) + b2f(b1) + b2f(b2) + b2f(b3);
        int frag = (o >> 4) * K32 + (c0 >> 5);
        int within = ((c0 >> 3) & 3) * 128 + (o & 15) * 8 + (c0 & 7);
        *(ushort4*)(abase + (size_t)frag * 512 + within) = pk;
    }
    if (mode < 2) {
        #pragma unroll
        for (int off = 32; off; off >>= 1) {
            au += __shfl_down(au, off, 64);
            av += __shfl_down(av, off, 64);
        }
        if (lane == 0) {
            u[(size_t)b * Opad + o] = au;
            v0[(size_t)b * Opad + o] = (src >= 0) ? av : 0.f;
        }
    }
}

// transpose dw weights: mode 0: [C][9]->[9][C]; mode 1: ffn remap to [9][1024]
__global__ __launch_bounds__(256) void wdw_prep(
    const float* __restrict__ src, float* __restrict__ dstT, int C, int mode)
{
    int i = blockIdx.x * 256 + threadIdx.x;
    if (i >= 9 * C) return;
    int tap = i / C, col = i % C;
    float v;
    if (mode == 0) v = src[(size_t)col * 9 + tap];
    else {
        if (col < 512) v = (col < 510) ? src[(size_t)col * 9 + tap] : 0.f;
        else { int c2 = col - 512; v = (c2 < 510) ? src[(size_t)(510 + c2) * 9 + tap] : 0.f; }
    }
    dstT[(size_t)tap * C + col] = v;
}

// ---------------------------------------------------------------------------
// LN stats + bf16 convert (channel-major / pixel-major input variants)
// ---------------------------------------------------------------------------
__global__ __launch_bounds__(256) void ln_cvt_cm(
    const float* __restrict__ x, float* __restrict__ mu, float* __restrict__ rstd,
    bfu* __restrict__ xbf, int cb)
{
    int idx = blockIdx.x * 256 + threadIdx.x;
    if (idx >= cb * NHW) return;
    int b = idx >> 14, n = idx & (NHW - 1);
    const float* p = x + (size_t)b * NC * NHW + n;
    bfu* orow = xbf + ((size_t)b * NHW + n) * NC;
    float s = 0.f, ss = 0.f;
    for (int c0 = 0; c0 < NC; c0 += 8) {
        float v[8];
        #pragma unroll
        for (int j = 0; j < 8; ++j) {
            v[j] = p[(size_t)(c0 + j) * NHW];
            s += v[j]; ss = fmaf(v[j], v[j], ss);
        }
        store8(orow + c0, v);
    }
    float m = s * (1.f / 192.f);
    float var = ss * (1.f / 192.f) - m * m;
    mu[idx] = m;
    rstd[idx] = rsqrtf(var + 1e-5f);
}

__global__ __launch_bounds__(256) void ln_cvt_pm(
    const float* __restrict__ x, float* __restrict__ mu, float* __restrict__ rstd,
    bfu* __restrict__ xbf, int cb)
{
    int idx = blockIdx.x * 256 + threadIdx.x;
    if (idx >= cb * NHW) return;
    const float* p = x + (size_t)idx * NC;
    bfu* orow = xbf + (size_t)idx * NC;
    float s = 0.f, ss = 0.f;
    for (int c0 = 0; c0 < NC; c0 += 8) {
        float4 v0 = *(const float4*)(p + c0);
        float4 v1 = *(const float4*)(p + c0 + 4);
        float v[8] = {v0.x, v0.y, v0.z, v0.w, v1.x, v1.y, v1.z, v1.w};
        #pragma unroll
        for (int j = 0; j < 8; ++j) { s += v[j]; ss = fmaf(v[j], v[j], ss); }
        store8(orow + c0, v);
    }
    float m = s * (1.f / 192.f);
    float var = ss * (1.f / 192.f) - m * m;
    mu[idx] = m;
    rstd[idx] = rsqrtf(var + 1e-5f);
}

// ---------------------------------------------------------------------------
// MFMA GEMM v2: A fragment-packed (coalesced global), X staged via LDS in
// BK=64 double-buffered chunks. Block = 4 waves (2o x 2n), tile 128o x 64px.
// EPI 0: LN -> bf16 Y; EPI 1: + bf16 res -> f32 Y; EPI 2: + f32 res -> f32 Y.
// grid (NHW/64, Opad/128, CB)
// ---------------------------------------------------------------------------
template<int EPI>
__global__ __launch_bounds__(256) void gemm_pm(
    const bfu* __restrict__ A, long aBStride, int Opad, int Oreal, int K,
    const bfu* __restrict__ X, int xRow, int xOff,
    void* __restrict__ Y, int yRow,
    const void* __restrict__ res, int resRow,
    const float* __restrict__ mu, const float* __restrict__ rstd,
    const float* __restrict__ uvec, const float* __restrict__ v0vec, int uStride)
{
    __shared__ __align__(16) bfu smem[2 * 64 * 72];     // 18432 B; epilogue aliases
    bfu* xsbuf = smem;
    bfu (*stg)[136] = (bfu(*)[136])smem;                // 64 x 136 = 17408 B

    const int b = blockIdx.z;
    const int om = blockIdx.y * 128;
    const int n0 = blockIdx.x * 64;
    const int tid = threadIdx.x;
    const int lane = tid & 63, wave = tid >> 6;
    const int wy = wave >> 1, wx = wave & 1;
    const int l15 = lane & 15, kg = lane >> 4;
    const int K32 = K >> 5;
    const int NCH = K >> 6;
    const int o16b = (om >> 4) + wy * 4;

    const bfu* Ab = A + (size_t)b * aBStride;
    const bfu* Xbase = X + ((size_t)b * NHW + n0) * xRow + xOff;
    const int sr = tid >> 3, sc = tid & 7;   // stage: 32 rows x 8 chunks per iter

    f32x4 acc[4][2];
    #pragma unroll
    for (int i = 0; i < 4; ++i)
        #pragma unroll
        for (int j = 0; j < 2; ++j) acc[i][j] = (f32x4){0.f, 0.f, 0.f, 0.f};

    // stage chunk 0
    #pragma unroll
    for (int i = 0; i < 2; ++i) {
        int r = i * 32 + sr;
        uint4 v = *(const uint4*)(Xbase + (size_t)r * xRow + sc * 8);
        *(uint4*)&xsbuf[((0) * 64 + r) * 72 + sc * 8] = v;
    }
    __syncthreads();

    for (int kc = 0; kc < NCH; ++kc) {
        const int cur = kc & 1;
        if (kc + 1 < NCH) {
            #pragma unroll
            for (int i = 0; i < 2; ++i) {
                int r = i * 32 + sr;
                uint4 v = *(const uint4*)(Xbase + (size_t)r * xRow + (kc + 1) * 64 + sc * 8);
                *(uint4*)&xsbuf[((cur ^ 1) * 64 + r) * 72 + sc * 8] = v;
            }
        }
        #pragma unroll
        for (int ks = 0; ks < 2; ++ks) {
            const int k32 = kc * 2 + ks;
            bf16x8 af[4], bfr[2];
            #pragma unroll
            for (int mf = 0; mf < 4; ++mf)
                af[mf] = *(const bf16x8*)(Ab + ((size_t)(o16b + mf) * K32 + k32) * 512 + lane * 8);
            #pragma unroll
            for (int nf = 0; nf < 2; ++nf)
                bfr[nf] = *(const bf16x8*)&xsbuf[(cur * 64 + wx * 32 + nf * 16 + l15) * 72 + ks * 32 + kg * 8];
            #pragma unroll
            for (int mf = 0; mf < 4; ++mf)
                #pragma unroll
                for (int nf = 0; nf < 2; ++nf)
                    acc[mf][nf] = __builtin_amdgcn_mfma_f32_16x16x32_bf16(af[mf], bfr[nf], acc[mf][nf], 0, 0, 0);
        }
        __syncthreads();
    }

    // epilogue: stage to LDS as [px_local][o_local] bf16 (aliases xsbuf; safe
    // because main loop ended with __syncthreads()).
    #pragma unroll
    for (int nf = 0; nf < 2; ++nf) {
        const int nl = wx * 32 + nf * 16 + l15;
        float muv = 0.f, rsv = 0.f;
        if (EPI == 0) {
            muv = mu[(size_t)b * NHW + n0 + nl];
            rsv = rstd[(size_t)b * NHW + n0 + nl];
        }
        #pragma unroll
        for (int mf = 0; mf < 4; ++mf) {
            const int obl = wy * 64 + mf * 16 + kg * 4;
            float r0, r1, r2, r3;
            if (EPI == 0) {
                float4 uv = *(const float4*)(uvec + (size_t)b * uStride + om + obl);
                float4 vv = *(const float4*)(v0vec + (size_t)b * uStride + om + obl);
                r0 = rsv * (acc[mf][nf][0] - muv * uv.x) + vv.x;
                r1 = rsv * (acc[mf][nf][1] - muv * uv.y) + vv.y;
                r2 = rsv * (acc[mf][nf][2] - muv * uv.z) + vv.z;
                r3 = rsv * (acc[mf][nf][3] - muv * uv.w) + vv.w;
            } else {
                r0 = acc[mf][nf][0]; r1 = acc[mf][nf][1];
                r2 = acc[mf][nf][2]; r3 = acc[mf][nf][3];
            }
            ushort4 pk;
            pk.x = f2b(r0); pk.y = f2b(r1); pk.z = f2b(r2); pk.w = f2b(r3);
            *(ushort4*)&stg[nl][obl] = pk;
        }
    }
    __syncthreads();

    #pragma unroll
    for (int it = 0; it < 4; ++it) {
        int task = it * 256 + tid;
        int nl = task >> 4, ch = task & 15;
        int oc = om + ch * 8;
        if (oc >= Oreal) continue;
        uint4 sv = *(const uint4*)&stg[nl][ch * 8];
        size_t nglob = (size_t)b * NHW + n0 + nl;
        if (EPI == 0) {
            *(uint4*)((bfu*)Y + nglob * yRow + oc) = sv;
        } else {
            float a[8];
            a[0] = b2f((unsigned short)(sv.x & 0xffff)); a[1] = b2f((unsigned short)(sv.x >> 16));
            a[2] = b2f((unsigned short)(sv.y & 0xffff)); a[3] = b2f((unsigned short)(sv.y >> 16));
            a[4] = b2f((unsigned short)(sv.z & 0xffff)); a[5] = b2f((unsigned short)(sv.z >> 16));
            a[6] = b2f((unsigned short)(sv.w & 0xffff)); a[7] = b2f((unsigned short)(sv.w >> 16));
            if (EPI == 1) {
                F8 rv = load8((const bfu*)res + nglob * resRow + oc);
                #pragma unroll
                for (int j = 0; j < 8; ++j) a[j] += rv.v[j];
            } else {
                const float* rp = (const float*)res + nglob * resRow + oc;
                float4 q0 = *(const float4*)rp, q1 = *(const float4*)(rp + 4);
                a[0] += q0.x; a[1] += q0.y; a[2] += q0.z; a[3] += q0.w;
                a[4] += q1.x; a[5] += q1.y; a[6] += q1.z; a[7] += q1.w;
            }
            float* yp = (float*)Y + nglob * yRow + oc;
            *(float4*)yp = make_float4(a[0], a[1], a[2], a[3]);
            *(float4*)(yp + 4) = make_float4(a[4], a[5], a[6], a[7]);
        }
    }
}

// ---------------------------------------------------------------------------
// depthwise 3x3 pixel-major, thread = 8ch x 4px, column-streaming.
// ---------------------------------------------------------------------------
template<int CIN, int COUT, bool GATE>
__global__ __launch_bounds__(256) void dw_pm(
    const bfu* __restrict__ in, const float* __restrict__ wT, bfu* __restrict__ out, int cb)
{
    const int CHUNKS = COUT / 8;
    const int NPB = NHW / 4;
    int f = blockIdx.x * 256 + threadIdx.x;
    if (f >= cb * NPB * CHUNKS) return;
    int ch = f % CHUNKS;
    int pb = f / CHUNKS;
    int n4 = pb & (NPB - 1);
    int b  = pb >> 12;
    int xb = n4 & 31, y = n4 >> 5;
    int x0 = xb * 4;
    const int c8 = ch * 8;
    const bfu* rowb = in + ((size_t)b * NHW + (size_t)y * NWID) * CIN + c8;

    float a1[4][8] = {};
    float a2[4][8] = {};
    #pragma unroll
    for (int dy = -1; dy <= 1; ++dy) {
        int yy = y + dy;
        if ((unsigned)yy >= (unsigned)NWID) continue;
        const bfu* rb = rowb + (long)dy * NWID * CIN;
        float w1[3][8], w2[3][8];
        #pragma unroll
        for (int t = 0; t < 3; ++t) {
            const float* wp = wT + (size_t)((dy + 1) * 3 + t) * CIN + c8;
            *(float4*)&w1[t][0] = *(const float4*)wp;
            *(float4*)&w1[t][4] = *(const float4*)(wp + 4);
            if (GATE) {
                *(float4*)&w2[t][0] = *(const float4*)(wp + 512);
                *(float4*)&w2[t][4] = *(const float4*)(wp + 516);
            }
        }
        #pragma unroll
        for (int c = 0; c < 6; ++c) {
            int xx = x0 - 1 + c;
            if ((unsigned)xx >= (unsigned)NWID) continue;
            F8 v1 = load8(rb + (size_t)xx * CIN);
            F8 v2;
            if (GATE) v2 = load8(rb + (size_t)xx * CIN + 512);
            #pragma unroll
            for (int j = 0; j < 4; ++j) {
                int t = c - j;
                if (t < 0 || t > 2) continue;
                #pragma unroll
                for (int e = 0; e < 8; ++e) {
                    a1[j][e] = fmaf(w1[t][e], v1.v[e], a1[j][e]);
                    if (GATE) a2[j][e] = fmaf(w2[t][e], v2.v[e], a2[j][e]);
                }
            }
        }
    }
    #pragma unroll
    for (int j = 0; j < 4; ++j) {
        float r[8];
        if (GATE) {
            #pragma unroll
            for (int e = 0; e < 8; ++e) r[e] = gelu_tanh(a1[j][e]) * a2[j][e];
        } else {
            #pragma unroll
            for (int e = 0; e < 8; ++e) r[e] = a1[j][e];
        }
        store8(out + ((size_t)b * NHW + (size_t)y * NWID + x0 + j) * COUT + c8, r);
    }
}

// ---------------------------------------------------------------------------
// MFMA Gram. grid (64 n-chunks, CB). 4 waves x 2 heads each.
// ---------------------------------------------------------------------------
__global__ __launch_bounds__(256) void gram_pm(
    const bfu* __restrict__ qkv, float* __restrict__ S32,
    float* __restrict__ Q2, float* __restrict__ K2, int b0)
{
    __shared__ bfu lds[392 * 72];
    const int b = blockIdx.y;
    const int nc = blockIdx.x;
    const int tid = threadIdx.x;
    const int lane = tid & 63, wave = tid >> 6;
    const int l15 = lane & 15, kg = lane >> 4;

    f32x4 sAcc[2][2][2], qAcc[2][2], kAcc[2][2];
    #pragma unroll
    for (int h = 0; h < 2; ++h)
        #pragma unroll
        for (int i = 0; i < 2; ++i) {
            qAcc[h][i] = (f32x4){0.f, 0.f, 0.f, 0.f};
            kAcc[h][i] = (f32x4){0.f, 0.f, 0.f, 0.f};
            #pragma unroll
            for (int j = 0; j < 2; ++j) sAcc[h][i][j] = (f32x4){0.f, 0.f, 0.f, 0.f};
        }

    const size_t pbase = (size_t)b * NHW + (size_t)nc * 256;
    unsigned* ldsw = (unsigned*)lds;

    for (int it = 0; it < 4; ++it) {
        const size_t nb = pbase + it * 64;
        #pragma unroll
        for (int i = 0; i < 6; ++i) {
            int task = i * 256 + tid;
            int np = task & 31, ch = task >> 5;
            const bfu* r0 = qkv + (nb + np * 2) * CQKV + ch * 8;
            uint4 v0 = *(const uint4*)r0;
            uint4 v1 = *(const uint4*)(r0 + CQKV);
            int cb8 = ch * 8;
            ldsw[(cb8 + 0) * 36 + np] = (v0.x & 0xffffu) | (v1.x << 16);
            ldsw[(cb8 + 1) * 36 + np] = (v0.x >> 16) | (v1.x & 0xffff0000u);
            ldsw[(cb8 + 2) * 36 + np] = (v0.y & 0xffffu) | (v1.y << 16);
            ldsw[(cb8 + 3) * 36 + np] = (v0.y >> 16) | (v1.y & 0xffff0000u);
            ldsw[(cb8 + 4) * 36 + np] = (v0.z & 0xffffu) | (v1.z << 16);
            ldsw[(cb8 + 5) * 36 + np] = (v0.z >> 16) | (v1.z & 0xffff0000u);
            ldsw[(cb8 + 6) * 36 + np] = (v0.w & 0xffffu) | (v1.w << 16);
            ldsw[(cb8 + 7) * 36 + np] = (v0.w >> 16) | (v1.w & 0xffff0000u);
        }
        ldsw[(384 + (tid >> 5)) * 36 + (tid & 31)] = 0;
        __syncthreads();
        #pragma unroll
        for (int hh = 0; hh < 2; ++hh) {
            const int h = wave * 2 + hh;
            const int qr = h * NCF, kr = NC + h * NCF;
            #pragma unroll
            for (int ks = 0; ks < 2; ++ks) {
                const int nsub = ks * 32 + kg * 8;
                bf16x8 aq0 = *(const bf16x8*)(lds + (qr + l15) * 72 + nsub);
                bf16x8 aq1 = *(const bf16x8*)(lds + (qr + 16 + l15) * 72 + nsub);
                bf16x8 bk0 = *(const bf16x8*)(lds + (kr + l15) * 72 + nsub);
                bf16x8 bk1 = *(const bf16x8*)(lds + (kr + 16 + l15) * 72 + nsub);
                sAcc[hh][0][0] = __builtin_amdgcn_mfma_f32_16x16x32_bf16(aq0, bk0, sAcc[hh][0][0], 0, 0, 0);
                sAcc[hh][0][1] = __builtin_amdgcn_mfma_f32_16x16x32_bf16(aq0, bk1, sAcc[hh][0][1], 0, 0, 0);
                sAcc[hh][1][0] = __builtin_amdgcn_mfma_f32_16x16x32_bf16(aq1, bk0, sAcc[hh][1][0], 0, 0, 0);
                sAcc[hh][1][1] = __builtin_amdgcn_mfma_f32_16x16x32_bf16(aq1, bk1, sAcc[hh][1][1], 0, 0, 0);
                qAcc[hh][0] = __builtin_amdgcn_mfma_f32_16x16x32_bf16(aq0, aq0, qAcc[hh][0], 0, 0, 0);
                qAcc[hh][1] = __builtin_amdgcn_mfma_f32_16x16x32_bf16(aq1, aq1, qAcc[hh][1], 0, 0, 0);
                kAcc[hh][0] = __builtin_amdgcn_mfma_f32_16x16x32_bf16(bk0, bk0, kAcc[hh][0], 0, 0, 0);
                kAcc[hh][1] = __builtin_amdgcn_mfma_f32_16x16x32_bf16(bk1, bk1, kAcc[hh][1], 0, 0, 0);
            }
        }
        __syncthreads();
    }

    const int gb = b0 + b;
    #pragma unroll
    for (int hh = 0; hh < 2; ++hh) {
        const int h = wave * 2 + hh;
        float* Sp = S32 + ((size_t)gb * NHEADS + h) * 1024;
        #pragma unroll
        for (int mt = 0; mt < 2; ++mt)
            #pragma unroll
            for (int nt = 0; nt < 2; ++nt)
                #pragma unroll
                for (int r = 0; r < 4; ++r) {
                    int c = mt * 16 + kg * 4 + r, d = nt * 16 + l15;
                    atomicAdd(&Sp[c * 32 + d], sAcc[hh][mt][nt][r]);
                }
        #pragma unroll
        for (int t = 0; t < 2; ++t)
            #pragma unroll
            for (int r = 0; r < 4; ++r) {
                int row = t * 16 + kg * 4 + r, col = t * 16 + l15;
                if (row == col && row < NCF) {
                    atomicAdd(&Q2[((size_t)gb * NHEADS + h) * NCF + row], qAcc[hh][t][r]);
                    atomicAdd(&K2[((size_t)gb * NHEADS + h) * NCF + row], kAcc[hh][t][r]);
                }
            }
    }
}

// ---------------------------------------------------------------------------
// normalize -> softmax -> fold proj_w -> Mbf packed-fragment layout. grid(CB)
// ---------------------------------------------------------------------------
__global__ __launch_bounds__(256) void attn_fold(
    const float* __restrict__ S32, const float* __restrict__ Q2, const float* __restrict__ K2,
    const float* __restrict__ temp, const float* __restrict__ projw, bfu* __restrict__ Mbf, int b0)
{
    const int gb = b0 + blockIdx.x, tid = threadIdx.x;
    __shared__ float P[NHEADS * NCF * NCF];
    for (int e = tid; e < NHEADS * NCF * NCF; e += 256) {
        int h = e / (NCF * NCF);
        int r = e % (NCF * NCF);
        int c = r / NCF, d = r % NCF;
        float sv = S32[((size_t)gb * NHEADS + h) * 1024 + c * 32 + d];
        float rq = sqrtf(Q2[((size_t)gb * NHEADS + h) * NCF + c]);
        float rk = sqrtf(K2[((size_t)gb * NHEADS + h) * NCF + d]);
        P[e] = sv / (rq * rk) * temp[h];
    }
    __syncthreads();
    if (tid < NHEADS * NCF) {
        int h = tid / NCF, c = tid % NCF;
        float* row = P + h * (NCF * NCF) + c * NCF;
        float mx = row[0];
        #pragma unroll
        for (int d = 1; d < NCF; ++d) mx = fmaxf(mx, row[d]);
        float sum = 0.f;
        #pragma unroll
        for (int d = 0; d < NCF; ++d) { float e2 = __expf(row[d] - mx); row[d] = e2; sum += e2; }
        float inv = 1.f / sum;
        #pragma unroll
        for (int d = 0; d < NCF; ++d) row[d] *= inv;
    }
    __syncthreads();
    bfu* Mb = Mbf + (size_t)gb * OM_PAD * NC;
    if (tid < NC) {
        int o = tid;
        int o16 = o >> 4, l15o = o & 15;
        for (int h = 0; h < NHEADS; ++h) {
            float pw[NCF];
            #pragma unroll
            for (int c = 0; c < NCF; ++c) pw[c] = projw[(size_t)o * NC + h * NCF + c];
            #pragma unroll
            for (int d = 0; d < NCF; ++d) {
                float acc = 0.f;
                #pragma unroll
                for (int c = 0; c < NCF; ++c) acc = fmaf(pw[c], P[h * (NCF * NCF) + c * NCF + d], acc);
                int cc = h * NCF + d;
                int idx = (o16 * 6 + (cc >> 5)) * 512 + ((cc >> 3) & 3) * 128 + l15o * 8 + (cc & 7);
                Mb[idx] = f2b(acc);
            }
        }
    }
    // zero padded o16-tiles 12..15 (packed region [36864, 49152))
    for (int e = tid; e < (OM_PAD - NC) * NC; e += 256) Mb[NC * NC + e] = 0;
}

// ---------------------------------------------------------------------------
// final: out2 pixel-major [n][192] f32 -> d_out channel-major [192][n]
// ---------------------------------------------------------------------------
__global__ __launch_bounds__(256) void transpose_out(
    const float* __restrict__ src, float* __restrict__ dst, int cb)
{
    __shared__ float t[64][196];
    const int nb = blockIdx.x;
    const int b = blockIdx.y;
    const int tid = threadIdx.x;
    #pragma unroll
    for (int i = 0; i < 12; ++i) {
        int task = i * 256 + tid;
        int nl = task / 48, ch = task % 48;
        float4 v = *(const float4*)(src + ((size_t)b * NHW + nb * 64 + nl) * NC + ch * 4);
        *(float4*)&t[nl][ch * 4] = v;
    }
    __syncthreads();
    #pragma unroll
    for (int i = 0; i < 12; ++i) {
        int task = i * 256 + tid;
        int c = task / 16, nch = task % 16;
        float4 v = make_float4(t[nch * 4 + 0][c], t[nch * 4 + 1][c], t[nch * 4 + 2][c], t[nch * 4 + 3][c]);
        *(float4*)(dst + ((size_t)b * NC + c) * NHW + nb * 64 + nch * 4) = v;
    }
}

// ---------------------------------------------------------------------------
extern "C" void kernel_launch(void* const* d_in, const int* in_sizes, int n_in,
                              void* d_out, int out_size, void* d_ws, size_t ws_size,
                              hipStream_t stream)
{
    const float* x     = (const float*)d_in[0];
    const float* kv    = (const float*)d_in[1];
    const float* ln1w  = (const float*)d_in[2];
    const float* ln1b  = (const float*)d_in[3];
    const float* akern = (const float*)d_in[4];
    const float* qkvw  = (const float*)d_in[5];
    const float* qkvdw = (const float*)d_in[6];
    const float* projw = (const float*)d_in[7];
    const float* temp  = (const float*)d_in[8];
    const float* ln2w  = (const float*)d_in[9];
    const float* ln2b  = (const float*)d_in[10];
    const float* fkern = (const float*)d_in[11];
    const float* pinw  = (const float*)d_in[12];
    const float* ffndw = (const float*)d_in[13];
    const float* poutw = (const float*)d_in[14];
    float* out = (float*)d_out;

    char* wp = (char*)d_ws;
    size_t off = 0;
    auto take = [&](size_t bytes) {
        char* r = wp + off;
        off = (off + bytes + 255) & ~(size_t)255;
        return r;
    };
    float* mu1   = (float*)take((size_t)NB * NHW * 4);
    float* rstd1 = (float*)take((size_t)NB * NHW * 4);
    float* mu2   = (float*)take((size_t)NB * NHW * 4);
    float* rstd2 = (float*)take((size_t)NB * NHW * 4);
    float* s1 = (float*)take(NB * NC * 4);  float* t1 = (float*)take(NB * NC * 4);
    float* s2 = (float*)take(NB * NC * 4);  float* t2 = (float*)take(NB * NC * 4);
    bfu* A1 = (bfu*)take((size_t)NB * OQKV_PAD * 192 * 2);
    bfu* A2 = (bfu*)take((size_t)NB * CPIN * 192 * 2);
    bfu* A3 = (bfu*)take((size_t)OM_PAD * 512 * 2);
    bfu* Mbf = (bfu*)take((size_t)NB * OM_PAD * NC * 2);
    float* u1  = (float*)take((size_t)NB * OQKV_PAD * 4);
    float* v01 = (float*)take((size_t)NB * OQKV_PAD * 4);
    float* u2  = (float*)take((size_t)NB * CPIN * 4);
    float* v02 = (float*)take((size_t)NB * CPIN * 4);
    float* wdwT1 = (float*)take(9 * CQKV * 4);
    float* wdwT2 = (float*)take(9 * CPIN * 4);
    float* S32 = (float*)take((size_t)NB * NHEADS * 1024 * 4);
    float* Q2  = (float*)take((size_t)NB * NHEADS * NCF * 4);
    float* K2  = (float*)take((size_t)NB * NHEADS * NCF * 4);
    const size_t bigoff = off;

    const size_t PB = (size_t)NHW * (768 + 384 + 2048 + 1152);
    size_t avail = (ws_size > bigoff) ? ws_size - bigoff : 0;
    int CB = 8;
    while (CB > 1 && (size_t)CB * PB > avail) CB >>= 1;

    dim3 blk(256);

    prep_film<<<dim3(48, NB), blk, 0, stream>>>(kv, akern, ln1w, ln1b, s1, t1);
    prep_film<<<dim3(48, NB), blk, 0, stream>>>(kv, fkern, ln2w, ln2b, s2, t2);
    wprep<<<dim3(OQKV_PAD / 4, NB), blk, 0, stream>>>(qkvw, s1, t1, A1, u1, v01, 0);
    wprep<<<dim3(CPIN / 4, NB), blk, 0, stream>>>(pinw, s2, t2, A2, u2, v02, 1);
    wprep<<<dim3(OM_PAD / 4, 1), blk, 0, stream>>>(poutw, s1, t1, A3, nullptr, nullptr, 2);
    wdw_prep<<<(9 * CQKV + 255) / 256, blk, 0, stream>>>(qkvdw, wdwT1, CQKV, 0);
    wdw_prep<<<(9 * CPIN + 255) / 256, blk, 0, stream>>>(ffndw, wdwT2, CPIN, 1);
    {
        int nz = NB * NHEADS * 1024 + 2 * NB * NHEADS * NCF + 256;
        zfill<<<(nz + 255) / 256, blk, 0, stream>>>(S32, nz);
    }

    for (int b0 = 0; b0 < NB; b0 += CB) {
        float* out1 = (float*)(wp + bigoff);
        bfu* bfX   = (bfu*)(wp + bigoff + (size_t)CB * NHW * 768);
        char* big1 = wp + bigoff + (size_t)CB * NHW * (768 + 384);
        char* big2 = big1 + (size_t)CB * NHW * 2048;
        bfu* qkv_pre = (bfu*)big1;
        bfu* qkvb    = (bfu*)big2;
        bfu* u_pre   = (bfu*)big1;
        bfu* gbuf    = (bfu*)big2;
        float* out2  = (float*)big1;

        const float* xb = x + (size_t)b0 * NC * NHW;
        float* mu1b = mu1 + (size_t)b0 * NHW;   float* rs1b = rstd1 + (size_t)b0 * NHW;
        float* mu2b = mu2 + (size_t)b0 * NHW;   float* rs2b = rstd2 + (size_t)b0 * NHW;

        // ---- attention branch ----
        ln_cvt_cm<<<CB * 64, blk, 0, stream>>>(xb, mu1b, rs1b, bfX, CB);
        gemm_pm<0><<<dim3(256, OQKV_PAD / 128, CB), blk, 0, stream>>>(
            A1 + (size_t)b0 * OQKV_PAD * 192, (long)OQKV_PAD * 192, OQKV_PAD, CQKV, 192,
            bfX, NC, 0, qkv_pre, CQKV, nullptr, 0,
            mu1b, rs1b, u1 + (size_t)b0 * OQKV_PAD, v01 + (size_t)b0 * OQKV_PAD, OQKV_PAD);
        dw_pm<CQKV, CQKV, false><<<CB * (NHW / 4) * (CQKV / 8) / 256, blk, 0, stream>>>(
            qkv_pre, wdwT1, qkvb, CB);
        gram_pm<<<dim3(64, CB), blk, 0, stream>>>(qkvb, S32, Q2, K2, b0);
        attn_fold<<<CB, blk, 0, stream>>>(S32, Q2, K2, temp, projw, Mbf, b0);
        gemm_pm<1><<<dim3(256, OM_PAD / 128, CB), blk, 0, stream>>>(
            Mbf + (size_t)b0 * OM_PAD * NC, (long)OM_PAD * NC, OM_PAD, NC, 192,
            qkvb, CQKV, 384, out1, NC, bfX, NC,
            nullptr, nullptr, nullptr, nullptr, 0);

        // ---- FFN branch ----
        ln_cvt_pm<<<CB * 64, blk, 0, stream>>>(out1, mu2b, rs2b, bfX, CB);
        gemm_pm<0><<<dim3(256, CPIN / 128, CB), blk, 0, stream>>>(
            A2 + (size_t)b0 * CPIN * 192, (long)CPIN * 192, CPIN, CPIN, 192,
            bfX, NC, 0, u_pre, CPIN, nullptr, 0,
            mu2b, rs2b, u2 + (size_t)b0 * CPIN, v02 + (size_t)b0 * CPIN, CPIN);
        dw_pm<CPIN, CG, true><<<CB * (NHW / 4) * (CG / 8) / 256, blk, 0, stream>>>(
            u_pre, wdwT2, gbuf, CB);
        gemm_pm<2><<<dim3(256, OM_PAD / 128, CB), blk, 0, stream>>>(
            A3, 0, OM_PAD, NC, 512,
            gbuf, CG, 0, out2, NC, out1, NC,
            nullptr, nullptr, nullptr, nullptr, 0);
        transpose_out<<<dim3(256, CB), blk, 0, stream>>>(out2, out + (size_t)b0 * NC * NHW, CB);
    }
}

// Round 7
// 836.072 us; speedup vs baseline: 3.3751x; 1.1122x over previous
//
#include <hip/hip_runtime.h>
#include <math.h>

#define NB 8
#define NC 192
#define NHEADS 8
#define NCF 24
#define NHW 16384
#define NWID 128
#define CQKV 576
#define OQKV_PAD 640
#define CPIN 1024
#define CG 512
#define OM_PAD 256

typedef unsigned short bfu;
typedef __bf16 bf16x8 __attribute__((ext_vector_type(8)));
typedef float f32x4 __attribute__((ext_vector_type(4)));

__device__ __forceinline__ float b2f(unsigned short u) { return __uint_as_float(((unsigned)u) << 16); }
__device__ __forceinline__ unsigned short f2b(float f) {
    unsigned u = __float_as_uint(f);
    u += 0x7FFFu + ((u >> 16) & 1u);
    return (unsigned short)(u >> 16);
}
// tanh-based GELU (max |err| vs exact ~3e-4; threshold margin ample)
__device__ __forceinline__ float gelu_tanh(float x) {
    float x3 = x * x * x;
    float z = 0.7978845608028654f * fmaf(0.044715f, x3, x);
    float e = __expf(2.f * z);
    float th = 1.f - 2.f / (e + 1.f);
    return 0.5f * x * (1.f + th);
}

struct F8 { float v[8]; };
__device__ __forceinline__ F8 load8(const bfu* p) {
    uint4 r = *(const uint4*)p;
    F8 o;
    o.v[0] = b2f((unsigned short)(r.x & 0xffff)); o.v[1] = b2f((unsigned short)(r.x >> 16));
    o.v[2] = b2f((unsigned short)(r.y & 0xffff)); o.v[3] = b2f((unsigned short)(r.y >> 16));
    o.v[4] = b2f((unsigned short)(r.z & 0xffff)); o.v[5] = b2f((unsigned short)(r.z >> 16));
    o.v[6] = b2f((unsigned short)(r.w & 0xffff)); o.v[7] = b2f((unsigned short)(r.w >> 16));
    return o;
}
__device__ __forceinline__ void store8(bfu* p, const float* a) {
    uint4 r;
    r.x = (unsigned)f2b(a[0]) | ((unsigned)f2b(a[1]) << 16);
    r.y = (unsigned)f2b(a[2]) | ((unsigned)f2b(a[3]) << 16);
    r.z = (unsigned)f2b(a[4]) | ((unsigned)f2b(a[5]) << 16);
    r.w = (unsigned)f2b(a[6]) | ((unsigned)f2b(a[7]) << 16);
    *(uint4*)p = r;
}

__global__ __launch_bounds__(256) void zfill(float* __restrict__ p, int n) {
    int i = blockIdx.x * 256 + threadIdx.x;
    if (i < n) p[i] = 0.f;
}

// ---------------------------------------------------------------------------
// prep_film, wave-parallel. grid (48, NB) x 256.
// ---------------------------------------------------------------------------
__global__ __launch_bounds__(256) void prep_film(
    const float* __restrict__ kv, const float* __restrict__ kern,
    const float* __restrict__ lnw, const float* __restrict__ lnb,
    float* __restrict__ sArr, float* __restrict__ tArr)
{
    const int b = blockIdx.y;
    const int wave = threadIdx.x >> 6, lane = threadIdx.x & 63;
    const int r = blockIdx.x * 4 + wave;
    const float* kvb = kv + b * 256;
    float4 kvv = *(const float4*)(kvb + lane * 4);
    float4 k1 = *(const float4*)(kern + (size_t)r * 256 + lane * 4);
    float4 k2 = *(const float4*)(kern + (size_t)(r + NC) * 256 + lane * 4);
    float d1 = kvv.x * k1.x + kvv.y * k1.y + kvv.z * k1.z + kvv.w * k1.w;
    float d2 = kvv.x * k2.x + kvv.y * k2.y + kvv.z * k2.z + kvv.w * k2.w;
    #pragma unroll
    for (int off = 32; off; off >>= 1) {
        d1 += __shfl_down(d1, off, 64);
        d2 += __shfl_down(d2, off, 64);
    }
    if (lane == 0) {
        sArr[b * NC + r] = lnw[r] * d1;
        tArr[b * NC + r] = lnb[r] * d1 + d2;
    }
}

// ---------------------------------------------------------------------------
// Build bf16 A in MFMA-fragment-packed layout:
//   frag = (o/16)*K32 + (c/32); within = ((c>>3)&3)*128 + (o&15)*8 + (c&7)
// + u=sum(bf16 A row), v0=W@t. Wave-per-row.
// ---------------------------------------------------------------------------
__global__ __launch_bounds__(256) void wprep(
    const float* __restrict__ W, const float* __restrict__ sA, const float* __restrict__ tA,
    bfu* __restrict__ Abf, float* __restrict__ u, float* __restrict__ v0, int mode)
{
    const int wave = threadIdx.x >> 6, lane = threadIdx.x & 63;
    const int o = blockIdx.x * 4 + wave;
    const int b = blockIdx.y;
    const int Opad = (mode == 0) ? OQKV_PAD : (mode == 1 ? CPIN : OM_PAD);
    const int K = (mode == 2) ? 512 : 192;
    const int Kr = (mode == 2) ? 510 : 192;
    const int K32 = K >> 5;
    int src;
    if (mode == 0) src = (o < 576) ? o : -1;
    else if (mode == 1) src = (o < 510) ? o : (o < 512 ? -1 : (o < 1022 ? o - 2 : -1));
    else src = (o < 192) ? o : -1;
    const float* wr = (src >= 0) ? W + (size_t)src * Kr : nullptr;
    const float* sb = sA + b * NC;
    const float* tb = tA + b * NC;
    bfu* abase = Abf + (size_t)b * Opad * K;
    float au = 0.f, av = 0.f;
    for (int c0 = lane * 4; c0 < K; c0 += 256) {
        float a[4] = {0.f, 0.f, 0.f, 0.f};
        if (src >= 0) {
            #pragma unroll
            for (int j = 0; j < 4; ++j) {
                int c = c0 + j;
                if (c < Kr) {
                    float w = wr[c];
                    if (mode == 2) a[j] = w;
                    else { a[j] = w * sb[c]; av = fmaf(w, tb[c], av); }
                }
            }
        }
        ushort4 pk;
        bfu b0 = f2b(a[0]), b1 = f2b(a[1]), b2 = f2b(a[2]), b3 = f2b(a[3]);
        pk.x = b0; pk.y = b1; pk.z = b2; pk.w = b3;
        au += b2f(b0) + b2f(b1) + b2f(b2) + b2f(b3);
        int frag = (o >> 4) * K32 + (c0 >> 5);
        int within = ((c0 >> 3) & 3) * 128 + (o & 15) * 8 + (c0 & 7);
        *(ushort4*)(abase + (size_t)frag * 512 + within) = pk;
    }
    if (mode < 2) {
        #pragma unroll
        for (int off = 32; off; off >>= 1) {
            au += __shfl_down(au, off, 64);
            av += __shfl_down(av, off, 64);
        }
        if (lane == 0) {
            u[(size_t)b * Opad + o] = au;
            v0[(size_t)b * Opad + o] = (src >= 0) ? av : 0.f;
        }
    }
}

// transpose dw weights: mode 0: [C][9]->[9][C]; mode 1: ffn remap to [9][1024]
__global__ __launch_bounds__(256) void wdw_prep(
    const float* __restrict__ src, float* __restrict__ dstT, int C, int mode)
{
    int i = blockIdx.x * 256 + threadIdx.x;
    if (i >= 9 * C) return;
    int tap = i / C, col = i % C;
    float v;
    if (mode == 0) v = src[(size_t)col * 9 + tap];
    else {
        if (col < 512) v = (col < 510) ? src[(size_t)col * 9 + tap] : 0.f;
        else { int c2 = col - 512; v = (c2 < 510) ? src[(size_t)(510 + c2) * 9 + tap] : 0.f; }
    }
    dstT[(size_t)tap * C + col] = v;
}

// ---------------------------------------------------------------------------
// LN stats + bf16 convert, channel-major fp32 in -> pixel-major bf16 out,
// fully coalesced via LDS transpose. Block = 64 px. grid CB*256.
// ---------------------------------------------------------------------------
__global__ __launch_bounds__(256) void ln_cvt_cm(
    const float* __restrict__ x, float* __restrict__ mu, float* __restrict__ rstd,
    bfu* __restrict__ xbf, int cb)
{
    __shared__ bfu lt[64][198];
    const int blkpx = blockIdx.x;
    const int b = blkpx >> 8;
    const int n0 = (blkpx & 255) * 64;
    const int tid = threadIdx.x;
    // phase 1: coalesced channel-major loads -> LDS transpose
    #pragma unroll
    for (int it = 0; it < 12; ++it) {
        int task = it * 256 + tid;       // 3072 = 192c x 16 quads
        int c = task >> 4, q = task & 15;
        float4 v = *(const float4*)(x + ((size_t)b * NC + c) * NHW + n0 + q * 4);
        lt[q * 4 + 0][c] = f2b(v.x);
        lt[q * 4 + 1][c] = f2b(v.y);
        lt[q * 4 + 2][c] = f2b(v.z);
        lt[q * 4 + 3][c] = f2b(v.w);
    }
    __syncthreads();
    // phase 2: per-pixel stats (4 threads/px)
    {
        int px = tid >> 2, part = tid & 3;
        const unsigned* row = (const unsigned*)&lt[px][0];
        float s = 0.f, ss = 0.f;
        #pragma unroll
        for (int i = 0; i < 24; ++i) {
            unsigned w = row[part * 24 + i];
            float a = b2f((unsigned short)(w & 0xffff));
            float bb = b2f((unsigned short)(w >> 16));
            s += a + bb; ss = fmaf(a, a, ss); ss = fmaf(bb, bb, ss);
        }
        s += __shfl_down(s, 2, 4); ss += __shfl_down(ss, 2, 4);
        s += __shfl_down(s, 1, 4); ss += __shfl_down(ss, 1, 4);
        if (part == 0) {
            int idx = b * NHW + n0 + px;
            float m = s * (1.f / 192.f);
            float var = ss * (1.f / 192.f) - m * m;
            mu[idx] = m;
            rstd[idx] = rsqrtf(var + 1e-5f);
        }
    }
    // phase 3: coalesced pixel-major row writes
    #pragma unroll
    for (int it = 0; it < 6; ++it) {
        int task = it * 256 + tid;       // 1536 = 64px x 24 chunks
        int px = task / 24, ckk = task % 24;
        const unsigned* row = (const unsigned*)&lt[px][0];
        uint4 o;
        o.x = row[ckk * 4 + 0]; o.y = row[ckk * 4 + 1];
        o.z = row[ckk * 4 + 2]; o.w = row[ckk * 4 + 3];
        *(uint4*)(xbf + ((size_t)b * NHW + n0 + px) * NC + ckk * 8) = o;
    }
}

// ---------------------------------------------------------------------------
// LN stats only, pixel-major bf16 input (out1). 8 lanes per pixel.
// grid CB*512 x 256.
// ---------------------------------------------------------------------------
__global__ __launch_bounds__(256) void ln_stats_pm8(
    const bfu* __restrict__ xpm, float* __restrict__ mu, float* __restrict__ rstd, int cb)
{
    int gt = blockIdx.x * 256 + threadIdx.x;
    int px = gt >> 3, seg = gt & 7;
    if (px >= cb * NHW) return;
    const bfu* row = xpm + (size_t)px * NC;
    float s = 0.f, ss = 0.f;
    #pragma unroll
    for (int it = 0; it < 3; ++it) {
        F8 v = load8(row + (seg + it * 8) * 8);
        #pragma unroll
        for (int j = 0; j < 8; ++j) { s += v.v[j]; ss = fmaf(v.v[j], v.v[j], ss); }
    }
    #pragma unroll
    for (int off = 4; off; off >>= 1) {
        s += __shfl_down(s, off, 8);
        ss += __shfl_down(ss, off, 8);
    }
    if (seg == 0) {
        float m = s * (1.f / 192.f);
        float var = ss * (1.f / 192.f) - m * m;
        mu[px] = m;
        rstd[px] = rsqrtf(var + 1e-5f);
    }
}

// ---------------------------------------------------------------------------
// MFMA GEMM: A fragment-packed, X staged via LDS (BK=64, double-buffered).
// Block = 4 waves (2o x 2n), tile 128o x 64px. grid (NHW/64, Opad/128, CB).
// EPI 0: LN epilogue -> bf16 pixel-major
// EPI 1: + bf16 res  -> bf16 pixel-major
// EPI 3: + bf16 res  -> f32 CHANNEL-major (direct d_out write, no transpose)
// ---------------------------------------------------------------------------
template<int EPI>
__global__ __launch_bounds__(256) void gemm_pm(
    const bfu* __restrict__ A, long aBStride, int Opad, int Oreal, int K,
    const bfu* __restrict__ X, int xRow, int xOff,
    void* __restrict__ Y, int yRow,
    const void* __restrict__ res, int resRow,
    const float* __restrict__ mu, const float* __restrict__ rstd,
    const float* __restrict__ uvec, const float* __restrict__ v0vec, int uStride)
{
    constexpr int SMEM = (EPI == 3) ? (64 * 129 * 4) : (2 * 64 * 72 * 2);
    __shared__ __align__(16) char smem[SMEM];
    bfu* xsbuf = (bfu*)smem;
    bfu (*stg)[136] = (bfu(*)[136])smem;     // 17408 B (EPI 0/1)
    float (*stg32)[129] = (float(*)[129])smem; // 33024 B (EPI 3)

    const int b = blockIdx.z;
    const int om = blockIdx.y * 128;
    const int n0 = blockIdx.x * 64;
    const int tid = threadIdx.x;
    const int lane = tid & 63, wave = tid >> 6;
    const int wy = wave >> 1, wx = wave & 1;
    const int l15 = lane & 15, kg = lane >> 4;
    const int K32 = K >> 5;
    const int NCH = K >> 6;
    const int o16b = (om >> 4) + wy * 4;

    const bfu* Ab = A + (size_t)b * aBStride;
    const bfu* Xbase = X + ((size_t)b * NHW + n0) * xRow + xOff;
    const int sr = tid >> 3, sc = tid & 7;

    f32x4 acc[4][2];
    #pragma unroll
    for (int i = 0; i < 4; ++i)
        #pragma unroll
        for (int j = 0; j < 2; ++j) acc[i][j] = (f32x4){0.f, 0.f, 0.f, 0.f};

    #pragma unroll
    for (int i = 0; i < 2; ++i) {
        int r = i * 32 + sr;
        uint4 v = *(const uint4*)(Xbase + (size_t)r * xRow + sc * 8);
        *(uint4*)&xsbuf[(r) * 72 + sc * 8] = v;
    }
    __syncthreads();

    for (int kc = 0; kc < NCH; ++kc) {
        const int cur = kc & 1;
        if (kc + 1 < NCH) {
            #pragma unroll
            for (int i = 0; i < 2; ++i) {
                int r = i * 32 + sr;
                uint4 v = *(const uint4*)(Xbase + (size_t)r * xRow + (kc + 1) * 64 + sc * 8);
                *(uint4*)&xsbuf[((cur ^ 1) * 64 + r) * 72 + sc * 8] = v;
            }
        }
        #pragma unroll
        for (int ks = 0; ks < 2; ++ks) {
            const int k32 = kc * 2 + ks;
            bf16x8 af[4], bfr[2];
            #pragma unroll
            for (int mf = 0; mf < 4; ++mf)
                af[mf] = *(const bf16x8*)(Ab + ((size_t)(o16b + mf) * K32 + k32) * 512 + lane * 8);
            #pragma unroll
            for (int nf = 0; nf < 2; ++nf)
                bfr[nf] = *(const bf16x8*)&xsbuf[(cur * 64 + wx * 32 + nf * 16 + l15) * 72 + ks * 32 + kg * 8];
            #pragma unroll
            for (int mf = 0; mf < 4; ++mf)
                #pragma unroll
                for (int nf = 0; nf < 2; ++nf)
                    acc[mf][nf] = __builtin_amdgcn_mfma_f32_16x16x32_bf16(af[mf], bfr[nf], acc[mf][nf], 0, 0, 0);
        }
        __syncthreads();
    }

    // ---- stage accumulators to LDS ----
    #pragma unroll
    for (int nf = 0; nf < 2; ++nf) {
        const int nl = wx * 32 + nf * 16 + l15;
        float muv = 0.f, rsv = 0.f;
        if (EPI == 0) {
            muv = mu[(size_t)b * NHW + n0 + nl];
            rsv = rstd[(size_t)b * NHW + n0 + nl];
        }
        #pragma unroll
        for (int mf = 0; mf < 4; ++mf) {
            const int obl = wy * 64 + mf * 16 + kg * 4;
            if (EPI == 3) {
                stg32[nl][obl + 0] = acc[mf][nf][0];
                stg32[nl][obl + 1] = acc[mf][nf][1];
                stg32[nl][obl + 2] = acc[mf][nf][2];
                stg32[nl][obl + 3] = acc[mf][nf][3];
            } else {
                float r0, r1, r2, r3;
                if (EPI == 0) {
                    float4 uv = *(const float4*)(uvec + (size_t)b * uStride + om + obl);
                    float4 vv = *(const float4*)(v0vec + (size_t)b * uStride + om + obl);
                    r0 = rsv * (acc[mf][nf][0] - muv * uv.x) + vv.x;
                    r1 = rsv * (acc[mf][nf][1] - muv * uv.y) + vv.y;
                    r2 = rsv * (acc[mf][nf][2] - muv * uv.z) + vv.z;
                    r3 = rsv * (acc[mf][nf][3] - muv * uv.w) + vv.w;
                } else {
                    r0 = acc[mf][nf][0]; r1 = acc[mf][nf][1];
                    r2 = acc[mf][nf][2]; r3 = acc[mf][nf][3];
                }
                ushort4 pk;
                pk.x = f2b(r0); pk.y = f2b(r1); pk.z = f2b(r2); pk.w = f2b(r3);
                *(ushort4*)&stg[nl][obl] = pk;
            }
        }
    }
    __syncthreads();

    // ---- writeout ----
    if (EPI == 3) {
        // channel-major f32: 16 consecutive threads share o, cover 64 px.
        #pragma unroll
        for (int it = 0; it < 8; ++it) {
            int task = it * 256 + tid;
            int o = task >> 4, q = task & 15;
            int oc = om + o;
            if (oc >= Oreal) continue;
            float vals[4];
            #pragma unroll
            for (int j = 0; j < 4; ++j) {
                float v = stg32[q * 4 + j][o];
                float r = b2f(((const bfu*)res)[((size_t)b * NHW + n0 + q * 4 + j) * resRow + oc]);
                vals[j] = v + r;
            }
            *(float4*)((float*)Y + ((size_t)b * NC + oc) * NHW + n0 + q * 4) =
                make_float4(vals[0], vals[1], vals[2], vals[3]);
        }
    } else {
        #pragma unroll
        for (int it = 0; it < 4; ++it) {
            int task = it * 256 + tid;
            int nl = task >> 4, ch = task & 15;
            int oc = om + ch * 8;
            if (oc >= Oreal) continue;
            uint4 sv = *(const uint4*)&stg[nl][ch * 8];
            size_t nglob = (size_t)b * NHW + n0 + nl;
            if (EPI == 0) {
                *(uint4*)((bfu*)Y + nglob * yRow + oc) = sv;
            } else {  // EPI 1: + bf16 res -> bf16
                float a[8];
                a[0] = b2f((unsigned short)(sv.x & 0xffff)); a[1] = b2f((unsigned short)(sv.x >> 16));
                a[2] = b2f((unsigned short)(sv.y & 0xffff)); a[3] = b2f((unsigned short)(sv.y >> 16));
                a[4] = b2f((unsigned short)(sv.z & 0xffff)); a[5] = b2f((unsigned short)(sv.z >> 16));
                a[6] = b2f((unsigned short)(sv.w & 0xffff)); a[7] = b2f((unsigned short)(sv.w >> 16));
                F8 rv = load8((const bfu*)res + nglob * resRow + oc);
                #pragma unroll
                for (int j = 0; j < 8; ++j) a[j] += rv.v[j];
                store8((bfu*)Y + nglob * yRow + oc, a);
            }
        }
    }
}

// ---------------------------------------------------------------------------
// depthwise 3x3 pixel-major, thread = 8ch x 8px, column-streaming (no gate).
// grid: cb * (NHW/8) * (CIN/8) / 256.
// ---------------------------------------------------------------------------
template<int CIN>
__global__ __launch_bounds__(256) void dw_pm8(
    const bfu* __restrict__ in, const float* __restrict__ wT, bfu* __restrict__ out, int cb)
{
    const int CHUNKS = CIN / 8;
    const int NPB = NHW / 8;
    int f = blockIdx.x * 256 + threadIdx.x;
    if (f >= cb * NPB * CHUNKS) return;
    int ch = f % CHUNKS;
    int pb = f / CHUNKS;
    int n8 = pb & (NPB - 1);
    int b  = pb >> 11;
    int xq = n8 & 15, y = n8 >> 4;
    int x0 = xq * 8;
    const int c8 = ch * 8;
    const bfu* rowb = in + ((size_t)b * NHW + (size_t)y * NWID) * CIN + c8;

    float acc[8][8] = {};
    #pragma unroll
    for (int dy = -1; dy <= 1; ++dy) {
        int yy = y + dy;
        if ((unsigned)yy >= (unsigned)NWID) continue;
        const bfu* rb = rowb + (long)dy * NWID * CIN;
        float w1[3][8];
        #pragma unroll
        for (int t = 0; t < 3; ++t) {
            const float* wp = wT + (size_t)((dy + 1) * 3 + t) * CIN + c8;
            *(float4*)&w1[t][0] = *(const float4*)wp;
            *(float4*)&w1[t][4] = *(const float4*)(wp + 4);
        }
        #pragma unroll
        for (int c = 0; c < 10; ++c) {
            int xx = x0 - 1 + c;
            if ((unsigned)xx >= (unsigned)NWID) continue;
            F8 v = load8(rb + (size_t)xx * CIN);
            #pragma unroll
            for (int j = 0; j < 8; ++j) {
                int t = c - j;
                if (t < 0 || t > 2) continue;
                #pragma unroll
                for (int e = 0; e < 8; ++e)
                    acc[j][e] = fmaf(w1[t][e], v.v[e], acc[j][e]);
            }
        }
    }
    #pragma unroll
    for (int j = 0; j < 8; ++j)
        store8(out + ((size_t)b * NHW + (size_t)y * NWID + x0 + j) * CIN + c8, acc[j]);
}

// ---------------------------------------------------------------------------
// depthwise 3x3 + GELU gate, thread = 8ch x 4px (FFN path).
// ---------------------------------------------------------------------------
template<int CIN, int COUT>
__global__ __launch_bounds__(256) void dw_gate(
    const bfu* __restrict__ in, const float* __restrict__ wT, bfu* __restrict__ out, int cb)
{
    const int CHUNKS = COUT / 8;
    const int NPB = NHW / 4;
    int f = blockIdx.x * 256 + threadIdx.x;
    if (f >= cb * NPB * CHUNKS) return;
    int ch = f % CHUNKS;
    int pb = f / CHUNKS;
    int n4 = pb & (NPB - 1);
    int b  = pb >> 12;
    int xb = n4 & 31, y = n4 >> 5;
    int x0 = xb * 4;
    const int c8 = ch * 8;
    const bfu* rowb = in + ((size_t)b * NHW + (size_t)y * NWID) * CIN + c8;

    float a1[4][8] = {};
    float a2[4][8] = {};
    #pragma unroll
    for (int dy = -1; dy <= 1; ++dy) {
        int yy = y + dy;
        if ((unsigned)yy >= (unsigned)NWID) continue;
        const bfu* rb = rowb + (long)dy * NWID * CIN;
        float w1[3][8], w2[3][8];
        #pragma unroll
        for (int t = 0; t < 3; ++t) {
            const float* wp = wT + (size_t)((dy + 1) * 3 + t) * CIN + c8;
            *(float4*)&w1[t][0] = *(const float4*)wp;
            *(float4*)&w1[t][4] = *(const float4*)(wp + 4);
            *(float4*)&w2[t][0] = *(const float4*)(wp + 512);
            *(float4*)&w2[t][4] = *(const float4*)(wp + 516);
        }
        #pragma unroll
        for (int c = 0; c < 6; ++c) {
            int xx = x0 - 1 + c;
            if ((unsigned)xx >= (unsigned)NWID) continue;
            F8 v1 = load8(rb + (size_t)xx * CIN);
            F8 v2 = load8(rb + (size_t)xx * CIN + 512);
            #pragma unroll
            for (int j = 0; j < 4; ++j) {
                int t = c - j;
                if (t < 0 || t > 2) continue;
                #pragma unroll
                for (int e = 0; e < 8; ++e) {
                    a1[j][e] = fmaf(w1[t][e], v1.v[e], a1[j][e]);
                    a2[j][e] = fmaf(w2[t][e], v2.v[e], a2[j][e]);
                }
            }
        }
    }
    #pragma unroll
    for (int j = 0; j < 4; ++j) {
        float r[8];
        #pragma unroll
        for (int e = 0; e < 8; ++e) r[e] = gelu_tanh(a1[j][e]) * a2[j][e];
        store8(out + ((size_t)b * NHW + (size_t)y * NWID + x0 + j) * COUT + c8, r);
    }
}

// ---------------------------------------------------------------------------
// MFMA Gram. grid (64 n-chunks, CB). 4 waves x 2 heads each.
// ---------------------------------------------------------------------------
__global__ __launch_bounds__(256) void gram_pm(
    const bfu* __restrict__ qkv, float* __restrict__ S32,
    float* __restrict__ Q2, float* __restrict__ K2, int b0)
{
    __shared__ bfu lds[392 * 72];
    const int b = blockIdx.y;
    const int nc = blockIdx.x;
    const int tid = threadIdx.x;
    const int lane = tid & 63, wave = tid >> 6;
    const int l15 = lane & 15, kg = lane >> 4;

    f32x4 sAcc[2][2][2], qAcc[2][2], kAcc[2][2];
    #pragma unroll
    for (int h = 0; h < 2; ++h)
        #pragma unroll
        for (int i = 0; i < 2; ++i) {
            qAcc[h][i] = (f32x4){0.f, 0.f, 0.f, 0.f};
            kAcc[h][i] = (f32x4){0.f, 0.f, 0.f, 0.f};
            #pragma unroll
            for (int j = 0; j < 2; ++j) sAcc[h][i][j] = (f32x4){0.f, 0.f, 0.f, 0.f};
        }

    const size_t pbase = (size_t)b * NHW + (size_t)nc * 256;
    unsigned* ldsw = (unsigned*)lds;

    for (int it = 0; it < 4; ++it) {
        const size_t nb = pbase + it * 64;
        #pragma unroll
        for (int i = 0; i < 6; ++i) {
            int task = i * 256 + tid;
            int np = task & 31, ch = task >> 5;
            const bfu* r0 = qkv + (nb + np * 2) * CQKV + ch * 8;
            uint4 v0 = *(const uint4*)r0;
            uint4 v1 = *(const uint4*)(r0 + CQKV);
            int cb8 = ch * 8;
            ldsw[(cb8 + 0) * 36 + np] = (v0.x & 0xffffu) | (v1.x << 16);
            ldsw[(cb8 + 1) * 36 + np] = (v0.x >> 16) | (v1.x & 0xffff0000u);
            ldsw[(cb8 + 2) * 36 + np] = (v0.y & 0xffffu) | (v1.y << 16);
            ldsw[(cb8 + 3) * 36 + np] = (v0.y >> 16) | (v1.y & 0xffff0000u);
            ldsw[(cb8 + 4) * 36 + np] = (v0.z & 0xffffu) | (v1.z << 16);
            ldsw[(cb8 + 5) * 36 + np] = (v0.z >> 16) | (v1.z & 0xffff0000u);
            ldsw[(cb8 + 6) * 36 + np] = (v0.w & 0xffffu) | (v1.w << 16);
            ldsw[(cb8 + 7) * 36 + np] = (v0.w >> 16) | (v1.w & 0xffff0000u);
        }
        ldsw[(384 + (tid >> 5)) * 36 + (tid & 31)] = 0;
        __syncthreads();
        #pragma unroll
        for (int hh = 0; hh < 2; ++hh) {
            const int h = wave * 2 + hh;
            const int qr = h * NCF, kr = NC + h * NCF;
            #pragma unroll
            for (int ks = 0; ks < 2; ++ks) {
                const int nsub = ks * 32 + kg * 8;
                bf16x8 aq0 = *(const bf16x8*)(lds + (qr + l15) * 72 + nsub);
                bf16x8 aq1 = *(const bf16x8*)(lds + (qr + 16 + l15) * 72 + nsub);
                bf16x8 bk0 = *(const bf16x8*)(lds + (kr + l15) * 72 + nsub);
                bf16x8 bk1 = *(const bf16x8*)(lds + (kr + 16 + l15) * 72 + nsub);
                sAcc[hh][0][0] = __builtin_amdgcn_mfma_f32_16x16x32_bf16(aq0, bk0, sAcc[hh][0][0], 0, 0, 0);
                sAcc[hh][0][1] = __builtin_amdgcn_mfma_f32_16x16x32_bf16(aq0, bk1, sAcc[hh][0][1], 0, 0, 0);
                sAcc[hh][1][0] = __builtin_amdgcn_mfma_f32_16x16x32_bf16(aq1, bk0, sAcc[hh][1][0], 0, 0, 0);
                sAcc[hh][1][1] = __builtin_amdgcn_mfma_f32_16x16x32_bf16(aq1, bk1, sAcc[hh][1][1], 0, 0, 0);
                qAcc[hh][0] = __builtin_amdgcn_mfma_f32_16x16x32_bf16(aq0, aq0, qAcc[hh][0], 0, 0, 0);
                qAcc[hh][1] = __builtin_amdgcn_mfma_f32_16x16x32_bf16(aq1, aq1, qAcc[hh][1], 0, 0, 0);
                kAcc[hh][0] = __builtin_amdgcn_mfma_f32_16x16x32_bf16(bk0, bk0, kAcc[hh][0], 0, 0, 0);
                kAcc[hh][1] = __builtin_amdgcn_mfma_f32_16x16x32_bf16(bk1, bk1, kAcc[hh][1], 0, 0, 0);
            }
        }
        __syncthreads();
    }

    const int gb = b0 + b;
    #pragma unroll
    for (int hh = 0; hh < 2; ++hh) {
        const int h = wave * 2 + hh;
        float* Sp = S32 + ((size_t)gb * NHEADS + h) * 1024;
        #pragma unroll
        for (int mt = 0; mt < 2; ++mt)
            #pragma unroll
            for (int nt = 0; nt < 2; ++nt)
                #pragma unroll
                for (int r = 0; r < 4; ++r) {
                    int c = mt * 16 + kg * 4 + r, d = nt * 16 + l15;
                    atomicAdd(&Sp[c * 32 + d], sAcc[hh][mt][nt][r]);
                }
        #pragma unroll
        for (int t = 0; t < 2; ++t)
            #pragma unroll
            for (int r = 0; r < 4; ++r) {
                int row = t * 16 + kg * 4 + r, col = t * 16 + l15;
                if (row == col && row < NCF) {
                    atomicAdd(&Q2[((size_t)gb * NHEADS + h) * NCF + row], qAcc[hh][t][r]);
                    atomicAdd(&K2[((size_t)gb * NHEADS + h) * NCF + row], kAcc[hh][t][r]);
                }
            }
    }
}

// ---------------------------------------------------------------------------
// normalize -> softmax -> fold proj_w -> Mbf packed-fragment layout. grid(CB)
// ---------------------------------------------------------------------------
__global__ __launch_bounds__(256) void attn_fold(
    const float* __restrict__ S32, const float* __restrict__ Q2, const float* __restrict__ K2,
    const float* __restrict__ temp, const float* __restrict__ projw, bfu* __restrict__ Mbf, int b0)
{
    const int gb = b0 + blockIdx.x, tid = threadIdx.x;
    __shared__ float P[NHEADS * NCF * NCF];
    for (int e = tid; e < NHEADS * NCF * NCF; e += 256) {
        int h = e / (NCF * NCF);
        int r = e % (NCF * NCF);
        int c = r / NCF, d = r % NCF;
        float sv = S32[((size_t)gb * NHEADS + h) * 1024 + c * 32 + d];
        float rq = sqrtf(Q2[((size_t)gb * NHEADS + h) * NCF + c]);
        float rk = sqrtf(K2[((size_t)gb * NHEADS + h) * NCF + d]);
        P[e] = sv / (rq * rk) * temp[h];
    }
    __syncthreads();
    if (tid < NHEADS * NCF) {
        int h = tid / NCF, c = tid % NCF;
        float* row = P + h * (NCF * NCF) + c * NCF;
        float mx = row[0];
        #pragma unroll
        for (int d = 1; d < NCF; ++d) mx = fmaxf(mx, row[d]);
        float sum = 0.f;
        #pragma unroll
        for (int d = 0; d < NCF; ++d) { float e2 = __expf(row[d] - mx); row[d] = e2; sum += e2; }
        float inv = 1.f / sum;
        #pragma unroll
        for (int d = 0; d < NCF; ++d) row[d] *= inv;
    }
    __syncthreads();
    bfu* Mb = Mbf + (size_t)gb * OM_PAD * NC;
    if (tid < NC) {
        int o = tid;
        int o16 = o >> 4, l15o = o & 15;
        for (int h = 0; h < NHEADS; ++h) {
            float pw[NCF];
            #pragma unroll
            for (int c = 0; c < NCF; ++c) pw[c] = projw[(size_t)o * NC + h * NCF + c];
            #pragma unroll
            for (int d = 0; d < NCF; ++d) {
                float acc = 0.f;
                #pragma unroll
                for (int c = 0; c < NCF; ++c) acc = fmaf(pw[c], P[h * (NCF * NCF) + c * NCF + d], acc);
                int cc = h * NCF + d;
                int idx = (o16 * 6 + (cc >> 5)) * 512 + ((cc >> 3) & 3) * 128 + l15o * 8 + (cc & 7);
                Mb[idx] = f2b(acc);
            }
        }
    }
    for (int e = tid; e < (OM_PAD - NC) * NC; e += 256) Mb[NC * NC + e] = 0;
}

// ---------------------------------------------------------------------------
extern "C" void kernel_launch(void* const* d_in, const int* in_sizes, int n_in,
                              void* d_out, int out_size, void* d_ws, size_t ws_size,
                              hipStream_t stream)
{
    const float* x     = (const float*)d_in[0];
    const float* kv    = (const float*)d_in[1];
    const float* ln1w  = (const float*)d_in[2];
    const float* ln1b  = (const float*)d_in[3];
    const float* akern = (const float*)d_in[4];
    const float* qkvw  = (const float*)d_in[5];
    const float* qkvdw = (const float*)d_in[6];
    const float* projw = (const float*)d_in[7];
    const float* temp  = (const float*)d_in[8];
    const float* ln2w  = (const float*)d_in[9];
    const float* ln2b  = (const float*)d_in[10];
    const float* fkern = (const float*)d_in[11];
    const float* pinw  = (const float*)d_in[12];
    const float* ffndw = (const float*)d_in[13];
    const float* poutw = (const float*)d_in[14];
    float* out = (float*)d_out;

    char* wp = (char*)d_ws;
    size_t off = 0;
    auto take = [&](size_t bytes) {
        char* r = wp + off;
        off = (off + bytes + 255) & ~(size_t)255;
        return r;
    };
    float* mu1   = (float*)take((size_t)NB * NHW * 4);
    float* rstd1 = (float*)take((size_t)NB * NHW * 4);
    float* mu2   = (float*)take((size_t)NB * NHW * 4);
    float* rstd2 = (float*)take((size_t)NB * NHW * 4);
    float* s1 = (float*)take(NB * NC * 4);  float* t1 = (float*)take(NB * NC * 4);
    float* s2 = (float*)take(NB * NC * 4);  float* t2 = (float*)take(NB * NC * 4);
    bfu* A1 = (bfu*)take((size_t)NB * OQKV_PAD * 192 * 2);
    bfu* A2 = (bfu*)take((size_t)NB * CPIN * 192 * 2);
    bfu* A3 = (bfu*)take((size_t)OM_PAD * 512 * 2);
    bfu* Mbf = (bfu*)take((size_t)NB * OM_PAD * NC * 2);
    float* u1  = (float*)take((size_t)NB * OQKV_PAD * 4);
    float* v01 = (float*)take((size_t)NB * OQKV_PAD * 4);
    float* u2  = (float*)take((size_t)NB * CPIN * 4);
    float* v02 = (float*)take((size_t)NB * CPIN * 4);
    float* wdwT1 = (float*)take(9 * CQKV * 4);
    float* wdwT2 = (float*)take(9 * CPIN * 4);
    float* S32 = (float*)take((size_t)NB * NHEADS * 1024 * 4);
    float* Q2  = (float*)take((size_t)NB * NHEADS * NCF * 4);
    float* K2  = (float*)take((size_t)NB * NHEADS * NCF * 4);
    const size_t bigoff = off;

    // per-batch big buffers: bfX(384) out1(384) big1(2048) big2(1152) bytes/px
    const size_t PB = (size_t)NHW * (384 + 384 + 2048 + 1152);
    size_t avail = (ws_size > bigoff) ? ws_size - bigoff : 0;
    int CB = 8;
    while (CB > 1 && (size_t)CB * PB > avail) CB >>= 1;

    dim3 blk(256);

    prep_film<<<dim3(48, NB), blk, 0, stream>>>(kv, akern, ln1w, ln1b, s1, t1);
    prep_film<<<dim3(48, NB), blk, 0, stream>>>(kv, fkern, ln2w, ln2b, s2, t2);
    wprep<<<dim3(OQKV_PAD / 4, NB), blk, 0, stream>>>(qkvw, s1, t1, A1, u1, v01, 0);
    wprep<<<dim3(CPIN / 4, NB), blk, 0, stream>>>(pinw, s2, t2, A2, u2, v02, 1);
    wprep<<<dim3(OM_PAD / 4, 1), blk, 0, stream>>>(poutw, s1, t1, A3, nullptr, nullptr, 2);
    wdw_prep<<<(9 * CQKV + 255) / 256, blk, 0, stream>>>(qkvdw, wdwT1, CQKV, 0);
    wdw_prep<<<(9 * CPIN + 255) / 256, blk, 0, stream>>>(ffndw, wdwT2, CPIN, 1);
    {
        int nz = NB * NHEADS * 1024 + 2 * NB * NHEADS * NCF + 256;
        zfill<<<(nz + 255) / 256, blk, 0, stream>>>(S32, nz);
    }

    for (int b0 = 0; b0 < NB; b0 += CB) {
        bfu* bfX  = (bfu*)(wp + bigoff);
        bfu* out1 = (bfu*)(wp + bigoff + (size_t)CB * NHW * 384);
        char* big1 = wp + bigoff + (size_t)CB * NHW * 768;
        char* big2 = big1 + (size_t)CB * NHW * 2048;
        bfu* qkv_pre = (bfu*)big1;
        bfu* qkvb    = (bfu*)big2;
        bfu* u_pre   = (bfu*)big1;
        bfu* gbuf    = (bfu*)big2;

        const float* xb = x + (size_t)b0 * NC * NHW;
        float* mu1b = mu1 + (size_t)b0 * NHW;   float* rs1b = rstd1 + (size_t)b0 * NHW;
        float* mu2b = mu2 + (size_t)b0 * NHW;   float* rs2b = rstd2 + (size_t)b0 * NHW;

        // ---- attention branch ----
        ln_cvt_cm<<<CB * 256, blk, 0, stream>>>(xb, mu1b, rs1b, bfX, CB);
        gemm_pm<0><<<dim3(256, OQKV_PAD / 128, CB), blk, 0, stream>>>(
            A1 + (size_t)b0 * OQKV_PAD * 192, (long)OQKV_PAD * 192, OQKV_PAD, CQKV, 192,
            bfX, NC, 0, qkv_pre, CQKV, nullptr, 0,
            mu1b, rs1b, u1 + (size_t)b0 * OQKV_PAD, v01 + (size_t)b0 * OQKV_PAD, OQKV_PAD);
        dw_pm8<CQKV><<<CB * 576, blk, 0, stream>>>(qkv_pre, wdwT1, qkvb, CB);
        gram_pm<<<dim3(64, CB), blk, 0, stream>>>(qkvb, S32, Q2, K2, b0);
        attn_fold<<<CB, blk, 0, stream>>>(S32, Q2, K2, temp, projw, Mbf, b0);
        // out1(bf16) = bfX + M @ v
        gemm_pm<1><<<dim3(256, OM_PAD / 128, CB), blk, 0, stream>>>(
            Mbf + (size_t)b0 * OM_PAD * NC, (long)OM_PAD * NC, OM_PAD, NC, 192,
            qkvb, CQKV, 384, out1, NC, bfX, NC,
            nullptr, nullptr, nullptr, nullptr, 0);

        // ---- FFN branch ----
        ln_stats_pm8<<<CB * 512, blk, 0, stream>>>(out1, mu2b, rs2b, CB);
        gemm_pm<0><<<dim3(256, CPIN / 128, CB), blk, 0, stream>>>(
            A2 + (size_t)b0 * CPIN * 192, (long)CPIN * 192, CPIN, CPIN, 192,
            out1, NC, 0, u_pre, CPIN, nullptr, 0,
            mu2b, rs2b, u2 + (size_t)b0 * CPIN, v02 + (size_t)b0 * CPIN, CPIN);
        dw_gate<CPIN, CG><<<CB * (NHW / 4) * (CG / 8) / 256, blk, 0, stream>>>(
            u_pre, wdwT2, gbuf, CB);
        // d_out (f32 channel-major) = out1 + pout @ g, written directly
        gemm_pm<3><<<dim3(256, OM_PAD / 128, CB), blk, 0, stream>>>(
            A3, 0, OM_PAD, NC, 512,
            gbuf, CG, 0, out + (size_t)b0 * NC * NHW, 0, out1, NC,
            nullptr, nullptr, nullptr, nullptr, 0);
    }
}

// Round 8
// 800.946 us; speedup vs baseline: 3.5231x; 1.0439x over previous
//
#include <hip/hip_runtime.h>
#include <math.h>

#define NB 8
#define NC 192
#define NHEADS 8
#define NCF 24
#define NHW 16384
#define NWID 128
#define CQKV 576
#define OQKV_PAD 640
#define CPIN 1024
#define CG 512
#define OM_PAD 256

typedef unsigned short bfu;                 // now holds fp16 bit patterns
typedef _Float16 f16x8 __attribute__((ext_vector_type(8)));
typedef _Float16 f16x2 __attribute__((ext_vector_type(2)));
typedef float f32x4 __attribute__((ext_vector_type(4)));

__device__ __forceinline__ unsigned short f2h(float f) {
    _Float16 h = (_Float16)f;
    return __builtin_bit_cast(unsigned short, h);
}
__device__ __forceinline__ float h2f(unsigned short u) {
    return (float)__builtin_bit_cast(_Float16, u);
}
// tanh-based GELU (max |err| vs exact ~3e-4; threshold margin ample)
__device__ __forceinline__ float gelu_tanh(float x) {
    float x3 = x * x * x;
    float z = 0.7978845608028654f * fmaf(0.044715f, x3, x);
    float e = __expf(2.f * z);
    float th = 1.f - 2.f / (e + 1.f);
    return 0.5f * x * (1.f + th);
}

struct F8 { float v[8]; };
union H8 { uint4 u; f16x2 h[4]; };
__device__ __forceinline__ F8 loadh8(const bfu* p) {
    uint4 r = *(const uint4*)p;
    F8 o;
    o.v[0] = h2f((unsigned short)(r.x & 0xffff)); o.v[1] = h2f((unsigned short)(r.x >> 16));
    o.v[2] = h2f((unsigned short)(r.y & 0xffff)); o.v[3] = h2f((unsigned short)(r.y >> 16));
    o.v[4] = h2f((unsigned short)(r.z & 0xffff)); o.v[5] = h2f((unsigned short)(r.z >> 16));
    o.v[6] = h2f((unsigned short)(r.w & 0xffff)); o.v[7] = h2f((unsigned short)(r.w >> 16));
    return o;
}
__device__ __forceinline__ void storeh8(bfu* p, const float* a) {
    uint4 r;
    r.x = (unsigned)f2h(a[0]) | ((unsigned)f2h(a[1]) << 16);
    r.y = (unsigned)f2h(a[2]) | ((unsigned)f2h(a[3]) << 16);
    r.z = (unsigned)f2h(a[4]) | ((unsigned)f2h(a[5]) << 16);
    r.w = (unsigned)f2h(a[6]) | ((unsigned)f2h(a[7]) << 16);
    *(uint4*)p = r;
}
__device__ __forceinline__ f16x2 h2z() {
    f16x2 z; z[0] = (_Float16)0.f; z[1] = (_Float16)0.f; return z;
}

__global__ __launch_bounds__(256) void zfill(float* __restrict__ p, int n) {
    int i = blockIdx.x * 256 + threadIdx.x;
    if (i < n) p[i] = 0.f;
}

// ---------------------------------------------------------------------------
// prep_film, wave-parallel. grid (48, NB) x 256.
// ---------------------------------------------------------------------------
__global__ __launch_bounds__(256) void prep_film(
    const float* __restrict__ kv, const float* __restrict__ kern,
    const float* __restrict__ lnw, const float* __restrict__ lnb,
    float* __restrict__ sArr, float* __restrict__ tArr)
{
    const int b = blockIdx.y;
    const int wave = threadIdx.x >> 6, lane = threadIdx.x & 63;
    const int r = blockIdx.x * 4 + wave;
    const float* kvb = kv + b * 256;
    float4 kvv = *(const float4*)(kvb + lane * 4);
    float4 k1 = *(const float4*)(kern + (size_t)r * 256 + lane * 4);
    float4 k2 = *(const float4*)(kern + (size_t)(r + NC) * 256 + lane * 4);
    float d1 = kvv.x * k1.x + kvv.y * k1.y + kvv.z * k1.z + kvv.w * k1.w;
    float d2 = kvv.x * k2.x + kvv.y * k2.y + kvv.z * k2.z + kvv.w * k2.w;
    #pragma unroll
    for (int off = 32; off; off >>= 1) {
        d1 += __shfl_down(d1, off, 64);
        d2 += __shfl_down(d2, off, 64);
    }
    if (lane == 0) {
        sArr[b * NC + r] = lnw[r] * d1;
        tArr[b * NC + r] = lnb[r] * d1 + d2;
    }
}

// ---------------------------------------------------------------------------
// Build fp16 A in MFMA-fragment-packed layout:
//   frag = (o/16)*K32 + (c/32); within = ((c>>3)&3)*128 + (o&15)*8 + (c&7)
// + u=sum(fp16 A row), v0=W@t. Wave-per-row.
// ---------------------------------------------------------------------------
__global__ __launch_bounds__(256) void wprep(
    const float* __restrict__ W, const float* __restrict__ sA, const float* __restrict__ tA,
    bfu* __restrict__ Abf, float* __restrict__ u, float* __restrict__ v0, int mode)
{
    const int wave = threadIdx.x >> 6, lane = threadIdx.x & 63;
    const int o = blockIdx.x * 4 + wave;
    const int b = blockIdx.y;
    const int Opad = (mode == 0) ? OQKV_PAD : (mode == 1 ? CPIN : OM_PAD);
    const int K = (mode == 2) ? 512 : 192;
    const int Kr = (mode == 2) ? 510 : 192;
    const int K32 = K >> 5;
    int src;
    if (mode == 0) src = (o < 576) ? o : -1;
    else if (mode == 1) src = (o < 510) ? o : (o < 512 ? -1 : (o < 1022 ? o - 2 : -1));
    else src = (o < 192) ? o : -1;
    const float* wr = (src >= 0) ? W + (size_t)src * Kr : nullptr;
    const float* sb = sA + b * NC;
    const float* tb = tA + b * NC;
    bfu* abase = Abf + (size_t)b * Opad * K;
    float au = 0.f, av = 0.f;
    for (int c0 = lane * 4; c0 < K; c0 += 256) {
        float a[4] = {0.f, 0.f, 0.f, 0.f};
        if (src >= 0) {
            #pragma unroll
            for (int j = 0; j < 4; ++j) {
                int c = c0 + j;
                if (c < Kr) {
                    float w = wr[c];
                    if (mode == 2) a[j] = w;
                    else { a[j] = w * sb[c]; av = fmaf(w, tb[c], av); }
                }
            }
        }
        ushort4 pk;
        bfu b0 = f2h(a[0]), b1 = f2h(a[1]), b2 = f2h(a[2]), b3 = f2h(a[3]);
        pk.x = b0; pk.y = b1; pk.z = b2; pk.w = b3;
        au += h2f(b0) + h2f(b1) + h2f(b2) + h2f(b3);
        int frag = (o >> 4) * K32 + (c0 >> 5);
        int within = ((c0 >> 3) & 3) * 128 + (o & 15) * 8 + (c0 & 7);
        *(ushort4*)(abase + (size_t)frag * 512 + within) = pk;
    }
    if (mode < 2) {
        #pragma unroll
        for (int off = 32; off; off >>= 1) {
            au += __shfl_down(au, off, 64);
            av += __shfl_down(av, off, 64);
        }
        if (lane == 0) {
            u[(size_t)b * Opad + o] = au;
            v0[(size_t)b * Opad + o] = (src >= 0) ? av : 0.f;
        }
    }
}

// transpose dw weights to fp16: mode 0: [C][9]->[9][C]; mode 1: remap [9][1024]
__global__ __launch_bounds__(256) void wdw_prep(
    const float* __restrict__ src, bfu* __restrict__ dstT, int C, int mode)
{
    int i = blockIdx.x * 256 + threadIdx.x;
    if (i >= 9 * C) return;
    int tap = i / C, col = i % C;
    float v;
    if (mode == 0) v = src[(size_t)col * 9 + tap];
    else {
        if (col < 512) v = (col < 510) ? src[(size_t)col * 9 + tap] : 0.f;
        else { int c2 = col - 512; v = (c2 < 510) ? src[(size_t)(510 + c2) * 9 + tap] : 0.f; }
    }
    dstT[(size_t)tap * C + col] = f2h(v);
}

// ---------------------------------------------------------------------------
// LN stats + fp16 convert, channel-major fp32 in -> pixel-major fp16 out,
// fully coalesced via LDS transpose. Block = 64 px. grid CB*256.
// ---------------------------------------------------------------------------
__global__ __launch_bounds__(256) void ln_cvt_cm(
    const float* __restrict__ x, float* __restrict__ mu, float* __restrict__ rstd,
    bfu* __restrict__ xbf, int cb)
{
    __shared__ bfu lt[64][198];
    const int blkpx = blockIdx.x;
    const int b = blkpx >> 8;
    const int n0 = (blkpx & 255) * 64;
    const int tid = threadIdx.x;
    #pragma unroll
    for (int it = 0; it < 12; ++it) {
        int task = it * 256 + tid;
        int c = task >> 4, q = task & 15;
        float4 v = *(const float4*)(x + ((size_t)b * NC + c) * NHW + n0 + q * 4);
        lt[q * 4 + 0][c] = f2h(v.x);
        lt[q * 4 + 1][c] = f2h(v.y);
        lt[q * 4 + 2][c] = f2h(v.z);
        lt[q * 4 + 3][c] = f2h(v.w);
    }
    __syncthreads();
    {
        int px = tid >> 2, part = tid & 3;
        const unsigned* row = (const unsigned*)&lt[px][0];
        float s = 0.f, ss = 0.f;
        #pragma unroll
        for (int i = 0; i < 24; ++i) {
            unsigned w = row[part * 24 + i];
            float a = h2f((unsigned short)(w & 0xffff));
            float bb = h2f((unsigned short)(w >> 16));
            s += a + bb; ss = fmaf(a, a, ss); ss = fmaf(bb, bb, ss);
        }
        s += __shfl_down(s, 2, 4); ss += __shfl_down(ss, 2, 4);
        s += __shfl_down(s, 1, 4); ss += __shfl_down(ss, 1, 4);
        if (part == 0) {
            int idx = b * NHW + n0 + px;
            float m = s * (1.f / 192.f);
            float var = ss * (1.f / 192.f) - m * m;
            mu[idx] = m;
            rstd[idx] = rsqrtf(var + 1e-5f);
        }
    }
    #pragma unroll
    for (int it = 0; it < 6; ++it) {
        int task = it * 256 + tid;
        int px = task / 24, ckk = task % 24;
        const unsigned* row = (const unsigned*)&lt[px][0];
        uint4 o;
        o.x = row[ckk * 4 + 0]; o.y = row[ckk * 4 + 1];
        o.z = row[ckk * 4 + 2]; o.w = row[ckk * 4 + 3];
        *(uint4*)(xbf + ((size_t)b * NHW + n0 + px) * NC + ckk * 8) = o;
    }
}

// ---------------------------------------------------------------------------
// LN stats only, pixel-major fp16 input (out1). 8 lanes per pixel.
// ---------------------------------------------------------------------------
__global__ __launch_bounds__(256) void ln_stats_pm8(
    const bfu* __restrict__ xpm, float* __restrict__ mu, float* __restrict__ rstd, int cb)
{
    int gt = blockIdx.x * 256 + threadIdx.x;
    int px = gt >> 3, seg = gt & 7;
    if (px >= cb * NHW) return;
    const bfu* row = xpm + (size_t)px * NC;
    float s = 0.f, ss = 0.f;
    #pragma unroll
    for (int it = 0; it < 3; ++it) {
        F8 v = loadh8(row + (seg + it * 8) * 8);
        #pragma unroll
        for (int j = 0; j < 8; ++j) { s += v.v[j]; ss = fmaf(v.v[j], v.v[j], ss); }
    }
    #pragma unroll
    for (int off = 4; off; off >>= 1) {
        s += __shfl_down(s, off, 8);
        ss += __shfl_down(ss, off, 8);
    }
    if (seg == 0) {
        float m = s * (1.f / 192.f);
        float var = ss * (1.f / 192.f) - m * m;
        mu[px] = m;
        rstd[px] = rsqrtf(var + 1e-5f);
    }
}

// ---------------------------------------------------------------------------
// MFMA GEMM (fp16): A fragment-packed, X via LDS.
// EPI 0/1 (K=192): SINGLE-STAGE — whole 64px x 192 tile staged once, one
//   barrier, 6 straight-line k-steps. EPI 3 (K=512): BK=64 double-buffered.
// Block = 4 waves (2o x 2n), tile 128o x 64px. grid (NHW/64, Opad/128, CB).
// EPI 0: LN epilogue -> fp16 pixel-major
// EPI 1: + fp16 res  -> fp16 pixel-major
// EPI 3: + fp16 res  -> f32 CHANNEL-major (direct d_out write)
// ---------------------------------------------------------------------------
template<int EPI>
__global__ __launch_bounds__(256) void gemm_pm(
    const bfu* __restrict__ A, long aBStride, int Opad, int Oreal, int K,
    const bfu* __restrict__ X, int xRow, int xOff,
    void* __restrict__ Y, int yRow,
    const void* __restrict__ res, int resRow,
    const float* __restrict__ mu, const float* __restrict__ rstd,
    const float* __restrict__ uvec, const float* __restrict__ v0vec, int uStride)
{
    constexpr bool FULLK = (EPI != 3);
    constexpr int SMEMSZ = FULLK ? (64 * 208 * 2) : 33024;
    __shared__ __align__(16) char smem[SMEMSZ];
    bfu* xs = (bfu*)smem;
    bfu (*stg)[136] = (bfu(*)[136])smem;       // epilogue fp16 (EPI 0/1)
    float (*stg32)[129] = (float(*)[129])smem; // epilogue f32 (EPI 3)

    const int b = blockIdx.z;
    const int om = blockIdx.y * 128;
    const int n0 = blockIdx.x * 64;
    const int tid = threadIdx.x;
    const int lane = tid & 63, wave = tid >> 6;
    const int wy = wave >> 1, wx = wave & 1;
    const int l15 = lane & 15, kg = lane >> 4;
    const int K32 = K >> 5;
    const int o16b = (om >> 4) + wy * 4;

    const bfu* Ab = A + (size_t)b * aBStride;
    const bfu* Xbase = X + ((size_t)b * NHW + n0) * xRow + xOff;

    f32x4 acc[4][2];
    #pragma unroll
    for (int i = 0; i < 4; ++i)
        #pragma unroll
        for (int j = 0; j < 2; ++j) acc[i][j] = (f32x4){0.f, 0.f, 0.f, 0.f};

    if constexpr (FULLK) {
        // ---- single-stage: 64 rows x 192 ch, pitch 208 halves ----
        #pragma unroll
        for (int i = 0; i < 6; ++i) {
            int task = i * 256 + tid;        // 1536 = 64 rows x 24 chunks
            int r = task / 24, c = task % 24;
            uint4 v = *(const uint4*)(Xbase + (size_t)r * xRow + c * 8);
            *(uint4*)&xs[r * 208 + c * 8] = v;
        }
        __syncthreads();
        #pragma unroll
        for (int k32 = 0; k32 < 6; ++k32) {
            f16x8 af[4], bfr[2];
            #pragma unroll
            for (int mf = 0; mf < 4; ++mf)
                af[mf] = *(const f16x8*)(Ab + ((size_t)(o16b + mf) * 6 + k32) * 512 + lane * 8);
            #pragma unroll
            for (int nf = 0; nf < 2; ++nf)
                bfr[nf] = *(const f16x8*)&xs[(wx * 32 + nf * 16 + l15) * 208 + k32 * 32 + kg * 8];
            #pragma unroll
            for (int mf = 0; mf < 4; ++mf)
                #pragma unroll
                for (int nf = 0; nf < 2; ++nf)
                    acc[mf][nf] = __builtin_amdgcn_mfma_f32_16x16x32_f16(af[mf], bfr[nf], acc[mf][nf], 0, 0, 0);
        }
        __syncthreads();
    } else {
        // ---- BK=64 double-buffered (K=512), pitch 72 ----
        const int sr = tid >> 3, sc = tid & 7;
        const int NCH = K >> 6;
        #pragma unroll
        for (int i = 0; i < 2; ++i) {
            int r = i * 32 + sr;
            uint4 v = *(const uint4*)(Xbase + (size_t)r * xRow + sc * 8);
            *(uint4*)&xs[r * 72 + sc * 8] = v;
        }
        __syncthreads();
        for (int kc = 0; kc < NCH; ++kc) {
            const int cur = kc & 1;
            if (kc + 1 < NCH) {
                #pragma unroll
                for (int i = 0; i < 2; ++i) {
                    int r = i * 32 + sr;
                    uint4 v = *(const uint4*)(Xbase + (size_t)r * xRow + (kc + 1) * 64 + sc * 8);
                    *(uint4*)&xs[((cur ^ 1) * 64 + r) * 72 + sc * 8] = v;
                }
            }
            #pragma unroll
            for (int ks = 0; ks < 2; ++ks) {
                const int k32 = kc * 2 + ks;
                f16x8 af[4], bfr[2];
                #pragma unroll
                for (int mf = 0; mf < 4; ++mf)
                    af[mf] = *(const f16x8*)(Ab + ((size_t)(o16b + mf) * K32 + k32) * 512 + lane * 8);
                #pragma unroll
                for (int nf = 0; nf < 2; ++nf)
                    bfr[nf] = *(const f16x8*)&xs[(cur * 64 + wx * 32 + nf * 16 + l15) * 72 + ks * 32 + kg * 8];
                #pragma unroll
                for (int mf = 0; mf < 4; ++mf)
                    #pragma unroll
                    for (int nf = 0; nf < 2; ++nf)
                        acc[mf][nf] = __builtin_amdgcn_mfma_f32_16x16x32_f16(af[mf], bfr[nf], acc[mf][nf], 0, 0, 0);
            }
            __syncthreads();
        }
    }

    // ---- stage accumulators to LDS ----
    #pragma unroll
    for (int nf = 0; nf < 2; ++nf) {
        const int nl = wx * 32 + nf * 16 + l15;
        float muv = 0.f, rsv = 0.f;
        if (EPI == 0) {
            muv = mu[(size_t)b * NHW + n0 + nl];
            rsv = rstd[(size_t)b * NHW + n0 + nl];
        }
        #pragma unroll
        for (int mf = 0; mf < 4; ++mf) {
            const int obl = wy * 64 + mf * 16 + kg * 4;
            if (EPI == 3) {
                stg32[nl][obl + 0] = acc[mf][nf][0];
                stg32[nl][obl + 1] = acc[mf][nf][1];
                stg32[nl][obl + 2] = acc[mf][nf][2];
                stg32[nl][obl + 3] = acc[mf][nf][3];
            } else {
                float r0, r1, r2, r3;
                if (EPI == 0) {
                    float4 uv = *(const float4*)(uvec + (size_t)b * uStride + om + obl);
                    float4 vv = *(const float4*)(v0vec + (size_t)b * uStride + om + obl);
                    r0 = rsv * (acc[mf][nf][0] - muv * uv.x) + vv.x;
                    r1 = rsv * (acc[mf][nf][1] - muv * uv.y) + vv.y;
                    r2 = rsv * (acc[mf][nf][2] - muv * uv.z) + vv.z;
                    r3 = rsv * (acc[mf][nf][3] - muv * uv.w) + vv.w;
                } else {
                    r0 = acc[mf][nf][0]; r1 = acc[mf][nf][1];
                    r2 = acc[mf][nf][2]; r3 = acc[mf][nf][3];
                }
                ushort4 pk;
                pk.x = f2h(r0); pk.y = f2h(r1); pk.z = f2h(r2); pk.w = f2h(r3);
                *(ushort4*)&stg[nl][obl] = pk;
            }
        }
    }
    __syncthreads();

    // ---- writeout ----
    if (EPI == 3) {
        #pragma unroll
        for (int it = 0; it < 8; ++it) {
            int task = it * 256 + tid;
            int o = task >> 4, q = task & 15;
            int oc = om + o;
            if (oc >= Oreal) continue;
            float vals[4];
            #pragma unroll
            for (int j = 0; j < 4; ++j) {
                float v = stg32[q * 4 + j][o];
                float r = h2f(((const bfu*)res)[((size_t)b * NHW + n0 + q * 4 + j) * resRow + oc]);
                vals[j] = v + r;
            }
            *(float4*)((float*)Y + ((size_t)b * NC + oc) * NHW + n0 + q * 4) =
                make_float4(vals[0], vals[1], vals[2], vals[3]);
        }
    } else {
        #pragma unroll
        for (int it = 0; it < 4; ++it) {
            int task = it * 256 + tid;
            int nl = task >> 4, ch = task & 15;
            int oc = om + ch * 8;
            if (oc >= Oreal) continue;
            uint4 sv = *(const uint4*)&stg[nl][ch * 8];
            size_t nglob = (size_t)b * NHW + n0 + nl;
            if (EPI == 0) {
                *(uint4*)((bfu*)Y + nglob * yRow + oc) = sv;
            } else {
                float a[8];
                a[0] = h2f((unsigned short)(sv.x & 0xffff)); a[1] = h2f((unsigned short)(sv.x >> 16));
                a[2] = h2f((unsigned short)(sv.y & 0xffff)); a[3] = h2f((unsigned short)(sv.y >> 16));
                a[4] = h2f((unsigned short)(sv.z & 0xffff)); a[5] = h2f((unsigned short)(sv.z >> 16));
                a[6] = h2f((unsigned short)(sv.w & 0xffff)); a[7] = h2f((unsigned short)(sv.w >> 16));
                F8 rv = loadh8((const bfu*)res + nglob * resRow + oc);
                #pragma unroll
                for (int j = 0; j < 8; ++j) a[j] += rv.v[j];
                storeh8((bfu*)Y + nglob * yRow + oc, a);
            }
        }
    }
}

// ---------------------------------------------------------------------------
// depthwise 3x3, fp16 packed math, thread = 8ch x 8px (no gate).
// ---------------------------------------------------------------------------
template<int CIN>
__global__ __launch_bounds__(256) void dw_pm8(
    const bfu* __restrict__ in, const bfu* __restrict__ wT, bfu* __restrict__ out, int cb)
{
    const int CHUNKS = CIN / 8;
    const int NPB = NHW / 8;
    int f = blockIdx.x * 256 + threadIdx.x;
    if (f >= cb * NPB * CHUNKS) return;
    int ch = f % CHUNKS;
    int pb = f / CHUNKS;
    int n8 = pb & (NPB - 1);
    int b  = pb >> 11;
    int xq = n8 & 15, y = n8 >> 4;
    int x0 = xq * 8;
    const int c8 = ch * 8;
    const bfu* rowb = in + ((size_t)b * NHW + (size_t)y * NWID) * CIN + c8;

    f16x2 acc[8][4];
    #pragma unroll
    for (int j = 0; j < 8; ++j)
        #pragma unroll
        for (int q = 0; q < 4; ++q) acc[j][q] = h2z();

    #pragma unroll
    for (int dy = -1; dy <= 1; ++dy) {
        int yy = y + dy;
        if ((unsigned)yy >= (unsigned)NWID) continue;
        const bfu* rb = rowb + (long)dy * NWID * CIN;
        f16x2 w1[3][4];
        #pragma unroll
        for (int t = 0; t < 3; ++t) {
            H8 wv; wv.u = *(const uint4*)(wT + (size_t)((dy + 1) * 3 + t) * CIN + c8);
            #pragma unroll
            for (int q = 0; q < 4; ++q) w1[t][q] = wv.h[q];
        }
        #pragma unroll
        for (int c = 0; c < 10; ++c) {
            int xx = x0 - 1 + c;
            if ((unsigned)xx >= (unsigned)NWID) continue;
            H8 v; v.u = *(const uint4*)(rb + (size_t)xx * CIN);
            #pragma unroll
            for (int j = 0; j < 8; ++j) {
                int t = c - j;
                if (t < 0 || t > 2) continue;
                #pragma unroll
                for (int q = 0; q < 4; ++q)
                    acc[j][q] = w1[t][q] * v.h[q] + acc[j][q];
            }
        }
    }
    #pragma unroll
    for (int j = 0; j < 8; ++j) {
        H8 o;
        #pragma unroll
        for (int q = 0; q < 4; ++q) o.h[q] = acc[j][q];
        *(uint4*)(out + ((size_t)b * NHW + (size_t)y * NWID + x0 + j) * CIN + c8) = o.u;
    }
}

// ---------------------------------------------------------------------------
// depthwise 3x3 + GELU gate, fp16 packed math, thread = 8ch x 4px.
// ---------------------------------------------------------------------------
template<int CIN, int COUT>
__global__ __launch_bounds__(256) void dw_gate(
    const bfu* __restrict__ in, const bfu* __restrict__ wT, bfu* __restrict__ out, int cb)
{
    const int CHUNKS = COUT / 8;
    const int NPB = NHW / 4;
    int f = blockIdx.x * 256 + threadIdx.x;
    if (f >= cb * NPB * CHUNKS) return;
    int ch = f % CHUNKS;
    int pb = f / CHUNKS;
    int n4 = pb & (NPB - 1);
    int b  = pb >> 12;
    int xb = n4 & 31, y = n4 >> 5;
    int x0 = xb * 4;
    const int c8 = ch * 8;
    const bfu* rowb = in + ((size_t)b * NHW + (size_t)y * NWID) * CIN + c8;

    f16x2 a1[4][4], a2[4][4];
    #pragma unroll
    for (int j = 0; j < 4; ++j)
        #pragma unroll
        for (int q = 0; q < 4; ++q) { a1[j][q] = h2z(); a2[j][q] = h2z(); }

    #pragma unroll
    for (int dy = -1; dy <= 1; ++dy) {
        int yy = y + dy;
        if ((unsigned)yy >= (unsigned)NWID) continue;
        const bfu* rb = rowb + (long)dy * NWID * CIN;
        f16x2 w1[3][4], w2[3][4];
        #pragma unroll
        for (int t = 0; t < 3; ++t) {
            const bfu* wp = wT + (size_t)((dy + 1) * 3 + t) * CIN + c8;
            H8 wa; wa.u = *(const uint4*)wp;
            H8 wb; wb.u = *(const uint4*)(wp + 512);
            #pragma unroll
            for (int q = 0; q < 4; ++q) { w1[t][q] = wa.h[q]; w2[t][q] = wb.h[q]; }
        }
        #pragma unroll
        for (int c = 0; c < 6; ++c) {
            int xx = x0 - 1 + c;
            if ((unsigned)xx >= (unsigned)NWID) continue;
            H8 v1; v1.u = *(const uint4*)(rb + (size_t)xx * CIN);
            H8 v2; v2.u = *(const uint4*)(rb + (size_t)xx * CIN + 512);
            #pragma unroll
            for (int j = 0; j < 4; ++j) {
                int t = c - j;
                if (t < 0 || t > 2) continue;
                #pragma unroll
                for (int q = 0; q < 4; ++q) {
                    a1[j][q] = w1[t][q] * v1.h[q] + a1[j][q];
                    a2[j][q] = w2[t][q] * v2.h[q] + a2[j][q];
                }
            }
        }
    }
    #pragma unroll
    for (int j = 0; j < 4; ++j) {
        H8 o;
        #pragma unroll
        for (int q = 0; q < 4; ++q) {
            float g0 = gelu_tanh((float)a1[j][q][0]) * (float)a2[j][q][0];
            float g1 = gelu_tanh((float)a1[j][q][1]) * (float)a2[j][q][1];
            f16x2 r; r[0] = (_Float16)g0; r[1] = (_Float16)g1;
            o.h[q] = r;
        }
        *(uint4*)(out + ((size_t)b * NHW + (size_t)y * NWID + x0 + j) * COUT + c8) = o.u;
    }
}

// ---------------------------------------------------------------------------
// MFMA Gram (fp16). grid (64 n-chunks, CB). 4 waves x 2 heads each.
// Raw-bit pair-packing is dtype-agnostic; only the intrinsic changed.
// ---------------------------------------------------------------------------
__global__ __launch_bounds__(256) void gram_pm(
    const bfu* __restrict__ qkv, float* __restrict__ S32,
    float* __restrict__ Q2, float* __restrict__ K2, int b0)
{
    __shared__ bfu lds[392 * 72];
    const int b = blockIdx.y;
    const int nc = blockIdx.x;
    const int tid = threadIdx.x;
    const int lane = tid & 63, wave = tid >> 6;
    const int l15 = lane & 15, kg = lane >> 4;

    f32x4 sAcc[2][2][2], qAcc[2][2], kAcc[2][2];
    #pragma unroll
    for (int h = 0; h < 2; ++h)
        #pragma unroll
        for (int i = 0; i < 2; ++i) {
            qAcc[h][i] = (f32x4){0.f, 0.f, 0.f, 0.f};
            kAcc[h][i] = (f32x4){0.f, 0.f, 0.f, 0.f};
            #pragma unroll
            for (int j = 0; j < 2; ++j) sAcc[h][i][j] = (f32x4){0.f, 0.f, 0.f, 0.f};
        }

    const size_t pbase = (size_t)b * NHW + (size_t)nc * 256;
    unsigned* ldsw = (unsigned*)lds;

    for (int it = 0; it < 4; ++it) {
        const size_t nb = pbase + it * 64;
        #pragma unroll
        for (int i = 0; i < 6; ++i) {
            int task = i * 256 + tid;
            int np = task & 31, ch = task >> 5;
            const bfu* r0 = qkv + (nb + np * 2) * CQKV + ch * 8;
            uint4 v0 = *(const uint4*)r0;
            uint4 v1 = *(const uint4*)(r0 + CQKV);
            int cb8 = ch * 8;
            ldsw[(cb8 + 0) * 36 + np] = (v0.x & 0xffffu) | (v1.x << 16);
            ldsw[(cb8 + 1) * 36 + np] = (v0.x >> 16) | (v1.x & 0xffff0000u);
            ldsw[(cb8 + 2) * 36 + np] = (v0.y & 0xffffu) | (v1.y << 16);
            ldsw[(cb8 + 3) * 36 + np] = (v0.y >> 16) | (v1.y & 0xffff0000u);
            ldsw[(cb8 + 4) * 36 + np] = (v0.z & 0xffffu) | (v1.z << 16);
            ldsw[(cb8 + 5) * 36 + np] = (v0.z >> 16) | (v1.z & 0xffff0000u);
            ldsw[(cb8 + 6) * 36 + np] = (v0.w & 0xffffu) | (v1.w << 16);
            ldsw[(cb8 + 7) * 36 + np] = (v0.w >> 16) | (v1.w & 0xffff0000u);
        }
        ldsw[(384 + (tid >> 5)) * 36 + (tid & 31)] = 0;
        __syncthreads();
        #pragma unroll
        for (int hh = 0; hh < 2; ++hh) {
            const int h = wave * 2 + hh;
            const int qr = h * NCF, kr = NC + h * NCF;
            #pragma unroll
            for (int ks = 0; ks < 2; ++ks) {
                const int nsub = ks * 32 + kg * 8;
                f16x8 aq0 = *(const f16x8*)(lds + (qr + l15) * 72 + nsub);
                f16x8 aq1 = *(const f16x8*)(lds + (qr + 16 + l15) * 72 + nsub);
                f16x8 bk0 = *(const f16x8*)(lds + (kr + l15) * 72 + nsub);
                f16x8 bk1 = *(const f16x8*)(lds + (kr + 16 + l15) * 72 + nsub);
                sAcc[hh][0][0] = __builtin_amdgcn_mfma_f32_16x16x32_f16(aq0, bk0, sAcc[hh][0][0], 0, 0, 0);
                sAcc[hh][0][1] = __builtin_amdgcn_mfma_f32_16x16x32_f16(aq0, bk1, sAcc[hh][0][1], 0, 0, 0);
                sAcc[hh][1][0] = __builtin_amdgcn_mfma_f32_16x16x32_f16(aq1, bk0, sAcc[hh][1][0], 0, 0, 0);
                sAcc[hh][1][1] = __builtin_amdgcn_mfma_f32_16x16x32_f16(aq1, bk1, sAcc[hh][1][1], 0, 0, 0);
                qAcc[hh][0] = __builtin_amdgcn_mfma_f32_16x16x32_f16(aq0, aq0, qAcc[hh][0], 0, 0, 0);
                qAcc[hh][1] = __builtin_amdgcn_mfma_f32_16x16x32_f16(aq1, aq1, qAcc[hh][1], 0, 0, 0);
                kAcc[hh][0] = __builtin_amdgcn_mfma_f32_16x16x32_f16(bk0, bk0, kAcc[hh][0], 0, 0, 0);
                kAcc[hh][1] = __builtin_amdgcn_mfma_f32_16x16x32_f16(bk1, bk1, kAcc[hh][1], 0, 0, 0);
            }
        }
        __syncthreads();
    }

    const int gb = b0 + b;
    #pragma unroll
    for (int hh = 0; hh < 2; ++hh) {
        const int h = wave * 2 + hh;
        float* Sp = S32 + ((size_t)gb * NHEADS + h) * 1024;
        #pragma unroll
        for (int mt = 0; mt < 2; ++mt)
            #pragma unroll
            for (int nt = 0; nt < 2; ++nt)
                #pragma unroll
                for (int r = 0; r < 4; ++r) {
                    int c = mt * 16 + kg * 4 + r, d = nt * 16 + l15;
                    atomicAdd(&Sp[c * 32 + d], sAcc[hh][mt][nt][r]);
                }
        #pragma unroll
        for (int t = 0; t < 2; ++t)
            #pragma unroll
            for (int r = 0; r < 4; ++r) {
                int row = t * 16 + kg * 4 + r, col = t * 16 + l15;
                if (row == col && row < NCF) {
                    atomicAdd(&Q2[((size_t)gb * NHEADS + h) * NCF + row], qAcc[hh][t][r]);
                    atomicAdd(&K2[((size_t)gb * NHEADS + h) * NCF + row], kAcc[hh][t][r]);
                }
            }
    }
}

// ---------------------------------------------------------------------------
// normalize -> softmax -> fold proj_w -> Mbf packed-fragment fp16. grid(CB)
// ---------------------------------------------------------------------------
__global__ __launch_bounds__(256) void attn_fold(
    const float* __restrict__ S32, const float* __restrict__ Q2, const float* __restrict__ K2,
    const float* __restrict__ temp, const float* __restrict__ projw, bfu* __restrict__ Mbf, int b0)
{
    const int gb = b0 + blockIdx.x, tid = threadIdx.x;
    __shared__ float P[NHEADS * NCF * NCF];
    for (int e = tid; e < NHEADS * NCF * NCF; e += 256) {
        int h = e / (NCF * NCF);
        int r = e % (NCF * NCF);
        int c = r / NCF, d = r % NCF;
        float sv = S32[((size_t)gb * NHEADS + h) * 1024 + c * 32 + d];
        float rq = sqrtf(Q2[((size_t)gb * NHEADS + h) * NCF + c]);
        float rk = sqrtf(K2[((size_t)gb * NHEADS + h) * NCF + d]);
        P[e] = sv / (rq * rk) * temp[h];
    }
    __syncthreads();
    if (tid < NHEADS * NCF) {
        int h = tid / NCF, c = tid % NCF;
        float* row = P + h * (NCF * NCF) + c * NCF;
        float mx = row[0];
        #pragma unroll
        for (int d = 1; d < NCF; ++d) mx = fmaxf(mx, row[d]);
        float sum = 0.f;
        #pragma unroll
        for (int d = 0; d < NCF; ++d) { float e2 = __expf(row[d] - mx); row[d] = e2; sum += e2; }
        float inv = 1.f / sum;
        #pragma unroll
        for (int d = 0; d < NCF; ++d) row[d] *= inv;
    }
    __syncthreads();
    bfu* Mb = Mbf + (size_t)gb * OM_PAD * NC;
    if (tid < NC) {
        int o = tid;
        int o16 = o >> 4, l15o = o & 15;
        for (int h = 0; h < NHEADS; ++h) {
            float pw[NCF];
            #pragma unroll
            for (int c = 0; c < NCF; ++c) pw[c] = projw[(size_t)o * NC + h * NCF + c];
            #pragma unroll
            for (int d = 0; d < NCF; ++d) {
                float acc = 0.f;
                #pragma unroll
                for (int c = 0; c < NCF; ++c) acc = fmaf(pw[c], P[h * (NCF * NCF) + c * NCF + d], acc);
                int cc = h * NCF + d;
                int idx = (o16 * 6 + (cc >> 5)) * 512 + ((cc >> 3) & 3) * 128 + l15o * 8 + (cc & 7);
                Mb[idx] = f2h(acc);
            }
        }
    }
    for (int e = tid; e < (OM_PAD - NC) * NC; e += 256) Mb[NC * NC + e] = 0;
}

// ---------------------------------------------------------------------------
extern "C" void kernel_launch(void* const* d_in, const int* in_sizes, int n_in,
                              void* d_out, int out_size, void* d_ws, size_t ws_size,
                              hipStream_t stream)
{
    const float* x     = (const float*)d_in[0];
    const float* kv    = (const float*)d_in[1];
    const float* ln1w  = (const float*)d_in[2];
    const float* ln1b  = (const float*)d_in[3];
    const float* akern = (const float*)d_in[4];
    const float* qkvw  = (const float*)d_in[5];
    const float* qkvdw = (const float*)d_in[6];
    const float* projw = (const float*)d_in[7];
    const float* temp  = (const float*)d_in[8];
    const float* ln2w  = (const float*)d_in[9];
    const float* ln2b  = (const float*)d_in[10];
    const float* fkern = (const float*)d_in[11];
    const float* pinw  = (const float*)d_in[12];
    const float* ffndw = (const float*)d_in[13];
    const float* poutw = (const float*)d_in[14];
    float* out = (float*)d_out;

    char* wp = (char*)d_ws;
    size_t off = 0;
    auto take = [&](size_t bytes) {
        char* r = wp + off;
        off = (off + bytes + 255) & ~(size_t)255;
        return r;
    };
    float* mu1   = (float*)take((size_t)NB * NHW * 4);
    float* rstd1 = (float*)take((size_t)NB * NHW * 4);
    float* mu2   = (float*)take((size_t)NB * NHW * 4);
    float* rstd2 = (float*)take((size_t)NB * NHW * 4);
    float* s1 = (float*)take(NB * NC * 4);  float* t1 = (float*)take(NB * NC * 4);
    float* s2 = (float*)take(NB * NC * 4);  float* t2 = (float*)take(NB * NC * 4);
    bfu* A1 = (bfu*)take((size_t)NB * OQKV_PAD * 192 * 2);
    bfu* A2 = (bfu*)take((size_t)NB * CPIN * 192 * 2);
    bfu* A3 = (bfu*)take((size_t)OM_PAD * 512 * 2);
    bfu* Mbf = (bfu*)take((size_t)NB * OM_PAD * NC * 2);
    float* u1  = (float*)take((size_t)NB * OQKV_PAD * 4);
    float* v01 = (float*)take((size_t)NB * OQKV_PAD * 4);
    float* u2  = (float*)take((size_t)NB * CPIN * 4);
    float* v02 = (float*)take((size_t)NB * CPIN * 4);
    bfu* wdwT1 = (bfu*)take(9 * CQKV * 2);
    bfu* wdwT2 = (bfu*)take(9 * CPIN * 2);
    float* S32 = (float*)take((size_t)NB * NHEADS * 1024 * 4);
    float* Q2  = (float*)take((size_t)NB * NHEADS * NCF * 4);
    float* K2  = (float*)take((size_t)NB * NHEADS * NCF * 4);
    const size_t bigoff = off;

    const size_t PB = (size_t)NHW * (384 + 384 + 2048 + 1152);
    size_t avail = (ws_size > bigoff) ? ws_size - bigoff : 0;
    int CB = 8;
    while (CB > 1 && (size_t)CB * PB > avail) CB >>= 1;

    dim3 blk(256);

    prep_film<<<dim3(48, NB), blk, 0, stream>>>(kv, akern, ln1w, ln1b, s1, t1);
    prep_film<<<dim3(48, NB), blk, 0, stream>>>(kv, fkern, ln2w, ln2b, s2, t2);
    wprep<<<dim3(OQKV_PAD / 4, NB), blk, 0, stream>>>(qkvw, s1, t1, A1, u1, v01, 0);
    wprep<<<dim3(CPIN / 4, NB), blk, 0, stream>>>(pinw, s2, t2, A2, u2, v02, 1);
    wprep<<<dim3(OM_PAD / 4, 1), blk, 0, stream>>>(poutw, s1, t1, A3, nullptr, nullptr, 2);
    wdw_prep<<<(9 * CQKV + 255) / 256, blk, 0, stream>>>(qkvdw, wdwT1, CQKV, 0);
    wdw_prep<<<(9 * CPIN + 255) / 256, blk, 0, stream>>>(ffndw, wdwT2, CPIN, 1);
    {
        int nz = NB * NHEADS * 1024 + 2 * NB * NHEADS * NCF + 256;
        zfill<<<(nz + 255) / 256, blk, 0, stream>>>(S32, nz);
    }

    for (int b0 = 0; b0 < NB; b0 += CB) {
        bfu* bfX  = (bfu*)(wp + bigoff);
        bfu* out1 = (bfu*)(wp + bigoff + (size_t)CB * NHW * 384);
        char* big1 = wp + bigoff + (size_t)CB * NHW * 768;
        char* big2 = big1 + (size_t)CB * NHW * 2048;
        bfu* qkv_pre = (bfu*)big1;
        bfu* qkvb    = (bfu*)big2;
        bfu* u_pre   = (bfu*)big1;
        bfu* gbuf    = (bfu*)big2;

        const float* xb = x + (size_t)b0 * NC * NHW;
        float* mu1b = mu1 + (size_t)b0 * NHW;   float* rs1b = rstd1 + (size_t)b0 * NHW;
        float* mu2b = mu2 + (size_t)b0 * NHW;   float* rs2b = rstd2 + (size_t)b0 * NHW;

        // ---- attention branch ----
        ln_cvt_cm<<<CB * 256, blk, 0, stream>>>(xb, mu1b, rs1b, bfX, CB);
        gemm_pm<0><<<dim3(256, OQKV_PAD / 128, CB), blk, 0, stream>>>(
            A1 + (size_t)b0 * OQKV_PAD * 192, (long)OQKV_PAD * 192, OQKV_PAD, CQKV, 192,
            bfX, NC, 0, qkv_pre, CQKV, nullptr, 0,
            mu1b, rs1b, u1 + (size_t)b0 * OQKV_PAD, v01 + (size_t)b0 * OQKV_PAD, OQKV_PAD);
        dw_pm8<CQKV><<<CB * 576, blk, 0, stream>>>(qkv_pre, wdwT1, qkvb, CB);
        gram_pm<<<dim3(64, CB), blk, 0, stream>>>(qkvb, S32, Q2, K2, b0);
        attn_fold<<<CB, blk, 0, stream>>>(S32, Q2, K2, temp, projw, Mbf, b0);
        // out1(fp16) = bfX + M @ v
        gemm_pm<1><<<dim3(256, OM_PAD / 128, CB), blk, 0, stream>>>(
            Mbf + (size_t)b0 * OM_PAD * NC, (long)OM_PAD * NC, OM_PAD, NC, 192,
            qkvb, CQKV, 384, out1, NC, bfX, NC,
            nullptr, nullptr, nullptr, nullptr, 0);

        // ---- FFN branch ----
        ln_stats_pm8<<<CB * 512, blk, 0, stream>>>(out1, mu2b, rs2b, CB);
        gemm_pm<0><<<dim3(256, CPIN / 128, CB), blk, 0, stream>>>(
            A2 + (size_t)b0 * CPIN * 192, (long)CPIN * 192, CPIN, CPIN, 192,
            out1, NC, 0, u_pre, CPIN, nullptr, 0,
            mu2b, rs2b, u2 + (size_t)b0 * CPIN, v02 + (size_t)b0 * CPIN, CPIN);
        dw_gate<CPIN, CG><<<CB * (NHW / 4) * (CG / 8) / 256, blk, 0, stream>>>(
            u_pre, wdwT2, gbuf, CB);
        // d_out (f32 channel-major) = out1 + pout @ g, written directly
        gemm_pm<3><<<dim3(256, OM_PAD / 128, CB), blk, 0, stream>>>(
            A3, 0, OM_PAD, NC, 512,
            gbuf, CG, 0, out + (size_t)b0 * NC * NHW, 0, out1, NC,
            nullptr, nullptr, nullptr, nullptr, 0);
    }
}

// Round 9
// 785.263 us; speedup vs baseline: 3.5934x; 1.0200x over previous
//
#include <hip/hip_runtime.h>
#include <math.h>

#define NB 8
#define NC 192
#define NHEADS 8
#define NCF 24
#define NHW 16384
#define NWID 128
#define CQKV 576
#define OQKV_PAD 640
#define CPIN 1024
#define CG 512
#define OM_PAD 256

typedef unsigned short bfu;                 // fp16 bit patterns
typedef _Float16 f16x8 __attribute__((ext_vector_type(8)));
typedef _Float16 f16x2 __attribute__((ext_vector_type(2)));
typedef float f32x4 __attribute__((ext_vector_type(4)));

__device__ __forceinline__ unsigned short f2h(float f) {
    _Float16 h = (_Float16)f;
    return __builtin_bit_cast(unsigned short, h);
}
__device__ __forceinline__ float h2f(unsigned short u) {
    return (float)__builtin_bit_cast(_Float16, u);
}
__device__ __forceinline__ float gelu_tanh(float x) {
    float x3 = x * x * x;
    float z = 0.7978845608028654f * fmaf(0.044715f, x3, x);
    float e = __expf(2.f * z);
    float th = 1.f - 2.f / (e + 1.f);
    return 0.5f * x * (1.f + th);
}

struct F8 { float v[8]; };
union H8 { uint4 u; f16x2 h[4]; };
__device__ __forceinline__ F8 loadh8(const bfu* p) {
    uint4 r = *(const uint4*)p;
    F8 o;
    o.v[0] = h2f((unsigned short)(r.x & 0xffff)); o.v[1] = h2f((unsigned short)(r.x >> 16));
    o.v[2] = h2f((unsigned short)(r.y & 0xffff)); o.v[3] = h2f((unsigned short)(r.y >> 16));
    o.v[4] = h2f((unsigned short)(r.z & 0xffff)); o.v[5] = h2f((unsigned short)(r.z >> 16));
    o.v[6] = h2f((unsigned short)(r.w & 0xffff)); o.v[7] = h2f((unsigned short)(r.w >> 16));
    return o;
}
__device__ __forceinline__ void storeh8(bfu* p, const float* a) {
    uint4 r;
    r.x = (unsigned)f2h(a[0]) | ((unsigned)f2h(a[1]) << 16);
    r.y = (unsigned)f2h(a[2]) | ((unsigned)f2h(a[3]) << 16);
    r.z = (unsigned)f2h(a[4]) | ((unsigned)f2h(a[5]) << 16);
    r.w = (unsigned)f2h(a[6]) | ((unsigned)f2h(a[7]) << 16);
    *(uint4*)p = r;
}
__device__ __forceinline__ f16x2 h2z() {
    f16x2 z; z[0] = (_Float16)0.f; z[1] = (_Float16)0.f; return z;
}

__global__ __launch_bounds__(256) void zfill(float* __restrict__ p, int n) {
    int i = blockIdx.x * 256 + threadIdx.x;
    if (i < n) p[i] = 0.f;
}

// ---------------------------------------------------------------------------
// prep_film, wave-parallel. grid (48, NB) x 256.
// ---------------------------------------------------------------------------
__global__ __launch_bounds__(256) void prep_film(
    const float* __restrict__ kv, const float* __restrict__ kern,
    const float* __restrict__ lnw, const float* __restrict__ lnb,
    float* __restrict__ sArr, float* __restrict__ tArr)
{
    const int b = blockIdx.y;
    const int wave = threadIdx.x >> 6, lane = threadIdx.x & 63;
    const int r = blockIdx.x * 4 + wave;
    const float* kvb = kv + b * 256;
    float4 kvv = *(const float4*)(kvb + lane * 4);
    float4 k1 = *(const float4*)(kern + (size_t)r * 256 + lane * 4);
    float4 k2 = *(const float4*)(kern + (size_t)(r + NC) * 256 + lane * 4);
    float d1 = kvv.x * k1.x + kvv.y * k1.y + kvv.z * k1.z + kvv.w * k1.w;
    float d2 = kvv.x * k2.x + kvv.y * k2.y + kvv.z * k2.z + kvv.w * k2.w;
    #pragma unroll
    for (int off = 32; off; off >>= 1) {
        d1 += __shfl_down(d1, off, 64);
        d2 += __shfl_down(d2, off, 64);
    }
    if (lane == 0) {
        sArr[b * NC + r] = lnw[r] * d1;
        tArr[b * NC + r] = lnb[r] * d1 + d2;
    }
}

// ---------------------------------------------------------------------------
// Build fp16 A in MFMA-fragment-packed layout + u, v0. Wave-per-row.
// ---------------------------------------------------------------------------
__global__ __launch_bounds__(256) void wprep(
    const float* __restrict__ W, const float* __restrict__ sA, const float* __restrict__ tA,
    bfu* __restrict__ Abf, float* __restrict__ u, float* __restrict__ v0, int mode)
{
    const int wave = threadIdx.x >> 6, lane = threadIdx.x & 63;
    const int o = blockIdx.x * 4 + wave;
    const int b = blockIdx.y;
    const int Opad = (mode == 0) ? OQKV_PAD : (mode == 1 ? CPIN : OM_PAD);
    const int K = (mode == 2) ? 512 : 192;
    const int Kr = (mode == 2) ? 510 : 192;
    const int K32 = K >> 5;
    int src;
    if (mode == 0) src = (o < 576) ? o : -1;
    else if (mode == 1) src = (o < 510) ? o : (o < 512 ? -1 : (o < 1022 ? o - 2 : -1));
    else src = (o < 192) ? o : -1;
    const float* wr = (src >= 0) ? W + (size_t)src * Kr : nullptr;
    const float* sb = sA + b * NC;
    const float* tb = tA + b * NC;
    bfu* abase = Abf + (size_t)b * Opad * K;
    float au = 0.f, av = 0.f;
    for (int c0 = lane * 4; c0 < K; c0 += 256) {
        float a[4] = {0.f, 0.f, 0.f, 0.f};
        if (src >= 0) {
            #pragma unroll
            for (int j = 0; j < 4; ++j) {
                int c = c0 + j;
                if (c < Kr) {
                    float w = wr[c];
                    if (mode == 2) a[j] = w;
                    else { a[j] = w * sb[c]; av = fmaf(w, tb[c], av); }
                }
            }
        }
        ushort4 pk;
        bfu b0 = f2h(a[0]), b1 = f2h(a[1]), b2 = f2h(a[2]), b3 = f2h(a[3]);
        pk.x = b0; pk.y = b1; pk.z = b2; pk.w = b3;
        au += h2f(b0) + h2f(b1) + h2f(b2) + h2f(b3);
        int frag = (o >> 4) * K32 + (c0 >> 5);
        int within = ((c0 >> 3) & 3) * 128 + (o & 15) * 8 + (c0 & 7);
        *(ushort4*)(abase + (size_t)frag * 512 + within) = pk;
    }
    if (mode < 2) {
        #pragma unroll
        for (int off = 32; off; off >>= 1) {
            au += __shfl_down(au, off, 64);
            av += __shfl_down(av, off, 64);
        }
        if (lane == 0) {
            u[(size_t)b * Opad + o] = au;
            v0[(size_t)b * Opad + o] = (src >= 0) ? av : 0.f;
        }
    }
}

// transpose dw weights to fp16
__global__ __launch_bounds__(256) void wdw_prep(
    const float* __restrict__ src, bfu* __restrict__ dstT, int C, int mode)
{
    int i = blockIdx.x * 256 + threadIdx.x;
    if (i >= 9 * C) return;
    int tap = i / C, col = i % C;
    float v;
    if (mode == 0) v = src[(size_t)col * 9 + tap];
    else {
        if (col < 512) v = (col < 510) ? src[(size_t)col * 9 + tap] : 0.f;
        else { int c2 = col - 512; v = (c2 < 510) ? src[(size_t)(510 + c2) * 9 + tap] : 0.f; }
    }
    dstT[(size_t)tap * C + col] = f2h(v);
}

// ---------------------------------------------------------------------------
// fp16 convert only (stats now computed inside the GEMM): channel-major fp32
// -> pixel-major fp16 via LDS transpose. Block = 64 px. grid CB*256.
// ---------------------------------------------------------------------------
__global__ __launch_bounds__(256) void ln_cvt_cm(
    const float* __restrict__ x, bfu* __restrict__ xbf, int cb)
{
    __shared__ bfu lt[64][198];
    const int blkpx = blockIdx.x;
    const int b = blkpx >> 8;
    const int n0 = (blkpx & 255) * 64;
    const int tid = threadIdx.x;
    #pragma unroll
    for (int it = 0; it < 12; ++it) {
        int task = it * 256 + tid;
        int c = task >> 4, q = task & 15;
        float4 v = *(const float4*)(x + ((size_t)b * NC + c) * NHW + n0 + q * 4);
        lt[q * 4 + 0][c] = f2h(v.x);
        lt[q * 4 + 1][c] = f2h(v.y);
        lt[q * 4 + 2][c] = f2h(v.z);
        lt[q * 4 + 3][c] = f2h(v.w);
    }
    __syncthreads();
    #pragma unroll
    for (int it = 0; it < 6; ++it) {
        int task = it * 256 + tid;
        int px = task / 24, ckk = task % 24;
        const unsigned* row = (const unsigned*)&lt[px][0];
        uint4 o;
        o.x = row[ckk * 4 + 0]; o.y = row[ckk * 4 + 1];
        o.z = row[ckk * 4 + 2]; o.w = row[ckk * 4 + 3];
        *(uint4*)(xbf + ((size_t)b * NHW + n0 + px) * NC + ckk * 8) = o;
    }
}

// ---------------------------------------------------------------------------
// MFMA GEMM (fp16), A fragment-packed.
// EPI 0/1 (K=192): tile 128o x 128px, single-stage full-K LDS (pitch 200).
//   EPI 0 computes LN stats IN-KERNEL from the staged tile.
// EPI 3 (K=512): tile 128o x 64px, BK=64 double-buffered; f32 channel-major out.
// ---------------------------------------------------------------------------
template<int EPI>
__global__ __launch_bounds__(256) void gemm_pm(
    const bfu* __restrict__ A, long aBStride, int Opad, int Oreal, int K,
    const bfu* __restrict__ X, int xRow, int xOff,
    void* __restrict__ Y, int yRow,
    const void* __restrict__ res, int resRow,
    const float* __restrict__ uvec, const float* __restrict__ v0vec, int uStride)
{
    constexpr bool FULLK = (EPI != 3);
    constexpr int SMEMSZ = FULLK ? (128 * 200 * 2 + 128 * 8) : 33024;
    __shared__ __align__(16) char smem[SMEMSZ];
    bfu* xs = (bfu*)smem;
    bfu (*stg)[136] = (bfu(*)[136])smem;       // epilogue fp16 (EPI 0/1)
    float (*stg32)[129] = (float(*)[129])smem; // epilogue f32 (EPI 3)
    float* smu = (float*)(smem + 128 * 200 * 2);
    float* srs = smu + 128;

    const int b = blockIdx.z;
    const int om = blockIdx.y * 128;
    const int tid = threadIdx.x;
    const int lane = tid & 63, wave = tid >> 6;
    const int wy = wave >> 1, wx = wave & 1;
    const int l15 = lane & 15, kg = lane >> 4;
    const int K32 = K >> 5;
    const int o16b = (om >> 4) + wy * 4;
    const bfu* Ab = A + (size_t)b * aBStride;

    if constexpr (FULLK) {
        const int n0 = blockIdx.x * 128;
        const bfu* Xbase = X + ((size_t)b * NHW + n0) * xRow + xOff;

        f32x4 acc[4][4];
        #pragma unroll
        for (int i = 0; i < 4; ++i)
            #pragma unroll
            for (int j = 0; j < 4; ++j) acc[i][j] = (f32x4){0.f, 0.f, 0.f, 0.f};

        // stage 128 rows x 192 ch (pitch 200 halves)
        #pragma unroll
        for (int i = 0; i < 12; ++i) {
            int task = i * 256 + tid;        // 3072 = 128 rows x 24 chunks
            int r = task / 24, c = task % 24;
            uint4 v = *(const uint4*)(Xbase + (size_t)r * xRow + c * 8);
            *(uint4*)&xs[r * 200 + c * 8] = v;
        }
        __syncthreads();

        // in-kernel LN stats (2 threads per pixel)
        if (EPI == 0) {
            int px = tid >> 1, hh = tid & 1;
            float s = 0.f, ss = 0.f;
            #pragma unroll
            for (int i = 0; i < 12; ++i) {
                F8 v = loadh8(xs + px * 200 + hh * 96 + i * 8);
                #pragma unroll
                for (int j = 0; j < 8; ++j) { s += v.v[j]; ss = fmaf(v.v[j], v.v[j], ss); }
            }
            s += __shfl_xor(s, 1, 64);
            ss += __shfl_xor(ss, 1, 64);
            if (hh == 0) {
                float m = s * (1.f / 192.f);
                float var = ss * (1.f / 192.f) - m * m;
                smu[px] = m;
                srs[px] = rsqrtf(var + 1e-5f);
            }
        }

        #pragma unroll
        for (int k32 = 0; k32 < 6; ++k32) {
            f16x8 af[4], bfr[4];
            #pragma unroll
            for (int mf = 0; mf < 4; ++mf)
                af[mf] = *(const f16x8*)(Ab + ((size_t)(o16b + mf) * 6 + k32) * 512 + lane * 8);
            #pragma unroll
            for (int nf = 0; nf < 4; ++nf)
                bfr[nf] = *(const f16x8*)&xs[(wx * 64 + nf * 16 + l15) * 200 + k32 * 32 + kg * 8];
            #pragma unroll
            for (int mf = 0; mf < 4; ++mf)
                #pragma unroll
                for (int nf = 0; nf < 4; ++nf)
                    acc[mf][nf] = __builtin_amdgcn_mfma_f32_16x16x32_f16(af[mf], bfr[nf], acc[mf][nf], 0, 0, 0);
        }
        __syncthreads();

        // stage accumulators to LDS (aliases xs; barrier above protects)
        #pragma unroll
        for (int nf = 0; nf < 4; ++nf) {
            const int nl = wx * 64 + nf * 16 + l15;
            float muv = 0.f, rsv = 0.f;
            if (EPI == 0) { muv = smu[nl]; rsv = srs[nl]; }
            #pragma unroll
            for (int mf = 0; mf < 4; ++mf) {
                const int obl = wy * 64 + mf * 16 + kg * 4;
                float r0, r1, r2, r3;
                if (EPI == 0) {
                    float4 uv = *(const float4*)(uvec + (size_t)b * uStride + om + obl);
                    float4 vv = *(const float4*)(v0vec + (size_t)b * uStride + om + obl);
                    r0 = rsv * (acc[mf][nf][0] - muv * uv.x) + vv.x;
                    r1 = rsv * (acc[mf][nf][1] - muv * uv.y) + vv.y;
                    r2 = rsv * (acc[mf][nf][2] - muv * uv.z) + vv.z;
                    r3 = rsv * (acc[mf][nf][3] - muv * uv.w) + vv.w;
                } else {
                    r0 = acc[mf][nf][0]; r1 = acc[mf][nf][1];
                    r2 = acc[mf][nf][2]; r3 = acc[mf][nf][3];
                }
                ushort4 pk;
                pk.x = f2h(r0); pk.y = f2h(r1); pk.z = f2h(r2); pk.w = f2h(r3);
                *(ushort4*)&stg[nl][obl] = pk;
            }
        }
        __syncthreads();

        // coalesced writeout (128 px x 16 o-chunks)
        #pragma unroll
        for (int it = 0; it < 8; ++it) {
            int task = it * 256 + tid;
            int nl = task >> 4, ch = task & 15;
            int oc = om + ch * 8;
            if (oc >= Oreal) continue;
            uint4 sv = *(const uint4*)&stg[nl][ch * 8];
            size_t nglob = (size_t)b * NHW + n0 + nl;
            if (EPI == 0) {
                *(uint4*)((bfu*)Y + nglob * yRow + oc) = sv;
            } else {
                float a[8];
                a[0] = h2f((unsigned short)(sv.x & 0xffff)); a[1] = h2f((unsigned short)(sv.x >> 16));
                a[2] = h2f((unsigned short)(sv.y & 0xffff)); a[3] = h2f((unsigned short)(sv.y >> 16));
                a[4] = h2f((unsigned short)(sv.z & 0xffff)); a[5] = h2f((unsigned short)(sv.z >> 16));
                a[6] = h2f((unsigned short)(sv.w & 0xffff)); a[7] = h2f((unsigned short)(sv.w >> 16));
                F8 rv = loadh8((const bfu*)res + nglob * resRow + oc);
                #pragma unroll
                for (int j = 0; j < 8; ++j) a[j] += rv.v[j];
                storeh8((bfu*)Y + nglob * yRow + oc, a);
            }
        }
    } else {
        // ---- EPI 3: K=512 double-buffered, 64px tile, f32 channel-major out ----
        const int n0 = blockIdx.x * 64;
        const bfu* Xbase = X + ((size_t)b * NHW + n0) * xRow + xOff;
        const int sr = tid >> 3, sc = tid & 7;
        const int NCH = K >> 6;

        f32x4 acc[4][2];
        #pragma unroll
        for (int i = 0; i < 4; ++i)
            #pragma unroll
            for (int j = 0; j < 2; ++j) acc[i][j] = (f32x4){0.f, 0.f, 0.f, 0.f};

        #pragma unroll
        for (int i = 0; i < 2; ++i) {
            int r = i * 32 + sr;
            uint4 v = *(const uint4*)(Xbase + (size_t)r * xRow + sc * 8);
            *(uint4*)&xs[r * 72 + sc * 8] = v;
        }
        __syncthreads();
        for (int kc = 0; kc < NCH; ++kc) {
            const int cur = kc & 1;
            if (kc + 1 < NCH) {
                #pragma unroll
                for (int i = 0; i < 2; ++i) {
                    int r = i * 32 + sr;
                    uint4 v = *(const uint4*)(Xbase + (size_t)r * xRow + (kc + 1) * 64 + sc * 8);
                    *(uint4*)&xs[((cur ^ 1) * 64 + r) * 72 + sc * 8] = v;
                }
            }
            #pragma unroll
            for (int ks = 0; ks < 2; ++ks) {
                const int k32 = kc * 2 + ks;
                f16x8 af[4], bfr[2];
                #pragma unroll
                for (int mf = 0; mf < 4; ++mf)
                    af[mf] = *(const f16x8*)(Ab + ((size_t)(o16b + mf) * K32 + k32) * 512 + lane * 8);
                #pragma unroll
                for (int nf = 0; nf < 2; ++nf)
                    bfr[nf] = *(const f16x8*)&xs[(cur * 64 + wx * 32 + nf * 16 + l15) * 72 + ks * 32 + kg * 8];
                #pragma unroll
                for (int mf = 0; mf < 4; ++mf)
                    #pragma unroll
                    for (int nf = 0; nf < 2; ++nf)
                        acc[mf][nf] = __builtin_amdgcn_mfma_f32_16x16x32_f16(af[mf], bfr[nf], acc[mf][nf], 0, 0, 0);
            }
            __syncthreads();
        }

        #pragma unroll
        for (int nf = 0; nf < 2; ++nf) {
            const int nl = wx * 32 + nf * 16 + l15;
            #pragma unroll
            for (int mf = 0; mf < 4; ++mf) {
                const int obl = wy * 64 + mf * 16 + kg * 4;
                stg32[nl][obl + 0] = acc[mf][nf][0];
                stg32[nl][obl + 1] = acc[mf][nf][1];
                stg32[nl][obl + 2] = acc[mf][nf][2];
                stg32[nl][obl + 3] = acc[mf][nf][3];
            }
        }
        __syncthreads();

        #pragma unroll
        for (int it = 0; it < 8; ++it) {
            int task = it * 256 + tid;
            int o = task >> 4, q = task & 15;
            int oc = om + o;
            if (oc >= Oreal) continue;
            float vals[4];
            #pragma unroll
            for (int j = 0; j < 4; ++j) {
                float v = stg32[q * 4 + j][o];
                float r = h2f(((const bfu*)res)[((size_t)b * NHW + n0 + q * 4 + j) * resRow + oc]);
                vals[j] = v + r;
            }
            *(float4*)((float*)Y + ((size_t)b * NC + oc) * NHW + n0 + q * 4) =
                make_float4(vals[0], vals[1], vals[2], vals[3]);
        }
    }
}

// ---------------------------------------------------------------------------
// depthwise 3x3, fp16 packed math, thread = 8ch x 8px (no gate).
// ---------------------------------------------------------------------------
template<int CIN>
__global__ __launch_bounds__(256) void dw_pm8(
    const bfu* __restrict__ in, const bfu* __restrict__ wT, bfu* __restrict__ out, int cb)
{
    const int CHUNKS = CIN / 8;
    const int NPB = NHW / 8;
    int f = blockIdx.x * 256 + threadIdx.x;
    if (f >= cb * NPB * CHUNKS) return;
    int ch = f % CHUNKS;
    int pb = f / CHUNKS;
    int n8 = pb & (NPB - 1);
    int b  = pb >> 11;
    int xq = n8 & 15, y = n8 >> 4;
    int x0 = xq * 8;
    const int c8 = ch * 8;
    const bfu* rowb = in + ((size_t)b * NHW + (size_t)y * NWID) * CIN + c8;

    f16x2 acc[8][4];
    #pragma unroll
    for (int j = 0; j < 8; ++j)
        #pragma unroll
        for (int q = 0; q < 4; ++q) acc[j][q] = h2z();

    #pragma unroll
    for (int dy = -1; dy <= 1; ++dy) {
        int yy = y + dy;
        if ((unsigned)yy >= (unsigned)NWID) continue;
        const bfu* rb = rowb + (long)dy * NWID * CIN;
        f16x2 w1[3][4];
        #pragma unroll
        for (int t = 0; t < 3; ++t) {
            H8 wv; wv.u = *(const uint4*)(wT + (size_t)((dy + 1) * 3 + t) * CIN + c8);
            #pragma unroll
            for (int q = 0; q < 4; ++q) w1[t][q] = wv.h[q];
        }
        #pragma unroll
        for (int c = 0; c < 10; ++c) {
            int xx = x0 - 1 + c;
            if ((unsigned)xx >= (unsigned)NWID) continue;
            H8 v; v.u = *(const uint4*)(rb + (size_t)xx * CIN);
            #pragma unroll
            for (int j = 0; j < 8; ++j) {
                int t = c - j;
                if (t < 0 || t > 2) continue;
                #pragma unroll
                for (int q = 0; q < 4; ++q)
                    acc[j][q] = w1[t][q] * v.h[q] + acc[j][q];
            }
        }
    }
    #pragma unroll
    for (int j = 0; j < 8; ++j) {
        H8 o;
        #pragma unroll
        for (int q = 0; q < 4; ++q) o.h[q] = acc[j][q];
        *(uint4*)(out + ((size_t)b * NHW + (size_t)y * NWID + x0 + j) * CIN + c8) = o.u;
    }
}

// ---------------------------------------------------------------------------
// depthwise 3x3 + GELU gate, fp16 packed math, thread = 8ch x 8px.
// ---------------------------------------------------------------------------
template<int CIN, int COUT>
__global__ __launch_bounds__(256) void dw_gate8(
    const bfu* __restrict__ in, const bfu* __restrict__ wT, bfu* __restrict__ out, int cb)
{
    const int CHUNKS = COUT / 8;      // 64
    const int NPB = NHW / 8;          // 2048
    int f = blockIdx.x * 256 + threadIdx.x;
    if (f >= cb * NPB * CHUNKS) return;
    int ch = f % CHUNKS;
    int pb = f / CHUNKS;
    int n8 = pb & (NPB - 1);
    int b  = pb >> 11;
    int xq = n8 & 15, y = n8 >> 4;
    int x0 = xq * 8;
    const int c8 = ch * 8;
    const bfu* rowb = in + ((size_t)b * NHW + (size_t)y * NWID) * CIN + c8;

    f16x2 a1[8][4], a2[8][4];
    #pragma unroll
    for (int j = 0; j < 8; ++j)
        #pragma unroll
        for (int q = 0; q < 4; ++q) { a1[j][q] = h2z(); a2[j][q] = h2z(); }

    #pragma unroll
    for (int dy = -1; dy <= 1; ++dy) {
        int yy = y + dy;
        if ((unsigned)yy >= (unsigned)NWID) continue;
        const bfu* rb = rowb + (long)dy * NWID * CIN;
        f16x2 w1[3][4], w2[3][4];
        #pragma unroll
        for (int t = 0; t < 3; ++t) {
            const bfu* wp = wT + (size_t)((dy + 1) * 3 + t) * CIN + c8;
            H8 wa; wa.u = *(const uint4*)wp;
            H8 wb; wb.u = *(const uint4*)(wp + 512);
            #pragma unroll
            for (int q = 0; q < 4; ++q) { w1[t][q] = wa.h[q]; w2[t][q] = wb.h[q]; }
        }
        #pragma unroll
        for (int c = 0; c < 10; ++c) {
            int xx = x0 - 1 + c;
            if ((unsigned)xx >= (unsigned)NWID) continue;
            H8 v1; v1.u = *(const uint4*)(rb + (size_t)xx * CIN);
            H8 v2; v2.u = *(const uint4*)(rb + (size_t)xx * CIN + 512);
            #pragma unroll
            for (int j = 0; j < 8; ++j) {
                int t = c - j;
                if (t < 0 || t > 2) continue;
                #pragma unroll
                for (int q = 0; q < 4; ++q) {
                    a1[j][q] = w1[t][q] * v1.h[q] + a1[j][q];
                    a2[j][q] = w2[t][q] * v2.h[q] + a2[j][q];
                }
            }
        }
    }
    #pragma unroll
    for (int j = 0; j < 8; ++j) {
        H8 o;
        #pragma unroll
        for (int q = 0; q < 4; ++q) {
            float g0 = gelu_tanh((float)a1[j][q][0]) * (float)a2[j][q][0];
            float g1 = gelu_tanh((float)a1[j][q][1]) * (float)a2[j][q][1];
            f16x2 r; r[0] = (_Float16)g0; r[1] = (_Float16)g1;
            o.h[q] = r;
        }
        *(uint4*)(out + ((size_t)b * NHW + (size_t)y * NWID + x0 + j) * COUT + c8) = o.u;
    }
}

// ---------------------------------------------------------------------------
// MFMA Gram (fp16). grid (64 n-chunks, CB). 4 waves x 2 heads each.
// ---------------------------------------------------------------------------
__global__ __launch_bounds__(256) void gram_pm(
    const bfu* __restrict__ qkv, float* __restrict__ S32,
    float* __restrict__ Q2, float* __restrict__ K2, int b0)
{
    __shared__ bfu lds[392 * 72];
    const int b = blockIdx.y;
    const int nc = blockIdx.x;
    const int tid = threadIdx.x;
    const int lane = tid & 63, wave = tid >> 6;
    const int l15 = lane & 15, kg = lane >> 4;

    f32x4 sAcc[2][2][2], qAcc[2][2], kAcc[2][2];
    #pragma unroll
    for (int h = 0; h < 2; ++h)
        #pragma unroll
        for (int i = 0; i < 2; ++i) {
            qAcc[h][i] = (f32x4){0.f, 0.f, 0.f, 0.f};
            kAcc[h][i] = (f32x4){0.f, 0.f, 0.f, 0.f};
            #pragma unroll
            for (int j = 0; j < 2; ++j) sAcc[h][i][j] = (f32x4){0.f, 0.f, 0.f, 0.f};
        }

    const size_t pbase = (size_t)b * NHW + (size_t)nc * 256;
    unsigned* ldsw = (unsigned*)lds;

    for (int it = 0; it < 4; ++it) {
        const size_t nb = pbase + it * 64;
        #pragma unroll
        for (int i = 0; i < 6; ++i) {
            int task = i * 256 + tid;
            int np = task & 31, ch = task >> 5;
            const bfu* r0 = qkv + (nb + np * 2) * CQKV + ch * 8;
            uint4 v0 = *(const uint4*)r0;
            uint4 v1 = *(const uint4*)(r0 + CQKV);
            int cb8 = ch * 8;
            ldsw[(cb8 + 0) * 36 + np] = (v0.x & 0xffffu) | (v1.x << 16);
            ldsw[(cb8 + 1) * 36 + np] = (v0.x >> 16) | (v1.x & 0xffff0000u);
            ldsw[(cb8 + 2) * 36 + np] = (v0.y & 0xffffu) | (v1.y << 16);
            ldsw[(cb8 + 3) * 36 + np] = (v0.y >> 16) | (v1.y & 0xffff0000u);
            ldsw[(cb8 + 4) * 36 + np] = (v0.z & 0xffffu) | (v1.z << 16);
            ldsw[(cb8 + 5) * 36 + np] = (v0.z >> 16) | (v1.z & 0xffff0000u);
            ldsw[(cb8 + 6) * 36 + np] = (v0.w & 0xffffu) | (v1.w << 16);
            ldsw[(cb8 + 7) * 36 + np] = (v0.w >> 16) | (v1.w & 0xffff0000u);
        }
        ldsw[(384 + (tid >> 5)) * 36 + (tid & 31)] = 0;
        __syncthreads();
        #pragma unroll
        for (int hh = 0; hh < 2; ++hh) {
            const int h = wave * 2 + hh;
            const int qr = h * NCF, kr = NC + h * NCF;
            #pragma unroll
            for (int ks = 0; ks < 2; ++ks) {
                const int nsub = ks * 32 + kg * 8;
                f16x8 aq0 = *(const f16x8*)(lds + (qr + l15) * 72 + nsub);
                f16x8 aq1 = *(const f16x8*)(lds + (qr + 16 + l15) * 72 + nsub);
                f16x8 bk0 = *(const f16x8*)(lds + (kr + l15) * 72 + nsub);
                f16x8 bk1 = *(const f16x8*)(lds + (kr + 16 + l15) * 72 + nsub);
                sAcc[hh][0][0] = __builtin_amdgcn_mfma_f32_16x16x32_f16(aq0, bk0, sAcc[hh][0][0], 0, 0, 0);
                sAcc[hh][0][1] = __builtin_amdgcn_mfma_f32_16x16x32_f16(aq0, bk1, sAcc[hh][0][1], 0, 0, 0);
                sAcc[hh][1][0] = __builtin_amdgcn_mfma_f32_16x16x32_f16(aq1, bk0, sAcc[hh][1][0], 0, 0, 0);
                sAcc[hh][1][1] = __builtin_amdgcn_mfma_f32_16x16x32_f16(aq1, bk1, sAcc[hh][1][1], 0, 0, 0);
                qAcc[hh][0] = __builtin_amdgcn_mfma_f32_16x16x32_f16(aq0, aq0, qAcc[hh][0], 0, 0, 0);
                qAcc[hh][1] = __builtin_amdgcn_mfma_f32_16x16x32_f16(aq1, aq1, qAcc[hh][1], 0, 0, 0);
                kAcc[hh][0] = __builtin_amdgcn_mfma_f32_16x16x32_f16(bk0, bk0, kAcc[hh][0], 0, 0, 0);
                kAcc[hh][1] = __builtin_amdgcn_mfma_f32_16x16x32_f16(bk1, bk1, kAcc[hh][1], 0, 0, 0);
            }
        }
        __syncthreads();
    }

    const int gb = b0 + b;
    #pragma unroll
    for (int hh = 0; hh < 2; ++hh) {
        const int h = wave * 2 + hh;
        float* Sp = S32 + ((size_t)gb * NHEADS + h) * 1024;
        #pragma unroll
        for (int mt = 0; mt < 2; ++mt)
            #pragma unroll
            for (int nt = 0; nt < 2; ++nt)
                #pragma unroll
                for (int r = 0; r < 4; ++r) {
                    int c = mt * 16 + kg * 4 + r, d = nt * 16 + l15;
                    atomicAdd(&Sp[c * 32 + d], sAcc[hh][mt][nt][r]);
                }
        #pragma unroll
        for (int t = 0; t < 2; ++t)
            #pragma unroll
            for (int r = 0; r < 4; ++r) {
                int row = t * 16 + kg * 4 + r, col = t * 16 + l15;
                if (row == col && row < NCF) {
                    atomicAdd(&Q2[((size_t)gb * NHEADS + h) * NCF + row], qAcc[hh][t][r]);
                    atomicAdd(&K2[((size_t)gb * NHEADS + h) * NCF + row], kAcc[hh][t][r]);
                }
            }
    }
}

// ---------------------------------------------------------------------------
// normalize -> softmax -> fold proj_w -> Mbf packed-fragment fp16. grid(CB)
// ---------------------------------------------------------------------------
__global__ __launch_bounds__(256) void attn_fold(
    const float* __restrict__ S32, const float* __restrict__ Q2, const float* __restrict__ K2,
    const float* __restrict__ temp, const float* __restrict__ projw, bfu* __restrict__ Mbf, int b0)
{
    const int gb = b0 + blockIdx.x, tid = threadIdx.x;
    __shared__ float P[NHEADS * NCF * NCF];
    for (int e = tid; e < NHEADS * NCF * NCF; e += 256) {
        int h = e / (NCF * NCF);
        int r = e % (NCF * NCF);
        int c = r / NCF, d = r % NCF;
        float sv = S32[((size_t)gb * NHEADS + h) * 1024 + c * 32 + d];
        float rq = sqrtf(Q2[((size_t)gb * NHEADS + h) * NCF + c]);
        float rk = sqrtf(K2[((size_t)gb * NHEADS + h) * NCF + d]);
        P[e] = sv / (rq * rk) * temp[h];
    }
    __syncthreads();
    if (tid < NHEADS * NCF) {
        int h = tid / NCF, c = tid % NCF;
        float* row = P + h * (NCF * NCF) + c * NCF;
        float mx = row[0];
        #pragma unroll
        for (int d = 1; d < NCF; ++d) mx = fmaxf(mx, row[d]);
        float sum = 0.f;
        #pragma unroll
        for (int d = 0; d < NCF; ++d) { float e2 = __expf(row[d] - mx); row[d] = e2; sum += e2; }
        float inv = 1.f / sum;
        #pragma unroll
        for (int d = 0; d < NCF; ++d) row[d] *= inv;
    }
    __syncthreads();
    bfu* Mb = Mbf + (size_t)gb * OM_PAD * NC;
    if (tid < NC) {
        int o = tid;
        int o16 = o >> 4, l15o = o & 15;
        for (int h = 0; h < NHEADS; ++h) {
            float pw[NCF];
            #pragma unroll
            for (int c = 0; c < NCF; ++c) pw[c] = projw[(size_t)o * NC + h * NCF + c];
            #pragma unroll
            for (int d = 0; d < NCF; ++d) {
                float acc = 0.f;
                #pragma unroll
                for (int c = 0; c < NCF; ++c) acc = fmaf(pw[c], P[h * (NCF * NCF) + c * NCF + d], acc);
                int cc = h * NCF + d;
                int idx = (o16 * 6 + (cc >> 5)) * 512 + ((cc >> 3) & 3) * 128 + l15o * 8 + (cc & 7);
                Mb[idx] = f2h(acc);
            }
        }
    }
    for (int e = tid; e < (OM_PAD - NC) * NC; e += 256) Mb[NC * NC + e] = 0;
}

// ---------------------------------------------------------------------------
extern "C" void kernel_launch(void* const* d_in, const int* in_sizes, int n_in,
                              void* d_out, int out_size, void* d_ws, size_t ws_size,
                              hipStream_t stream)
{
    const float* x     = (const float*)d_in[0];
    const float* kv    = (const float*)d_in[1];
    const float* ln1w  = (const float*)d_in[2];
    const float* ln1b  = (const float*)d_in[3];
    const float* akern = (const float*)d_in[4];
    const float* qkvw  = (const float*)d_in[5];
    const float* qkvdw = (const float*)d_in[6];
    const float* projw = (const float*)d_in[7];
    const float* temp  = (const float*)d_in[8];
    const float* ln2w  = (const float*)d_in[9];
    const float* ln2b  = (const float*)d_in[10];
    const float* fkern = (const float*)d_in[11];
    const float* pinw  = (const float*)d_in[12];
    const float* ffndw = (const float*)d_in[13];
    const float* poutw = (const float*)d_in[14];
    float* out = (float*)d_out;

    char* wp = (char*)d_ws;
    size_t off = 0;
    auto take = [&](size_t bytes) {
        char* r = wp + off;
        off = (off + bytes + 255) & ~(size_t)255;
        return r;
    };
    float* s1 = (float*)take(NB * NC * 4);  float* t1 = (float*)take(NB * NC * 4);
    float* s2 = (float*)take(NB * NC * 4);  float* t2 = (float*)take(NB * NC * 4);
    bfu* A1 = (bfu*)take((size_t)NB * OQKV_PAD * 192 * 2);
    bfu* A2 = (bfu*)take((size_t)NB * CPIN * 192 * 2);
    bfu* A3 = (bfu*)take((size_t)OM_PAD * 512 * 2);
    bfu* Mbf = (bfu*)take((size_t)NB * OM_PAD * NC * 2);
    float* u1  = (float*)take((size_t)NB * OQKV_PAD * 4);
    float* v01 = (float*)take((size_t)NB * OQKV_PAD * 4);
    float* u2  = (float*)take((size_t)NB * CPIN * 4);
    float* v02 = (float*)take((size_t)NB * CPIN * 4);
    bfu* wdwT1 = (bfu*)take(9 * CQKV * 2);
    bfu* wdwT2 = (bfu*)take(9 * CPIN * 2);
    float* S32 = (float*)take((size_t)NB * NHEADS * 1024 * 4);
    float* Q2  = (float*)take((size_t)NB * NHEADS * NCF * 4);
    float* K2  = (float*)take((size_t)NB * NHEADS * NCF * 4);
    const size_t bigoff = off;

    const size_t PB = (size_t)NHW * (384 + 384 + 2048 + 1152);
    size_t avail = (ws_size > bigoff) ? ws_size - bigoff : 0;
    int CB = 8;
    while (CB > 1 && (size_t)CB * PB > avail) CB >>= 1;

    dim3 blk(256);

    prep_film<<<dim3(48, NB), blk, 0, stream>>>(kv, akern, ln1w, ln1b, s1, t1);
    prep_film<<<dim3(48, NB), blk, 0, stream>>>(kv, fkern, ln2w, ln2b, s2, t2);
    wprep<<<dim3(OQKV_PAD / 4, NB), blk, 0, stream>>>(qkvw, s1, t1, A1, u1, v01, 0);
    wprep<<<dim3(CPIN / 4, NB), blk, 0, stream>>>(pinw, s2, t2, A2, u2, v02, 1);
    wprep<<<dim3(OM_PAD / 4, 1), blk, 0, stream>>>(poutw, s1, t1, A3, nullptr, nullptr, 2);
    wdw_prep<<<(9 * CQKV + 255) / 256, blk, 0, stream>>>(qkvdw, wdwT1, CQKV, 0);
    wdw_prep<<<(9 * CPIN + 255) / 256, blk, 0, stream>>>(ffndw, wdwT2, CPIN, 1);
    {
        int nz = NB * NHEADS * 1024 + 2 * NB * NHEADS * NCF + 256;
        zfill<<<(nz + 255) / 256, blk, 0, stream>>>(S32, nz);
    }

    for (int b0 = 0; b0 < NB; b0 += CB) {
        bfu* bfX  = (bfu*)(wp + bigoff);
        bfu* out1 = (bfu*)(wp + bigoff + (size_t)CB * NHW * 384);
        char* big1 = wp + bigoff + (size_t)CB * NHW * 768;
        char* big2 = big1 + (size_t)CB * NHW * 2048;
        bfu* qkv_pre = (bfu*)big1;
        bfu* qkvb    = (bfu*)big2;
        bfu* u_pre   = (bfu*)big1;
        bfu* gbuf    = (bfu*)big2;

        const float* xb = x + (size_t)b0 * NC * NHW;

        // ---- attention branch ----
        ln_cvt_cm<<<CB * 256, blk, 0, stream>>>(xb, bfX, CB);
        gemm_pm<0><<<dim3(128, OQKV_PAD / 128, CB), blk, 0, stream>>>(
            A1 + (size_t)b0 * OQKV_PAD * 192, (long)OQKV_PAD * 192, OQKV_PAD, CQKV, 192,
            bfX, NC, 0, qkv_pre, CQKV, nullptr, 0,
            u1 + (size_t)b0 * OQKV_PAD, v01 + (size_t)b0 * OQKV_PAD, OQKV_PAD);
        dw_pm8<CQKV><<<CB * 576, blk, 0, stream>>>(qkv_pre, wdwT1, qkvb, CB);
        gram_pm<<<dim3(64, CB), blk, 0, stream>>>(qkvb, S32, Q2, K2, b0);
        attn_fold<<<CB, blk, 0, stream>>>(S32, Q2, K2, temp, projw, Mbf, b0);
        // out1(fp16) = bfX + M @ v
        gemm_pm<1><<<dim3(128, OM_PAD / 128, CB), blk, 0, stream>>>(
            Mbf + (size_t)b0 * OM_PAD * NC, (long)OM_PAD * NC, OM_PAD, NC, 192,
            qkvb, CQKV, 384, out1, NC, bfX, NC,
            nullptr, nullptr, 0);

        // ---- FFN branch ----
        gemm_pm<0><<<dim3(128, CPIN / 128, CB), blk, 0, stream>>>(
            A2 + (size_t)b0 * CPIN * 192, (long)CPIN * 192, CPIN, CPIN, 192,
            out1, NC, 0, u_pre, CPIN, nullptr, 0,
            u2 + (size_t)b0 * CPIN, v02 + (size_t)b0 * CPIN, CPIN);
        dw_gate8<CPIN, CG><<<CB * 512, blk, 0, stream>>>(u_pre, wdwT2, gbuf, CB);
        // d_out (f32 channel-major) = out1 + pout @ g, written directly
        gemm_pm<3><<<dim3(256, OM_PAD / 128, CB), blk, 0, stream>>>(
            A3, 0, OM_PAD, NC, 512,
            gbuf, CG, 0, out + (size_t)b0 * NC * NHW, 0, out1, NC,
            nullptr, nullptr, 0);
    }
}

// Round 10
// 718.263 us; speedup vs baseline: 3.9286x; 1.0933x over previous
//
#include <hip/hip_runtime.h>
#include <math.h>

#define NB 8
#define NC 192
#define NHEADS 8
#define NCF 24
#define NHW 16384
#define NWID 128
#define CQKV 576
#define OQKV_PAD 640
#define CPIN 1024
#define CG 512
#define OM_PAD 256

typedef unsigned short bfu;                 // fp16 bit patterns
typedef _Float16 f16x8 __attribute__((ext_vector_type(8)));
typedef _Float16 f16x2 __attribute__((ext_vector_type(2)));
typedef float f32x4 __attribute__((ext_vector_type(4)));

__device__ __forceinline__ unsigned short f2h(float f) {
    _Float16 h = (_Float16)f;
    return __builtin_bit_cast(unsigned short, h);
}
__device__ __forceinline__ float h2f(unsigned short u) {
    return (float)__builtin_bit_cast(_Float16, u);
}
__device__ __forceinline__ float gelu_tanh(float x) {
    float x3 = x * x * x;
    float z = 0.7978845608028654f * fmaf(0.044715f, x3, x);
    float e = __expf(2.f * z);
    float th = 1.f - 2.f / (e + 1.f);
    return 0.5f * x * (1.f + th);
}

struct F8 { float v[8]; };
union H8 { uint4 u; f16x2 h[4]; };
__device__ __forceinline__ F8 loadh8(const bfu* p) {
    uint4 r = *(const uint4*)p;
    F8 o;
    o.v[0] = h2f((unsigned short)(r.x & 0xffff)); o.v[1] = h2f((unsigned short)(r.x >> 16));
    o.v[2] = h2f((unsigned short)(r.y & 0xffff)); o.v[3] = h2f((unsigned short)(r.y >> 16));
    o.v[4] = h2f((unsigned short)(r.z & 0xffff)); o.v[5] = h2f((unsigned short)(r.z >> 16));
    o.v[6] = h2f((unsigned short)(r.w & 0xffff)); o.v[7] = h2f((unsigned short)(r.w >> 16));
    return o;
}
__device__ __forceinline__ void storeh8(bfu* p, const float* a) {
    uint4 r;
    r.x = (unsigned)f2h(a[0]) | ((unsigned)f2h(a[1]) << 16);
    r.y = (unsigned)f2h(a[2]) | ((unsigned)f2h(a[3]) << 16);
    r.z = (unsigned)f2h(a[4]) | ((unsigned)f2h(a[5]) << 16);
    r.w = (unsigned)f2h(a[6]) | ((unsigned)f2h(a[7]) << 16);
    *(uint4*)p = r;
}
__device__ __forceinline__ f16x2 h2z() {
    f16x2 z; z[0] = (_Float16)0.f; z[1] = (_Float16)0.f; return z;
}
// bijective chunked XCD remap (gridDim.x % 8 == 0)
__device__ __forceinline__ int xcd_swz(int bid, int nblk) {
    return (bid & 7) * (nblk >> 3) + (bid >> 3);
}

__global__ __launch_bounds__(256) void zfill(float* __restrict__ p, int n) {
    int i = blockIdx.x * 256 + threadIdx.x;
    if (i < n) p[i] = 0.f;
}

// ---------------------------------------------------------------------------
// prep_film, wave-parallel. grid (48, NB) x 256.
// ---------------------------------------------------------------------------
__global__ __launch_bounds__(256) void prep_film(
    const float* __restrict__ kv, const float* __restrict__ kern,
    const float* __restrict__ lnw, const float* __restrict__ lnb,
    float* __restrict__ sArr, float* __restrict__ tArr)
{
    const int b = blockIdx.y;
    const int wave = threadIdx.x >> 6, lane = threadIdx.x & 63;
    const int r = blockIdx.x * 4 + wave;
    const float* kvb = kv + b * 256;
    float4 kvv = *(const float4*)(kvb + lane * 4);
    float4 k1 = *(const float4*)(kern + (size_t)r * 256 + lane * 4);
    float4 k2 = *(const float4*)(kern + (size_t)(r + NC) * 256 + lane * 4);
    float d1 = kvv.x * k1.x + kvv.y * k1.y + kvv.z * k1.z + kvv.w * k1.w;
    float d2 = kvv.x * k2.x + kvv.y * k2.y + kvv.z * k2.z + kvv.w * k2.w;
    #pragma unroll
    for (int off = 32; off; off >>= 1) {
        d1 += __shfl_down(d1, off, 64);
        d2 += __shfl_down(d2, off, 64);
    }
    if (lane == 0) {
        sArr[b * NC + r] = lnw[r] * d1;
        tArr[b * NC + r] = lnb[r] * d1 + d2;
    }
}

// ---------------------------------------------------------------------------
// Build fp16 A in MFMA-fragment-packed layout + u, v0. Wave-per-row.
// ---------------------------------------------------------------------------
__global__ __launch_bounds__(256) void wprep(
    const float* __restrict__ W, const float* __restrict__ sA, const float* __restrict__ tA,
    bfu* __restrict__ Abf, float* __restrict__ u, float* __restrict__ v0, int mode)
{
    const int wave = threadIdx.x >> 6, lane = threadIdx.x & 63;
    const int o = blockIdx.x * 4 + wave;
    const int b = blockIdx.y;
    const int Opad = (mode == 0) ? OQKV_PAD : (mode == 1 ? CPIN : OM_PAD);
    const int K = (mode == 2) ? 512 : 192;
    const int Kr = (mode == 2) ? 510 : 192;
    const int K32 = K >> 5;
    int src;
    if (mode == 0) src = (o < 576) ? o : -1;
    else if (mode == 1) src = (o < 510) ? o : (o < 512 ? -1 : (o < 1022 ? o - 2 : -1));
    else src = (o < 192) ? o : -1;
    const float* wr = (src >= 0) ? W + (size_t)src * Kr : nullptr;
    const float* sb = sA + b * NC;
    const float* tb = tA + b * NC;
    bfu* abase = Abf + (size_t)b * Opad * K;
    float au = 0.f, av = 0.f;
    for (int c0 = lane * 4; c0 < K; c0 += 256) {
        float a[4] = {0.f, 0.f, 0.f, 0.f};
        if (src >= 0) {
            #pragma unroll
            for (int j = 0; j < 4; ++j) {
                int c = c0 + j;
                if (c < Kr) {
                    float w = wr[c];
                    if (mode == 2) a[j] = w;
                    else { a[j] = w * sb[c]; av = fmaf(w, tb[c], av); }
                }
            }
        }
        ushort4 pk;
        bfu b0 = f2h(a[0]), b1 = f2h(a[1]), b2 = f2h(a[2]), b3 = f2h(a[3]);
        pk.x = b0; pk.y = b1; pk.z = b2; pk.w = b3;
        au += h2f(b0) + h2f(b1) + h2f(b2) + h2f(b3);
        int frag = (o >> 4) * K32 + (c0 >> 5);
        int within = ((c0 >> 3) & 3) * 128 + (o & 15) * 8 + (c0 & 7);
        *(ushort4*)(abase + (size_t)frag * 512 + within) = pk;
    }
    if (mode < 2) {
        #pragma unroll
        for (int off = 32; off; off >>= 1) {
            au += __shfl_down(au, off, 64);
            av += __shfl_down(av, off, 64);
        }
        if (lane == 0) {
            u[(size_t)b * Opad + o] = au;
            v0[(size_t)b * Opad + o] = (src >= 0) ? av : 0.f;
        }
    }
}

// transpose dw weights to fp16
__global__ __launch_bounds__(256) void wdw_prep(
    const float* __restrict__ src, bfu* __restrict__ dstT, int C, int mode)
{
    int i = blockIdx.x * 256 + threadIdx.x;
    if (i >= 9 * C) return;
    int tap = i / C, col = i % C;
    float v;
    if (mode == 0) v = src[(size_t)col * 9 + tap];
    else {
        if (col < 512) v = (col < 510) ? src[(size_t)col * 9 + tap] : 0.f;
        else { int c2 = col - 512; v = (c2 < 510) ? src[(size_t)(510 + c2) * 9 + tap] : 0.f; }
    }
    dstT[(size_t)tap * C + col] = f2h(v);
}

// ---------------------------------------------------------------------------
// fp16 convert only: channel-major fp32 -> pixel-major fp16 via LDS transpose.
// ---------------------------------------------------------------------------
__global__ __launch_bounds__(256) void ln_cvt_cm(
    const float* __restrict__ x, bfu* __restrict__ xbf, int cb)
{
    __shared__ bfu lt[64][198];
    const int blkpx = blockIdx.x;
    const int b = blkpx >> 8;
    const int n0 = (blkpx & 255) * 64;
    const int tid = threadIdx.x;
    #pragma unroll
    for (int it = 0; it < 12; ++it) {
        int task = it * 256 + tid;
        int c = task >> 4, q = task & 15;
        float4 v = *(const float4*)(x + ((size_t)b * NC + c) * NHW + n0 + q * 4);
        lt[q * 4 + 0][c] = f2h(v.x);
        lt[q * 4 + 1][c] = f2h(v.y);
        lt[q * 4 + 2][c] = f2h(v.z);
        lt[q * 4 + 3][c] = f2h(v.w);
    }
    __syncthreads();
    #pragma unroll
    for (int it = 0; it < 6; ++it) {
        int task = it * 256 + tid;
        int px = task / 24, ckk = task % 24;
        const unsigned* row = (const unsigned*)&lt[px][0];
        uint4 o;
        o.x = row[ckk * 4 + 0]; o.y = row[ckk * 4 + 1];
        o.z = row[ckk * 4 + 2]; o.w = row[ckk * 4 + 3];
        *(uint4*)(xbf + ((size_t)b * NHW + n0 + px) * NC + ckk * 8) = o;
    }
}

// ---------------------------------------------------------------------------
// MFMA GEMM (fp16), A fragment-packed.
// EPI 0/1 (K=192): tile 128o x 128px, single-stage full-K LDS (pitch 200).
//   EPI 0 computes LN stats IN-KERNEL from the staged tile.
// EPI 3 (K=512): tile 128o x 64px, BK=64 double-buffered; f32 channel-major out.
// ---------------------------------------------------------------------------
template<int EPI>
__global__ __launch_bounds__(256) void gemm_pm(
    const bfu* __restrict__ A, long aBStride, int Opad, int Oreal, int K,
    const bfu* __restrict__ X, int xRow, int xOff,
    void* __restrict__ Y, int yRow,
    const void* __restrict__ res, int resRow,
    const float* __restrict__ uvec, const float* __restrict__ v0vec, int uStride)
{
    constexpr bool FULLK = (EPI != 3);
    constexpr int SMEMSZ = FULLK ? (128 * 200 * 2 + 128 * 8) : 33024;
    __shared__ __align__(16) char smem[SMEMSZ];
    bfu* xs = (bfu*)smem;
    bfu (*stg)[136] = (bfu(*)[136])smem;
    float (*stg32)[129] = (float(*)[129])smem;
    float* smu = (float*)(smem + 128 * 200 * 2);
    float* srs = smu + 128;

    const int b = blockIdx.z;
    const int om = blockIdx.y * 128;
    const int tid = threadIdx.x;
    const int lane = tid & 63, wave = tid >> 6;
    const int wy = wave >> 1, wx = wave & 1;
    const int l15 = lane & 15, kg = lane >> 4;
    const int K32 = K >> 5;
    const int o16b = (om >> 4) + wy * 4;
    const bfu* Ab = A + (size_t)b * aBStride;

    if constexpr (FULLK) {
        const int n0 = blockIdx.x * 128;
        const bfu* Xbase = X + ((size_t)b * NHW + n0) * xRow + xOff;

        f32x4 acc[4][4];
        #pragma unroll
        for (int i = 0; i < 4; ++i)
            #pragma unroll
            for (int j = 0; j < 4; ++j) acc[i][j] = (f32x4){0.f, 0.f, 0.f, 0.f};

        #pragma unroll
        for (int i = 0; i < 12; ++i) {
            int task = i * 256 + tid;
            int r = task / 24, c = task % 24;
            uint4 v = *(const uint4*)(Xbase + (size_t)r * xRow + c * 8);
            *(uint4*)&xs[r * 200 + c * 8] = v;
        }
        __syncthreads();

        if (EPI == 0) {
            int px = tid >> 1, hh = tid & 1;
            float s = 0.f, ss = 0.f;
            #pragma unroll
            for (int i = 0; i < 12; ++i) {
                F8 v = loadh8(xs + px * 200 + hh * 96 + i * 8);
                #pragma unroll
                for (int j = 0; j < 8; ++j) { s += v.v[j]; ss = fmaf(v.v[j], v.v[j], ss); }
            }
            s += __shfl_xor(s, 1, 64);
            ss += __shfl_xor(ss, 1, 64);
            if (hh == 0) {
                float m = s * (1.f / 192.f);
                float var = ss * (1.f / 192.f) - m * m;
                smu[px] = m;
                srs[px] = rsqrtf(var + 1e-5f);
            }
        }

        #pragma unroll
        for (int k32 = 0; k32 < 6; ++k32) {
            f16x8 af[4], bfr[4];
            #pragma unroll
            for (int mf = 0; mf < 4; ++mf)
                af[mf] = *(const f16x8*)(Ab + ((size_t)(o16b + mf) * 6 + k32) * 512 + lane * 8);
            #pragma unroll
            for (int nf = 0; nf < 4; ++nf)
                bfr[nf] = *(const f16x8*)&xs[(wx * 64 + nf * 16 + l15) * 200 + k32 * 32 + kg * 8];
            #pragma unroll
            for (int mf = 0; mf < 4; ++mf)
                #pragma unroll
                for (int nf = 0; nf < 4; ++nf)
                    acc[mf][nf] = __builtin_amdgcn_mfma_f32_16x16x32_f16(af[mf], bfr[nf], acc[mf][nf], 0, 0, 0);
        }
        __syncthreads();

        #pragma unroll
        for (int nf = 0; nf < 4; ++nf) {
            const int nl = wx * 64 + nf * 16 + l15;
            float muv = 0.f, rsv = 0.f;
            if (EPI == 0) { muv = smu[nl]; rsv = srs[nl]; }
            #pragma unroll
            for (int mf = 0; mf < 4; ++mf) {
                const int obl = wy * 64 + mf * 16 + kg * 4;
                float r0, r1, r2, r3;
                if (EPI == 0) {
                    float4 uv = *(const float4*)(uvec + (size_t)b * uStride + om + obl);
                    float4 vv = *(const float4*)(v0vec + (size_t)b * uStride + om + obl);
                    r0 = rsv * (acc[mf][nf][0] - muv * uv.x) + vv.x;
                    r1 = rsv * (acc[mf][nf][1] - muv * uv.y) + vv.y;
                    r2 = rsv * (acc[mf][nf][2] - muv * uv.z) + vv.z;
                    r3 = rsv * (acc[mf][nf][3] - muv * uv.w) + vv.w;
                } else {
                    r0 = acc[mf][nf][0]; r1 = acc[mf][nf][1];
                    r2 = acc[mf][nf][2]; r3 = acc[mf][nf][3];
                }
                ushort4 pk;
                pk.x = f2h(r0); pk.y = f2h(r1); pk.z = f2h(r2); pk.w = f2h(r3);
                *(ushort4*)&stg[nl][obl] = pk;
            }
        }
        __syncthreads();

        #pragma unroll
        for (int it = 0; it < 8; ++it) {
            int task = it * 256 + tid;
            int nl = task >> 4, ch = task & 15;
            int oc = om + ch * 8;
            if (oc >= Oreal) continue;
            uint4 sv = *(const uint4*)&stg[nl][ch * 8];
            size_t nglob = (size_t)b * NHW + n0 + nl;
            if (EPI == 0) {
                *(uint4*)((bfu*)Y + nglob * yRow + oc) = sv;
            } else {
                float a[8];
                a[0] = h2f((unsigned short)(sv.x & 0xffff)); a[1] = h2f((unsigned short)(sv.x >> 16));
                a[2] = h2f((unsigned short)(sv.y & 0xffff)); a[3] = h2f((unsigned short)(sv.y >> 16));
                a[4] = h2f((unsigned short)(sv.z & 0xffff)); a[5] = h2f((unsigned short)(sv.z >> 16));
                a[6] = h2f((unsigned short)(sv.w & 0xffff)); a[7] = h2f((unsigned short)(sv.w >> 16));
                F8 rv = loadh8((const bfu*)res + nglob * resRow + oc);
                #pragma unroll
                for (int j = 0; j < 8; ++j) a[j] += rv.v[j];
                storeh8((bfu*)Y + nglob * yRow + oc, a);
            }
        }
    } else {
        const int n0 = blockIdx.x * 64;
        const bfu* Xbase = X + ((size_t)b * NHW + n0) * xRow + xOff;
        const int sr = tid >> 3, sc = tid & 7;
        const int NCH = K >> 6;

        f32x4 acc[4][2];
        #pragma unroll
        for (int i = 0; i < 4; ++i)
            #pragma unroll
            for (int j = 0; j < 2; ++j) acc[i][j] = (f32x4){0.f, 0.f, 0.f, 0.f};

        #pragma unroll
        for (int i = 0; i < 2; ++i) {
            int r = i * 32 + sr;
            uint4 v = *(const uint4*)(Xbase + (size_t)r * xRow + sc * 8);
            *(uint4*)&xs[r * 72 + sc * 8] = v;
        }
        __syncthreads();
        for (int kc = 0; kc < NCH; ++kc) {
            const int cur = kc & 1;
            if (kc + 1 < NCH) {
                #pragma unroll
                for (int i = 0; i < 2; ++i) {
                    int r = i * 32 + sr;
                    uint4 v = *(const uint4*)(Xbase + (size_t)r * xRow + (kc + 1) * 64 + sc * 8);
                    *(uint4*)&xs[((cur ^ 1) * 64 + r) * 72 + sc * 8] = v;
                }
            }
            #pragma unroll
            for (int ks = 0; ks < 2; ++ks) {
                const int k32 = kc * 2 + ks;
                f16x8 af[4], bfr[2];
                #pragma unroll
                for (int mf = 0; mf < 4; ++mf)
                    af[mf] = *(const f16x8*)(Ab + ((size_t)(o16b + mf) * K32 + k32) * 512 + lane * 8);
                #pragma unroll
                for (int nf = 0; nf < 2; ++nf)
                    bfr[nf] = *(const f16x8*)&xs[(cur * 64 + wx * 32 + nf * 16 + l15) * 72 + ks * 32 + kg * 8];
                #pragma unroll
                for (int mf = 0; mf < 4; ++mf)
                    #pragma unroll
                    for (int nf = 0; nf < 2; ++nf)
                        acc[mf][nf] = __builtin_amdgcn_mfma_f32_16x16x32_f16(af[mf], bfr[nf], acc[mf][nf], 0, 0, 0);
            }
            __syncthreads();
        }

        #pragma unroll
        for (int nf = 0; nf < 2; ++nf) {
            const int nl = wx * 32 + nf * 16 + l15;
            #pragma unroll
            for (int mf = 0; mf < 4; ++mf) {
                const int obl = wy * 64 + mf * 16 + kg * 4;
                stg32[nl][obl + 0] = acc[mf][nf][0];
                stg32[nl][obl + 1] = acc[mf][nf][1];
                stg32[nl][obl + 2] = acc[mf][nf][2];
                stg32[nl][obl + 3] = acc[mf][nf][3];
            }
        }
        __syncthreads();

        #pragma unroll
        for (int it = 0; it < 8; ++it) {
            int task = it * 256 + tid;
            int o = task >> 4, q = task & 15;
            int oc = om + o;
            if (oc >= Oreal) continue;
            float vals[4];
            #pragma unroll
            for (int j = 0; j < 4; ++j) {
                float v = stg32[q * 4 + j][o];
                float r = h2f(((const bfu*)res)[((size_t)b * NHW + n0 + q * 4 + j) * resRow + oc]);
                vals[j] = v + r;
            }
            *(float4*)((float*)Y + ((size_t)b * NC + oc) * NHW + n0 + q * 4) =
                make_float4(vals[0], vals[1], vals[2], vals[3]);
        }
    }
}

// ---------------------------------------------------------------------------
// depthwise 3x3, fp16 packed math, thread = 8ch x 8px x 2 ROWS, XCD-swizzled.
// grid: cb * (NHW/16) * (CIN/8) / 256  (must be %8==0)
// ---------------------------------------------------------------------------
template<int CIN>
__global__ __launch_bounds__(256) void dw_pm8x2(
    const bfu* __restrict__ in, const bfu* __restrict__ wT, bfu* __restrict__ out, int cb)
{
    const int CHUNKS = CIN / 8;       // 72
    const int UNITS = NHW / 16;       // 1024 (16 x-octets * 64 y-pairs)
    const int wid = xcd_swz(blockIdx.x, gridDim.x);
    int f = wid * 256 + threadIdx.x;
    if (f >= cb * UNITS * CHUNKS) return;
    int ch = f % CHUNKS;
    int pu = f / CHUNKS;
    int u = pu % UNITS;
    int b = pu / UNITS;
    int xq = u & 15, yh = u >> 4;
    int x0 = xq * 8, y0 = yh * 2;
    const int c8 = ch * 8;
    const bfu* base = in + ((size_t)b * NHW) * CIN + c8;

    // full 9-tap weight cache
    f16x2 w[9][4];
    #pragma unroll
    for (int t = 0; t < 9; ++t) {
        H8 wv; wv.u = *(const uint4*)(wT + (size_t)t * CIN + c8);
        #pragma unroll
        for (int q = 0; q < 4; ++q) w[t][q] = wv.h[q];
    }

    f16x2 acc[2][8][4];
    #pragma unroll
    for (int oy = 0; oy < 2; ++oy)
        #pragma unroll
        for (int j = 0; j < 8; ++j)
            #pragma unroll
            for (int q = 0; q < 4; ++q) acc[oy][j][q] = h2z();

    #pragma unroll
    for (int ry = 0; ry < 4; ++ry) {
        int yy = y0 - 1 + ry;
        if ((unsigned)yy >= (unsigned)NWID) continue;
        const bfu* rb = base + (size_t)yy * NWID * CIN;
        #pragma unroll
        for (int c = 0; c < 10; ++c) {
            int xx = x0 - 1 + c;
            if ((unsigned)xx >= (unsigned)NWID) continue;
            H8 v; v.u = *(const uint4*)(rb + (size_t)xx * CIN);
            #pragma unroll
            for (int oy = 0; oy < 2; ++oy) {
                int rt = ry - oy;
                if (rt < 0 || rt > 2) continue;
                #pragma unroll
                for (int j = 0; j < 8; ++j) {
                    int tx = c - j;
                    if (tx < 0 || tx > 2) continue;
                    #pragma unroll
                    for (int q = 0; q < 4; ++q)
                        acc[oy][j][q] = w[rt * 3 + tx][q] * v.h[q] + acc[oy][j][q];
                }
            }
        }
    }
    #pragma unroll
    for (int oy = 0; oy < 2; ++oy) {
        #pragma unroll
        for (int j = 0; j < 8; ++j) {
            H8 o;
            #pragma unroll
            for (int q = 0; q < 4; ++q) o.h[q] = acc[oy][j][q];
            *(uint4*)(out + ((size_t)b * NHW + (size_t)(y0 + oy) * NWID + x0 + j) * CIN + c8) = o.u;
        }
    }
}

// ---------------------------------------------------------------------------
// depthwise 3x3 + GELU gate, fp16 packed math, thread = 8ch x 8px, XCD-swz.
// ---------------------------------------------------------------------------
template<int CIN, int COUT>
__global__ __launch_bounds__(256) void dw_gate8(
    const bfu* __restrict__ in, const bfu* __restrict__ wT, bfu* __restrict__ out, int cb)
{
    const int CHUNKS = COUT / 8;      // 64
    const int NPB = NHW / 8;          // 2048
    const int wid = xcd_swz(blockIdx.x, gridDim.x);
    int f = wid * 256 + threadIdx.x;
    if (f >= cb * NPB * CHUNKS) return;
    int ch = f % CHUNKS;
    int pb = f / CHUNKS;
    int n8 = pb & (NPB - 1);
    int b  = pb >> 11;
    int xq = n8 & 15, y = n8 >> 4;
    int x0 = xq * 8;
    const int c8 = ch * 8;
    const bfu* rowb = in + ((size_t)b * NHW + (size_t)y * NWID) * CIN + c8;

    f16x2 a1[8][4], a2[8][4];
    #pragma unroll
    for (int j = 0; j < 8; ++j)
        #pragma unroll
        for (int q = 0; q < 4; ++q) { a1[j][q] = h2z(); a2[j][q] = h2z(); }

    #pragma unroll
    for (int dy = -1; dy <= 1; ++dy) {
        int yy = y + dy;
        if ((unsigned)yy >= (unsigned)NWID) continue;
        const bfu* rb = rowb + (long)dy * NWID * CIN;
        f16x2 w1[3][4], w2[3][4];
        #pragma unroll
        for (int t = 0; t < 3; ++t) {
            const bfu* wp = wT + (size_t)((dy + 1) * 3 + t) * CIN + c8;
            H8 wa; wa.u = *(const uint4*)wp;
            H8 wb; wb.u = *(const uint4*)(wp + 512);
            #pragma unroll
            for (int q = 0; q < 4; ++q) { w1[t][q] = wa.h[q]; w2[t][q] = wb.h[q]; }
        }
        #pragma unroll
        for (int c = 0; c < 10; ++c) {
            int xx = x0 - 1 + c;
            if ((unsigned)xx >= (unsigned)NWID) continue;
            H8 v1; v1.u = *(const uint4*)(rb + (size_t)xx * CIN);
            H8 v2; v2.u = *(const uint4*)(rb + (size_t)xx * CIN + 512);
            #pragma unroll
            for (int j = 0; j < 8; ++j) {
                int t = c - j;
                if (t < 0 || t > 2) continue;
                #pragma unroll
                for (int q = 0; q < 4; ++q) {
                    a1[j][q] = w1[t][q] * v1.h[q] + a1[j][q];
                    a2[j][q] = w2[t][q] * v2.h[q] + a2[j][q];
                }
            }
        }
    }
    #pragma unroll
    for (int j = 0; j < 8; ++j) {
        H8 o;
        #pragma unroll
        for (int q = 0; q < 4; ++q) {
            float g0 = gelu_tanh((float)a1[j][q][0]) * (float)a2[j][q][0];
            float g1 = gelu_tanh((float)a1[j][q][1]) * (float)a2[j][q][1];
            f16x2 r; r[0] = (_Float16)g0; r[1] = (_Float16)g1;
            o.h[q] = r;
        }
        *(uint4*)(out + ((size_t)b * NHW + (size_t)y * NWID + x0 + j) * COUT + c8) = o.u;
    }
}

// ---------------------------------------------------------------------------
// MFMA Gram (fp16). grid (64 n-chunks, CB). 4 waves x 2 heads each.
// ---------------------------------------------------------------------------
__global__ __launch_bounds__(256) void gram_pm(
    const bfu* __restrict__ qkv, float* __restrict__ S32,
    float* __restrict__ Q2, float* __restrict__ K2, int b0)
{
    __shared__ bfu lds[392 * 72];
    const int b = blockIdx.y;
    const int nc = blockIdx.x;
    const int tid = threadIdx.x;
    const int lane = tid & 63, wave = tid >> 6;
    const int l15 = lane & 15, kg = lane >> 4;

    f32x4 sAcc[2][2][2], qAcc[2][2], kAcc[2][2];
    #pragma unroll
    for (int h = 0; h < 2; ++h)
        #pragma unroll
        for (int i = 0; i < 2; ++i) {
            qAcc[h][i] = (f32x4){0.f, 0.f, 0.f, 0.f};
            kAcc[h][i] = (f32x4){0.f, 0.f, 0.f, 0.f};
            #pragma unroll
            for (int j = 0; j < 2; ++j) sAcc[h][i][j] = (f32x4){0.f, 0.f, 0.f, 0.f};
        }

    const size_t pbase = (size_t)b * NHW + (size_t)nc * 256;
    unsigned* ldsw = (unsigned*)lds;

    for (int it = 0; it < 4; ++it) {
        const size_t nb = pbase + it * 64;
        #pragma unroll
        for (int i = 0; i < 6; ++i) {
            int task = i * 256 + tid;
            int np = task & 31, ch = task >> 5;
            const bfu* r0 = qkv + (nb + np * 2) * CQKV + ch * 8;
            uint4 v0 = *(const uint4*)r0;
            uint4 v1 = *(const uint4*)(r0 + CQKV);
            int cb8 = ch * 8;
            ldsw[(cb8 + 0) * 36 + np] = (v0.x & 0xffffu) | (v1.x << 16);
            ldsw[(cb8 + 1) * 36 + np] = (v0.x >> 16) | (v1.x & 0xffff0000u);
            ldsw[(cb8 + 2) * 36 + np] = (v0.y & 0xffffu) | (v1.y << 16);
            ldsw[(cb8 + 3) * 36 + np] = (v0.y >> 16) | (v1.y & 0xffff0000u);
            ldsw[(cb8 + 4) * 36 + np] = (v0.z & 0xffffu) | (v1.z << 16);
            ldsw[(cb8 + 5) * 36 + np] = (v0.z >> 16) | (v1.z & 0xffff0000u);
            ldsw[(cb8 + 6) * 36 + np] = (v0.w & 0xffffu) | (v1.w << 16);
            ldsw[(cb8 + 7) * 36 + np] = (v0.w >> 16) | (v1.w & 0xffff0000u);
        }
        ldsw[(384 + (tid >> 5)) * 36 + (tid & 31)] = 0;
        __syncthreads();
        #pragma unroll
        for (int hh = 0; hh < 2; ++hh) {
            const int h = wave * 2 + hh;
            const int qr = h * NCF, kr = NC + h * NCF;
            #pragma unroll
            for (int ks = 0; ks < 2; ++ks) {
                const int nsub = ks * 32 + kg * 8;
                f16x8 aq0 = *(const f16x8*)(lds + (qr + l15) * 72 + nsub);
                f16x8 aq1 = *(const f16x8*)(lds + (qr + 16 + l15) * 72 + nsub);
                f16x8 bk0 = *(const f16x8*)(lds + (kr + l15) * 72 + nsub);
                f16x8 bk1 = *(const f16x8*)(lds + (kr + 16 + l15) * 72 + nsub);
                sAcc[hh][0][0] = __builtin_amdgcn_mfma_f32_16x16x32_f16(aq0, bk0, sAcc[hh][0][0], 0, 0, 0);
                sAcc[hh][0][1] = __builtin_amdgcn_mfma_f32_16x16x32_f16(aq0, bk1, sAcc[hh][0][1], 0, 0, 0);
                sAcc[hh][1][0] = __builtin_amdgcn_mfma_f32_16x16x32_f16(aq1, bk0, sAcc[hh][1][0], 0, 0, 0);
                sAcc[hh][1][1] = __builtin_amdgcn_mfma_f32_16x16x32_f16(aq1, bk1, sAcc[hh][1][1], 0, 0, 0);
                qAcc[hh][0] = __builtin_amdgcn_mfma_f32_16x16x32_f16(aq0, aq0, qAcc[hh][0], 0, 0, 0);
                qAcc[hh][1] = __builtin_amdgcn_mfma_f32_16x16x32_f16(aq1, aq1, qAcc[hh][1], 0, 0, 0);
                kAcc[hh][0] = __builtin_amdgcn_mfma_f32_16x16x32_f16(bk0, bk0, kAcc[hh][0], 0, 0, 0);
                kAcc[hh][1] = __builtin_amdgcn_mfma_f32_16x16x32_f16(bk1, bk1, kAcc[hh][1], 0, 0, 0);
            }
        }
        __syncthreads();
    }

    const int gb = b0 + b;
    #pragma unroll
    for (int hh = 0; hh < 2; ++hh) {
        const int h = wave * 2 + hh;
        float* Sp = S32 + ((size_t)gb * NHEADS + h) * 1024;
        #pragma unroll
        for (int mt = 0; mt < 2; ++mt)
            #pragma unroll
            for (int nt = 0; nt < 2; ++nt)
                #pragma unroll
                for (int r = 0; r < 4; ++r) {
                    int c = mt * 16 + kg * 4 + r, d = nt * 16 + l15;
                    atomicAdd(&Sp[c * 32 + d], sAcc[hh][mt][nt][r]);
                }
        #pragma unroll
        for (int t = 0; t < 2; ++t)
            #pragma unroll
            for (int r = 0; r < 4; ++r) {
                int row = t * 16 + kg * 4 + r, col = t * 16 + l15;
                if (row == col && row < NCF) {
                    atomicAdd(&Q2[((size_t)gb * NHEADS + h) * NCF + row], qAcc[hh][t][r]);
                    atomicAdd(&K2[((size_t)gb * NHEADS + h) * NCF + row], kAcc[hh][t][r]);
                }
            }
    }
}

// ---------------------------------------------------------------------------
// normalize -> softmax -> fold proj_w -> Mbf packed-fragment fp16. grid(CB)
// ---------------------------------------------------------------------------
__global__ __launch_bounds__(256) void attn_fold(
    const float* __restrict__ S32, const float* __restrict__ Q2, const float* __restrict__ K2,
    const float* __restrict__ temp, const float* __restrict__ projw, bfu* __restrict__ Mbf, int b0)
{
    const int gb = b0 + blockIdx.x, tid = threadIdx.x;
    __shared__ float P[NHEADS * NCF * NCF];
    for (int e = tid; e < NHEADS * NCF * NCF; e += 256) {
        int h = e / (NCF * NCF);
        int r = e % (NCF * NCF);
        int c = r / NCF, d = r % NCF;
        float sv = S32[((size_t)gb * NHEADS + h) * 1024 + c * 32 + d];
        float rq = sqrtf(Q2[((size_t)gb * NHEADS + h) * NCF + c]);
        float rk = sqrtf(K2[((size_t)gb * NHEADS + h) * NCF + d]);
        P[e] = sv / (rq * rk) * temp[h];
    }
    __syncthreads();
    if (tid < NHEADS * NCF) {
        int h = tid / NCF, c = tid % NCF;
        float* row = P + h * (NCF * NCF) + c * NCF;
        float mx = row[0];
        #pragma unroll
        for (int d = 1; d < NCF; ++d) mx = fmaxf(mx, row[d]);
        float sum = 0.f;
        #pragma unroll
        for (int d = 0; d < NCF; ++d) { float e2 = __expf(row[d] - mx); row[d] = e2; sum += e2; }
        float inv = 1.f / sum;
        #pragma unroll
        for (int d = 0; d < NCF; ++d) row[d] *= inv;
    }
    __syncthreads();
    bfu* Mb = Mbf + (size_t)gb * OM_PAD * NC;
    if (tid < NC) {
        int o = tid;
        int o16 = o >> 4, l15o = o & 15;
        for (int h = 0; h < NHEADS; ++h) {
            float pw[NCF];
            #pragma unroll
            for (int c = 0; c < NCF; ++c) pw[c] = projw[(size_t)o * NC + h * NCF + c];
            #pragma unroll
            for (int d = 0; d < NCF; ++d) {
                float acc = 0.f;
                #pragma unroll
                for (int c = 0; c < NCF; ++c) acc = fmaf(pw[c], P[h * (NCF * NCF) + c * NCF + d], acc);
                int cc = h * NCF + d;
                int idx = (o16 * 6 + (cc >> 5)) * 512 + ((cc >> 3) & 3) * 128 + l15o * 8 + (cc & 7);
                Mb[idx] = f2h(acc);
            }
        }
    }
    for (int e = tid; e < (OM_PAD - NC) * NC; e += 256) Mb[NC * NC + e] = 0;
}

// ---------------------------------------------------------------------------
extern "C" void kernel_launch(void* const* d_in, const int* in_sizes, int n_in,
                              void* d_out, int out_size, void* d_ws, size_t ws_size,
                              hipStream_t stream)
{
    const float* x     = (const float*)d_in[0];
    const float* kv    = (const float*)d_in[1];
    const float* ln1w  = (const float*)d_in[2];
    const float* ln1b  = (const float*)d_in[3];
    const float* akern = (const float*)d_in[4];
    const float* qkvw  = (const float*)d_in[5];
    const float* qkvdw = (const float*)d_in[6];
    const float* projw = (const float*)d_in[7];
    const float* temp  = (const float*)d_in[8];
    const float* ln2w  = (const float*)d_in[9];
    const float* ln2b  = (const float*)d_in[10];
    const float* fkern = (const float*)d_in[11];
    const float* pinw  = (const float*)d_in[12];
    const float* ffndw = (const float*)d_in[13];
    const float* poutw = (const float*)d_in[14];
    float* out = (float*)d_out;

    char* wp = (char*)d_ws;
    size_t off = 0;
    auto take = [&](size_t bytes) {
        char* r = wp + off;
        off = (off + bytes + 255) & ~(size_t)255;
        return r;
    };
    float* s1 = (float*)take(NB * NC * 4);  float* t1 = (float*)take(NB * NC * 4);
    float* s2 = (float*)take(NB * NC * 4);  float* t2 = (float*)take(NB * NC * 4);
    bfu* A1 = (bfu*)take((size_t)NB * OQKV_PAD * 192 * 2);
    bfu* A2 = (bfu*)take((size_t)NB * CPIN * 192 * 2);
    bfu* A3 = (bfu*)take((size_t)OM_PAD * 512 * 2);
    bfu* Mbf = (bfu*)take((size_t)NB * OM_PAD * NC * 2);
    float* u1  = (float*)take((size_t)NB * OQKV_PAD * 4);
    float* v01 = (float*)take((size_t)NB * OQKV_PAD * 4);
    float* u2  = (float*)take((size_t)NB * CPIN * 4);
    float* v02 = (float*)take((size_t)NB * CPIN * 4);
    bfu* wdwT1 = (bfu*)take(9 * CQKV * 2);
    bfu* wdwT2 = (bfu*)take(9 * CPIN * 2);
    float* S32 = (float*)take((size_t)NB * NHEADS * 1024 * 4);
    float* Q2  = (float*)take((size_t)NB * NHEADS * NCF * 4);
    float* K2  = (float*)take((size_t)NB * NHEADS * NCF * 4);
    const size_t bigoff = off;

    const size_t PB = (size_t)NHW * (384 + 384 + 2048 + 1152);
    size_t avail = (ws_size > bigoff) ? ws_size - bigoff : 0;
    int CB = 8;
    while (CB > 1 && (size_t)CB * PB > avail) CB >>= 1;

    dim3 blk(256);

    prep_film<<<dim3(48, NB), blk, 0, stream>>>(kv, akern, ln1w, ln1b, s1, t1);
    prep_film<<<dim3(48, NB), blk, 0, stream>>>(kv, fkern, ln2w, ln2b, s2, t2);
    wprep<<<dim3(OQKV_PAD / 4, NB), blk, 0, stream>>>(qkvw, s1, t1, A1, u1, v01, 0);
    wprep<<<dim3(CPIN / 4, NB), blk, 0, stream>>>(pinw, s2, t2, A2, u2, v02, 1);
    wprep<<<dim3(OM_PAD / 4, 1), blk, 0, stream>>>(poutw, s1, t1, A3, nullptr, nullptr, 2);
    wdw_prep<<<(9 * CQKV + 255) / 256, blk, 0, stream>>>(qkvdw, wdwT1, CQKV, 0);
    wdw_prep<<<(9 * CPIN + 255) / 256, blk, 0, stream>>>(ffndw, wdwT2, CPIN, 1);
    {
        int nz = NB * NHEADS * 1024 + 2 * NB * NHEADS * NCF + 256;
        zfill<<<(nz + 255) / 256, blk, 0, stream>>>(S32, nz);
    }

    for (int b0 = 0; b0 < NB; b0 += CB) {
        bfu* bfX  = (bfu*)(wp + bigoff);
        bfu* out1 = (bfu*)(wp + bigoff + (size_t)CB * NHW * 384);
        char* big1 = wp + bigoff + (size_t)CB * NHW * 768;
        char* big2 = big1 + (size_t)CB * NHW * 2048;
        bfu* qkv_pre = (bfu*)big1;
        bfu* qkvb    = (bfu*)big2;
        bfu* u_pre   = (bfu*)big1;
        bfu* gbuf    = (bfu*)big2;

        const float* xb = x + (size_t)b0 * NC * NHW;

        // ---- attention branch ----
        ln_cvt_cm<<<CB * 256, blk, 0, stream>>>(xb, bfX, CB);
        gemm_pm<0><<<dim3(128, OQKV_PAD / 128, CB), blk, 0, stream>>>(
            A1 + (size_t)b0 * OQKV_PAD * 192, (long)OQKV_PAD * 192, OQKV_PAD, CQKV, 192,
            bfX, NC, 0, qkv_pre, CQKV, nullptr, 0,
            u1 + (size_t)b0 * OQKV_PAD, v01 + (size_t)b0 * OQKV_PAD, OQKV_PAD);
        dw_pm8x2<CQKV><<<CB * 288, blk, 0, stream>>>(qkv_pre, wdwT1, qkvb, CB);
        gram_pm<<<dim3(64, CB), blk, 0, stream>>>(qkvb, S32, Q2, K2, b0);
        attn_fold<<<CB, blk, 0, stream>>>(S32, Q2, K2, temp, projw, Mbf, b0);
        // out1(fp16) = bfX + M @ v
        gemm_pm<1><<<dim3(128, OM_PAD / 128, CB), blk, 0, stream>>>(
            Mbf + (size_t)b0 * OM_PAD * NC, (long)OM_PAD * NC, OM_PAD, NC, 192,
            qkvb, CQKV, 384, out1, NC, bfX, NC,
            nullptr, nullptr, 0);

        // ---- FFN branch ----
        gemm_pm<0><<<dim3(128, CPIN / 128, CB), blk, 0, stream>>>(
            A2 + (size_t)b0 * CPIN * 192, (long)CPIN * 192, CPIN, CPIN, 192,
            out1, NC, 0, u_pre, CPIN, nullptr, 0,
            u2 + (size_t)b0 * CPIN, v02 + (size_t)b0 * CPIN, CPIN);
        dw_gate8<CPIN, CG><<<CB * 512, blk, 0, stream>>>(u_pre, wdwT2, gbuf, CB);
        // d_out (f32 channel-major) = out1 + pout @ g, written directly
        gemm_pm<3><<<dim3(256, OM_PAD / 128, CB), blk, 0, stream>>>(
            A3, 0, OM_PAD, NC, 512,
            gbuf, CG, 0, out + (size_t)b0 * NC * NHW, 0, out1, NC,
            nullptr, nullptr, 0);
    }
}